// Round 6
// baseline (435.718 us; speedup 1.0000x reference)
//
#include <hip/hip_runtime.h>

typedef unsigned short u16;
typedef __attribute__((ext_vector_type(8))) short bf16x8;
typedef __attribute__((ext_vector_type(8))) unsigned short u16x8;
typedef __attribute__((ext_vector_type(4))) float f32x4;

#define L_SEQ 2048
#define NTOK 4096   // B*L
#define DMODEL 1024
#define DEXP 2048
#define NH 16
#define DH 128

__device__ __forceinline__ u16 f2bf(float f) {
    unsigned u = __float_as_uint(f);
    unsigned r = (u + 0x7FFFu + ((u >> 16) & 1u)) >> 16;
    return (u16)r;
}
__device__ __forceinline__ float bf2f(u16 h) {
    return __uint_as_float(((unsigned)h) << 16);
}

// DPP cross-lane (16-lane row) reduction helpers: VALU latency, no LDS.
template <int CTRL>
__device__ __forceinline__ float dpp_f(float x) {
    return __int_as_float(__builtin_amdgcn_update_dpp(0, __float_as_int(x), CTRL, 0xF, 0xF, true));
}
__device__ __forceinline__ float red16_max(float x) {
    x = fmaxf(x, dpp_f<0xB1>(x));   // quad_perm xor1
    x = fmaxf(x, dpp_f<0x4E>(x));   // quad_perm xor2
    x = fmaxf(x, dpp_f<0x124>(x));  // row_ror:4
    x = fmaxf(x, dpp_f<0x128>(x));  // row_ror:8
    return x;
}

// async global->LDS, 16B per lane; LDS dest = wave-uniform base + lane*16
__device__ __forceinline__ void gl_lds16(const u16* g, u16* l) {
    __builtin_amdgcn_global_load_lds((const __attribute__((address_space(1))) void*)g,
                                     (__attribute__((address_space(3))) void*)l, 16, 0, 0);
}

// ---------------- convert + transpose fp32 -> bf16, out[c*R + r] = in[r*C + c]
__global__ void conv_transpose(const float* __restrict__ in, u16* __restrict__ out, int R, int C) {
    __shared__ unsigned tile[32][33];
    int c0 = blockIdx.x * 32, r0 = blockIdx.y * 32;
    int tx = threadIdx.x, ty = threadIdx.y;
    for (int j = 0; j < 32; j += 8)
        tile[ty + j][tx] = (unsigned)f2bf(in[(size_t)(r0 + ty + j) * C + c0 + tx]);
    __syncthreads();
    for (int j = 0; j < 32; j += 8)
        out[(size_t)(c0 + ty + j) * R + r0 + tx] = (u16)tile[tx][ty + j];
}

// ---------------- layernorm over 1024, out bf16 or fp32
__global__ __launch_bounds__(256) void ln_fwd(const float* __restrict__ x, const float* __restrict__ g,
                                              const float* __restrict__ bta, void* __restrict__ outp,
                                              int out_bf16) {
    int row = blockIdx.x;
    int t = threadIdx.x;
    const float* xr = x + (size_t)row * DMODEL;
    float4 xv = *(const float4*)&xr[t * 4];
    float s = xv.x + xv.y + xv.z + xv.w;
    float s2 = xv.x * xv.x + xv.y * xv.y + xv.z * xv.z + xv.w * xv.w;
    for (int off = 32; off >= 1; off >>= 1) {
        s += __shfl_xor(s, off);
        s2 += __shfl_xor(s2, off);
    }
    __shared__ float red[10];
    int w = t >> 6;
    if ((t & 63) == 0) { red[w] = s; red[4 + w] = s2; }
    __syncthreads();
    if (t == 0) {
        red[8] = red[0] + red[1] + red[2] + red[3];
        red[9] = red[4] + red[5] + red[6] + red[7];
    }
    __syncthreads();
    float mu = red[8] * (1.0f / DMODEL);
    float var = red[9] * (1.0f / DMODEL) - mu * mu;
    float rstd = rsqrtf(var + 1e-5f);
    float vals[4] = {xv.x, xv.y, xv.z, xv.w};
    for (int e = 0; e < 4; e++) {
        int c = t * 4 + e;
        float y = (vals[e] - mu) * rstd * g[c] + bta[c];
        if (out_bf16) ((u16*)outp)[(size_t)row * DMODEL + c] = f2bf(y);
        else          ((float*)outp)[(size_t)row * DMODEL + c] = y;
    }
}

// ---------------- GEMM (128^2, 2-phase): C[M,N] = A[M,K](bf16)*B, B as BT[N,K]
__device__ __forceinline__ void store_out(u16* C, size_t idx, float v) { C[idx] = f2bf(v); }
__device__ __forceinline__ void store_out(float* C, size_t idx, float v) { C[idx] = v; }

template <typename OutT>
__global__ __launch_bounds__(256) void gemm_bt(const u16* __restrict__ A, const u16* __restrict__ BT,
                                               OutT* __restrict__ C, int M, int N, int K) {
    __shared__ u16 a_s[2][4096];   // dbuf x 128 rows x 32 k (16-row chunks)
    __shared__ u16 b_s[2][4096];
    int tid = threadIdx.x;
    unsigned NX = gridDim.x;
    unsigned lin = blockIdx.x + NX * blockIdx.y;
    unsigned per = NX >> 3;                 // N-panels per XCD (NX % 8 == 0)
    unsigned xcd = lin & 7, t = lin >> 3;
    unsigned n_p = xcd * per + (t % per);
    unsigned m_p = t / per;
    int m0 = m_p * 128, n0 = n_p * 128;
    int w = tid >> 6, lane = tid & 63, quad = lane >> 4, ln = lane & 15;
    int wr = (w >> 1) * 64, wc = (w & 1) * 64;
    f32x4 zero4 = {0.f, 0.f, 0.f, 0.f};
    f32x4 acc[4][4];
    for (int r = 0; r < 4; r++)
        for (int c = 0; c < 4; c++) acc[r][c] = zero4;

    int lrow = lane >> 2, lseg = (lane & 3) * 8;
    const u16* Ag0 = A + (size_t)(m0 + 32 * w + lrow) * K + lseg;
    const u16* Ag1 = Ag0 + (size_t)16 * K;
    const u16* Bg0 = BT + (size_t)(n0 + 32 * w + lrow) * K + lseg;
    const u16* Bg1 = Bg0 + (size_t)16 * K;
    int lo0 = (2 * w) * 512, lo1 = (2 * w + 1) * 512;

    gl_lds16(Ag0, &a_s[0][lo0]);
    gl_lds16(Ag1, &a_s[0][lo1]);
    gl_lds16(Bg0, &b_s[0][lo0]);
    gl_lds16(Bg1, &b_s[0][lo1]);
    __syncthreads();

    int cur = 0;
    for (int k0 = 0; k0 < K; k0 += 32) {
        if (k0 + 32 < K) {
            int nb = cur ^ 1;
            gl_lds16(Ag0 + k0 + 32, &a_s[nb][lo0]);
            gl_lds16(Ag1 + k0 + 32, &a_s[nb][lo1]);
            gl_lds16(Bg0 + k0 + 32, &b_s[nb][lo0]);
            gl_lds16(Bg1 + k0 + 32, &b_s[nb][lo1]);
        }
        bf16x8 af[4], bfr[4];
        for (int r = 0; r < 4; r++) af[r]  = *(const bf16x8*)&a_s[cur][(wr + r * 16 + ln) * 32 + quad * 8];
        for (int c = 0; c < 4; c++) bfr[c] = *(const bf16x8*)&b_s[cur][(wc + c * 16 + ln) * 32 + quad * 8];
        __builtin_amdgcn_s_setprio(1);
        for (int r = 0; r < 4; r++)
            for (int c = 0; c < 4; c++)
                acc[r][c] = __builtin_amdgcn_mfma_f32_16x16x32_bf16(af[r], bfr[c], acc[r][c], 0, 0, 0);
        __builtin_amdgcn_s_setprio(0);
        __syncthreads();
        cur ^= 1;
    }
    for (int r = 0; r < 4; r++)
        for (int c = 0; c < 4; c++)
            for (int e = 0; e < 4; e++) {
                int row = m0 + wr + r * 16 + quad * 4 + e;
                int col = n0 + wc + c * 16 + ln;
                store_out(C, (size_t)row * N + col, acc[r][c][e]);
            }
}

// ---------------- smear: k_sm[bh][l][d] = (1-s)*k + s*k_prev  (head-major layout)
__global__ __launch_bounds__(256) void smear_kernel(const u16* __restrict__ qkvp,
                                                    const float* __restrict__ smear_f,
                                                    u16* __restrict__ k_sm) {
    int gid = blockIdx.x * 256 + threadIdx.x;
    int base = gid * 8;
    int bl = base >> 11;       // token index
    int c = base & 2047;
    int h = c >> 7;
    int d = c & 127;
    int l = bl & (L_SEQ - 1);
    int bb = bl >> 11;
    float s = 1.0f / (1.0f + __expf(-smear_f[h]));
    u16x8 cur = *(const u16x8*)&qkvp[(size_t)bl * 8192 + 2048 + c];
    u16x8 prv = {0, 0, 0, 0, 0, 0, 0, 0};
    if (l > 0) prv = *(const u16x8*)&qkvp[(size_t)(bl - 1) * 8192 + 2048 + c];
    u16x8 outv;
    for (int u = 0; u < 8; u++) {
        float kc = bf2f(cur[u]);
        float kp = bf2f(prv[u]);
        outv[u] = f2bf((1.0f - s) * kc + s * kp);
    }
    *(u16x8*)&k_sm[(((size_t)(bb * 16 + h)) * L_SEQ + l) * DH + d] = outv;
}

// ---------------- per-(b,h) transpose of V: v_t[bh,d,l] = qkvp[tok, 4096 + h*128 + d]
__global__ void vT_kernel(const u16* __restrict__ qkvp, u16* __restrict__ v_t) {
    __shared__ unsigned tile[32][33];
    int l0 = blockIdx.x * 32, d0 = blockIdx.y * 32;
    int bh = blockIdx.z;
    int bb = bh >> 4, h = bh & 15;
    int tx = threadIdx.x, ty = threadIdx.y;
    size_t tokb = (size_t)bb * L_SEQ;
    for (int j = 0; j < 32; j += 8)
        tile[ty + j][tx] = (unsigned)qkvp[(tokb + l0 + ty + j) * 8192 + 4096 + h * DH + d0 + tx];
    __syncthreads();
    for (int j = 0; j < 32; j += 8)
        v_t[((size_t)bh * DH + d0 + ty + j) * L_SEQ + l0 + tx] = (u16)tile[tx][ty + j];
}

// ---------------- flash attention + SiLU(p) gating
// Round-13: tile-level software pipeline. Iter t: QK(t) -> PV(t-1) -> softmax(t)
// -> rescale(alpha_t). PV(t-1) MFMAs and softmax(t) VALU are independent ->
// MFMA pipe drains under the softmax chain (was: strictly serial QK->SM->PV).
// O-update sequence ..., +PV(t-1), *alpha(t), +PV(t), ... is IDENTICAL math to
// the serial version. P double-buffered in LDS with r2's 64-stride slot-XOR
// (0 conflicts measured); V staging staggered by one tile (stage V(t) at iter t)
// so the V dbuf parity stays legal with lagged PV. K staging unchanged.
// LDS = 32K (K dbuf) + 32K (V dbuf) + 16K (P dbuf) = 81920 B -> 2 blocks/CU.
__global__ __launch_bounds__(256) void attn_kernel(const u16* __restrict__ qkvp,
                                                   const u16* __restrict__ k_sm,
                                                   const u16* __restrict__ v_t,
                                                   u16* __restrict__ ag2,
                                                   const float* __restrict__ log_scale) {
    __shared__ u16 k_s[16384];     // 2 bufs x [kt 0..3][jrow 0..63][32 k] (swizzled content)
    __shared__ u16 vt_s[16384];    // 2 bufs x [jt 0..1][d 0..127][32 j]  (swizzled content)
    __shared__ u16 p_s[2][4096];   // 2 bufs x per-wave 16 rows x 64 (slot-swizzled)
    int tid = threadIdx.x;
    // XCD clustering: lin%8 = XCD (round-robin dispatch); 4 heads per XCD.
    unsigned lin = blockIdx.x + 16u * blockIdx.y;
    unsigned xcd = lin & 7, tt = lin >> 3;
    int bh = (int)(xcd * 4 + (tt & 3));
    int pair = (int)(tt >> 2);
    int bb = bh >> 4, h = bh & 15;
    int w = tid >> 6, lane = tid & 63, quad = lane >> 4, ln = lane & 15;
    size_t tokb = (size_t)bb * L_SEQ;

    const float LOG2E = 1.44269504f;
    float inv = 1.0f / (__expf(2.0f * log_scale[h]) * sqrtf((float)DH));
    float scl = inv * LOG2E;
    float slope2 = ((h < 8) ? exp2f(-8.0f * (float)h / 7.0f) : 0.0f) * LOG2E;

    int lrow = lane >> 2, lcol = lane & 3;
    int lsw8 = (lcol ^ ((lrow >> 1) & 3)) * 8;  // write-side swizzle via global source addr
    int qsw = (quad ^ ((ln >> 1) & 3)) * 8;     // read-side swizzle (same involution)
    f32x4 zero4 = {0.f, 0.f, 0.f, 0.f};
    u16* pwA = &p_s[0][w * 1024];
    u16* pwB = &p_s[1][w * 1024];
    const short ONE_BF = (short)0x3F80;
    bf16x8 ones = {ONE_BF, ONE_BF, ONE_BF, ONE_BF, ONE_BF, ONE_BF, ONE_BF, ONE_BF};

    for (int sidx = 0; sidx < 2; sidx++) {
        int ib = sidx == 0 ? (31 - pair) : pair;
        int i0 = ib * 64;
        int si = i0 + w * 16;
        int nt = i0 >> 6;   // tiles t = 0..nt

        // Q fragments straight from global (A-layout: m=ln, k=quad*8+..)
        bf16x8 qf[4];
        for (int kt = 0; kt < 4; kt++)
            qf[kt] = *(const bf16x8*)&qkvp[(tokb + si + ln) * 8192 + h * DH + kt * 32 + quad * 8];

        float m_i[4];
        for (int r = 0; r < 4; r++) m_i[r] = -1e30f;
        f32x4 o_acc[8], l_acc;
        for (int dt = 0; dt < 8; dt++) o_acc[dt] = zero4;
        l_acc = zero4;

        // staging pointers: advance by constant per staged tile (pre-swizzled source)
        const u16* kg[4];
        for (int g = 0; g < 4; g++)
            kg[g] = k_sm + ((size_t)bh * L_SEQ + g * 16 + lrow) * DH + w * 32 + lsw8;
        const u16* vg[4];
        int vloff[4];
        for (int q = 0; q < 4; q++) {
            int c = w * 4 + q;
            int jt = c >> 3, dg = c & 7;
            vg[q] = v_t + ((size_t)bh * DH + dg * 16 + lrow) * L_SEQ + jt * 32 + lsw8;
            vloff[q] = jt * 4096 + dg * 512;
        }

        // prologue: stage K(0) into kbuf[0]
        for (int g = 0; g < 4; g++) { gl_lds16(kg[g], &k_s[w * 2048 + g * 512]); kg[g] += 64 * DH; }
        __syncthreads();

        for (int t = 0; t <= nt; t++) {
            int j0 = t << 6;
            // phase 1: stage K(t+1) -> kbuf[(t+1)&1], V(t) -> vbuf[t&1]
            if (t < nt) {
                int nb = ((t + 1) & 1) * 8192;
                for (int g = 0; g < 4; g++) { gl_lds16(kg[g], &k_s[nb + w * 2048 + g * 512]); kg[g] += 64 * DH; }
            }
            {
                int vb_ = (t & 1) * 8192;
                for (int q = 0; q < 4; q++) { gl_lds16(vg[q], &vt_s[vb_ + vloff[q]]); vg[q] += 64; }
            }
            const u16* kb = &k_s[(t & 1) * 8192];

            // phase 2: QK(t): 16 rows x 64 cols per wave
            f32x4 sc[4];
            for (int ct = 0; ct < 4; ct++) sc[ct] = zero4;
            __builtin_amdgcn_s_setprio(1);
            for (int kt = 0; kt < 4; kt++)
                for (int ct = 0; ct < 4; ct++) {
                    bf16x8 bfr = *(const bf16x8*)&kb[kt * 2048 + (ct * 16 + ln) * 32 + qsw];
                    sc[ct] = __builtin_amdgcn_mfma_f32_16x16x32_bf16(qf[kt], bfr, sc[ct], 0, 0, 0);
                }
            __builtin_amdgcn_s_setprio(0);

            // phase 3: PV(t-1) -- independent of softmax(t); MFMA drains under it
            if (t > 0) {
                const u16* vbp = &vt_s[((t - 1) & 1) * 8192];
                const u16* pr = (t & 1) ? pwA : pwB;   // p_s[(t-1)&1]
                __builtin_amdgcn_s_setprio(1);
                for (int ks = 0; ks < 2; ks++) {
                    bf16x8 pa = *(const bf16x8*)&pr[ln * 64 + (((ks * 4 + quad) ^ (ln & 7)) << 3)];
                    l_acc = __builtin_amdgcn_mfma_f32_16x16x32_bf16(pa, ones, l_acc, 0, 0, 0);
                    for (int dt = 0; dt < 8; dt++) {
                        bf16x8 vf = *(const bf16x8*)&vbp[ks * 4096 + (dt * 16 + ln) * 32 + qsw];
                        o_acc[dt] = __builtin_amdgcn_mfma_f32_16x16x32_bf16(pa, vf, o_acc[dt], 0, 0, 0);
                    }
                }
                __builtin_amdgcn_s_setprio(0);
            }

            // phase 4: softmax(t) from sc; write P(t) -> p_s[t&1]
            bool full = (j0 + 63 <= si);
            float s2[4][4];
            float aj0 = slope2 * (float)(j0 + ln);
            for (int ct = 0; ct < 4; ct++) {
                float ajv = aj0 + slope2 * (float)(16 * ct);
                int j = j0 + ct * 16 + ln;
                for (int r = 0; r < 4; r++) {
                    float v = fmaf(sc[ct][r], scl, ajv);
                    if (!full) {
                        int i = si + quad * 4 + r;
                        if (j > i) v = -3.0e38f;
                    }
                    s2[ct][r] = v;
                }
            }
            u16* pcur = (t & 1) ? pwB : pwA;
            float alpha[4];
            bool any_resc = false;
            for (int r = 0; r < 4; r++) {
                float mr = fmaxf(fmaxf(s2[0][r], s2[1][r]), fmaxf(s2[2][r], s2[3][r]));
                mr = red16_max(mr);
                float mnew = fmaxf(m_i[r], mr);
                alpha[r] = exp2f(m_i[r] - mnew);
                any_resc |= (alpha[r] != 1.0f);
                m_i[r] = mnew;
                int row = quad * 4 + r;
                int rk = row & 7;
                for (int ct = 0; ct < 4; ct++) {
                    float p = exp2f(s2[ct][r] - mnew);
                    u16 pb = (u16)(__float_as_uint(p) >> 16);  // trunc; consistent num/denom
                    int sl = ct * 2 + (ln >> 3);
                    pcur[row * 64 + ((sl ^ rk) << 3) + (ln & 7)] = pb;
                }
            }
            // phase 5: rescale AFTER PV(t-1) has accumulated (sequence: +PV(t-1), *alpha(t))
            if (__any(any_resc)) {
                for (int dt = 0; dt < 8; dt++) {
                    f32x4 o = o_acc[dt];
                    for (int r = 0; r < 4; r++) o[r] *= alpha[r];
                    o_acc[dt] = o;
                }
                for (int r = 0; r < 4; r++) l_acc[r] *= alpha[r];
            }
            __syncthreads();   // drains staged K(t+1)/V(t) + all LDS traffic
        }

        // epilogue: PV(nt), then normalize (rcp), SiLU(p) gate, store bf16
        {
            const u16* vbp = &vt_s[(nt & 1) * 8192];
            const u16* pr = (nt & 1) ? pwB : pwA;
            __builtin_amdgcn_s_setprio(1);
            for (int ks = 0; ks < 2; ks++) {
                bf16x8 pa = *(const bf16x8*)&pr[ln * 64 + (((ks * 4 + quad) ^ (ln & 7)) << 3)];
                l_acc = __builtin_amdgcn_mfma_f32_16x16x32_bf16(pa, ones, l_acc, 0, 0, 0);
                for (int dt = 0; dt < 8; dt++) {
                    bf16x8 vf = *(const bf16x8*)&vbp[ks * 4096 + (dt * 16 + ln) * 32 + qsw];
                    o_acc[dt] = __builtin_amdgcn_mfma_f32_16x16x32_bf16(pa, vf, o_acc[dt], 0, 0, 0);
                }
            }
            __builtin_amdgcn_s_setprio(0);
        }

        float rinv[4];
        for (int r = 0; r < 4; r++) rinv[r] = __builtin_amdgcn_rcpf(l_acc[r]);
        for (int dt = 0; dt < 8; dt++)
            for (int r = 0; r < 4; r++) {
                int i = si + quad * 4 + r;
                int dcol = dt * 16 + ln;
                float o = o_acc[dt][r] * rinv[r];
                float pv = bf2f(qkvp[(tokb + i) * 8192 + 6144 + h * DH + dcol]);
                float gate = pv * __builtin_amdgcn_rcpf(1.0f + exp2f(-pv * LOG2E));
                ag2[(tokb + i) * 2048 + h * DH + dcol] = f2bf(gate * o);
            }
    }
}

extern "C" void kernel_launch(void* const* d_in, const int* in_sizes, int n_in,
                              void* d_out, int out_size, void* d_ws, size_t ws_size,
                              hipStream_t stream) {
    const float* x       = (const float*)d_in[0];
    const float* ln1_g   = (const float*)d_in[1];
    const float* ln1_b   = (const float*)d_in[2];
    const float* ln2_g   = (const float*)d_in[3];
    const float* ln2_b   = (const float*)d_in[4];
    const float* w_in    = (const float*)d_in[5];
    const float* w_out   = (const float*)d_in[6];
    const float* smear_f = (const float*)d_in[7];
    const float* logsc   = (const float*)d_in[8];
    float* out = (float*)d_out;
    char* ws = (char*)d_ws;

    // ws layout (bytes)
    u16* w_inT   = (u16*)(ws + 0);                       // 16 MB  [8192,1024]
    u16* w_outT  = (u16*)(ws + (size_t)16777216);        //  4 MB  [1024,2048]
    u16* lnA     = (u16*)(ws + (size_t)20971520);        //  8 MB  [4096,1024]
    u16* qkvp    = (u16*)(ws + (size_t)29360128);        // 64 MB  [4096,8192]
    u16* k_sm    = (u16*)(ws + (size_t)96468992);        // 16 MB  [bh][l][128]
    u16* ag2     = (u16*)(ws + (size_t)113246208);       // 16 MB  [4096,2048]
    float* out_pre = (float*)(ws + (size_t)96468992);    // alias k_sm (dead after attn)
    u16* v_t     = (u16*)(ws + 0);                       // alias w_inT (dead after gemm1)

    dim3 b32x8(32, 8);
    conv_transpose<<<dim3(8192 / 32, 1024 / 32), b32x8, 0, stream>>>(w_in, w_inT, 1024, 8192);
    conv_transpose<<<dim3(1024 / 32, 2048 / 32), b32x8, 0, stream>>>(w_out, w_outT, 2048, 1024);
    ln_fwd<<<NTOK, 256, 0, stream>>>(x, ln1_g, ln1_b, (void*)lnA, 1);
    gemm_bt<u16><<<dim3(8192 / 128, 4096 / 128), 256, 0, stream>>>(lnA, w_inT, qkvp, NTOK, 8192, 1024);
    smear_kernel<<<4096, 256, 0, stream>>>(qkvp, smear_f, k_sm);
    vT_kernel<<<dim3(L_SEQ / 32, DH / 32, 32), b32x8, 0, stream>>>(qkvp, v_t);
    attn_kernel<<<dim3(16, 32), 256, 0, stream>>>(qkvp, k_sm, v_t, ag2, logsc);
    gemm_bt<float><<<dim3(1024 / 128, 4096 / 128), 256, 0, stream>>>(ag2, w_outT, out_pre, NTOK, 1024, 2048);
    ln_fwd<<<NTOK, 256, 0, stream>>>(out_pre, ln2_g, ln2_b, (void*)out, 0);
}

// Round 7
// 363.768 us; speedup vs baseline: 1.1978x; 1.1978x over previous
//
#include <hip/hip_runtime.h>

typedef unsigned short u16;
typedef __attribute__((ext_vector_type(8))) short bf16x8;
typedef __attribute__((ext_vector_type(8))) unsigned short u16x8;
typedef __attribute__((ext_vector_type(4))) float f32x4;

#define L_SEQ 2048
#define NTOK 4096   // B*L
#define DMODEL 1024
#define DEXP 2048
#define NH 16
#define DH 128

__device__ __forceinline__ u16 f2bf(float f) {
    unsigned u = __float_as_uint(f);
    unsigned r = (u + 0x7FFFu + ((u >> 16) & 1u)) >> 16;
    return (u16)r;
}
__device__ __forceinline__ float bf2f(u16 h) {
    return __uint_as_float(((unsigned)h) << 16);
}

// DPP cross-lane (16-lane row) reduction helpers: VALU latency, no LDS.
template <int CTRL>
__device__ __forceinline__ float dpp_f(float x) {
    return __int_as_float(__builtin_amdgcn_update_dpp(0, __float_as_int(x), CTRL, 0xF, 0xF, true));
}
__device__ __forceinline__ float red16_max(float x) {
    x = fmaxf(x, dpp_f<0xB1>(x));   // quad_perm xor1
    x = fmaxf(x, dpp_f<0x4E>(x));   // quad_perm xor2
    x = fmaxf(x, dpp_f<0x124>(x));  // row_ror:4
    x = fmaxf(x, dpp_f<0x128>(x));  // row_ror:8
    return x;
}

// async global->LDS, 16B per lane; LDS dest = wave-uniform base + lane*16
__device__ __forceinline__ void gl_lds16(const u16* g, u16* l) {
    __builtin_amdgcn_global_load_lds((const __attribute__((address_space(1))) void*)g,
                                     (__attribute__((address_space(3))) void*)l, 16, 0, 0);
}

// ---------------- convert + transpose fp32 -> bf16, out[c*R + r] = in[r*C + c]
__global__ void conv_transpose(const float* __restrict__ in, u16* __restrict__ out, int R, int C) {
    __shared__ unsigned tile[32][33];
    int c0 = blockIdx.x * 32, r0 = blockIdx.y * 32;
    int tx = threadIdx.x, ty = threadIdx.y;
    for (int j = 0; j < 32; j += 8)
        tile[ty + j][tx] = (unsigned)f2bf(in[(size_t)(r0 + ty + j) * C + c0 + tx]);
    __syncthreads();
    for (int j = 0; j < 32; j += 8)
        out[(size_t)(c0 + ty + j) * R + r0 + tx] = (u16)tile[tx][ty + j];
}

// ---------------- layernorm over 1024, out bf16 or fp32
__global__ __launch_bounds__(256) void ln_fwd(const float* __restrict__ x, const float* __restrict__ g,
                                              const float* __restrict__ bta, void* __restrict__ outp,
                                              int out_bf16) {
    int row = blockIdx.x;
    int t = threadIdx.x;
    const float* xr = x + (size_t)row * DMODEL;
    float4 xv = *(const float4*)&xr[t * 4];
    float s = xv.x + xv.y + xv.z + xv.w;
    float s2 = xv.x * xv.x + xv.y * xv.y + xv.z * xv.z + xv.w * xv.w;
    for (int off = 32; off >= 1; off >>= 1) {
        s += __shfl_xor(s, off);
        s2 += __shfl_xor(s2, off);
    }
    __shared__ float red[10];
    int w = t >> 6;
    if ((t & 63) == 0) { red[w] = s; red[4 + w] = s2; }
    __syncthreads();
    if (t == 0) {
        red[8] = red[0] + red[1] + red[2] + red[3];
        red[9] = red[4] + red[5] + red[6] + red[7];
    }
    __syncthreads();
    float mu = red[8] * (1.0f / DMODEL);
    float var = red[9] * (1.0f / DMODEL) - mu * mu;
    float rstd = rsqrtf(var + 1e-5f);
    float vals[4] = {xv.x, xv.y, xv.z, xv.w};
    for (int e = 0; e < 4; e++) {
        int c = t * 4 + e;
        float y = (vals[e] - mu) * rstd * g[c] + bta[c];
        if (out_bf16) ((u16*)outp)[(size_t)row * DMODEL + c] = f2bf(y);
        else          ((float*)outp)[(size_t)row * DMODEL + c] = y;
    }
}

// ---------------- GEMM (128^2, 2-phase): C[M,N] = A[M,K](bf16)*B, B as BT[N,K]
__device__ __forceinline__ void store_out(u16* C, size_t idx, float v) { C[idx] = f2bf(v); }
__device__ __forceinline__ void store_out(float* C, size_t idx, float v) { C[idx] = v; }

template <typename OutT>
__global__ __launch_bounds__(256) void gemm_bt(const u16* __restrict__ A, const u16* __restrict__ BT,
                                               OutT* __restrict__ C, int M, int N, int K) {
    __shared__ u16 a_s[2][4096];   // dbuf x 128 rows x 32 k (16-row chunks)
    __shared__ u16 b_s[2][4096];
    int tid = threadIdx.x;
    unsigned NX = gridDim.x;
    unsigned lin = blockIdx.x + NX * blockIdx.y;
    unsigned per = NX >> 3;                 // N-panels per XCD (NX % 8 == 0)
    unsigned xcd = lin & 7, t = lin >> 3;
    unsigned n_p = xcd * per + (t % per);
    unsigned m_p = t / per;
    int m0 = m_p * 128, n0 = n_p * 128;
    int w = tid >> 6, lane = tid & 63, quad = lane >> 4, ln = lane & 15;
    int wr = (w >> 1) * 64, wc = (w & 1) * 64;
    f32x4 zero4 = {0.f, 0.f, 0.f, 0.f};
    f32x4 acc[4][4];
    for (int r = 0; r < 4; r++)
        for (int c = 0; c < 4; c++) acc[r][c] = zero4;

    int lrow = lane >> 2, lseg = (lane & 3) * 8;
    const u16* Ag0 = A + (size_t)(m0 + 32 * w + lrow) * K + lseg;
    const u16* Ag1 = Ag0 + (size_t)16 * K;
    const u16* Bg0 = BT + (size_t)(n0 + 32 * w + lrow) * K + lseg;
    const u16* Bg1 = Bg0 + (size_t)16 * K;
    int lo0 = (2 * w) * 512, lo1 = (2 * w + 1) * 512;

    gl_lds16(Ag0, &a_s[0][lo0]);
    gl_lds16(Ag1, &a_s[0][lo1]);
    gl_lds16(Bg0, &b_s[0][lo0]);
    gl_lds16(Bg1, &b_s[0][lo1]);
    __syncthreads();

    int cur = 0;
    for (int k0 = 0; k0 < K; k0 += 32) {
        if (k0 + 32 < K) {
            int nb = cur ^ 1;
            gl_lds16(Ag0 + k0 + 32, &a_s[nb][lo0]);
            gl_lds16(Ag1 + k0 + 32, &a_s[nb][lo1]);
            gl_lds16(Bg0 + k0 + 32, &b_s[nb][lo0]);
            gl_lds16(Bg1 + k0 + 32, &b_s[nb][lo1]);
        }
        bf16x8 af[4], bfr[4];
        for (int r = 0; r < 4; r++) af[r]  = *(const bf16x8*)&a_s[cur][(wr + r * 16 + ln) * 32 + quad * 8];
        for (int c = 0; c < 4; c++) bfr[c] = *(const bf16x8*)&b_s[cur][(wc + c * 16 + ln) * 32 + quad * 8];
        __builtin_amdgcn_s_setprio(1);
        for (int r = 0; r < 4; r++)
            for (int c = 0; c < 4; c++)
                acc[r][c] = __builtin_amdgcn_mfma_f32_16x16x32_bf16(af[r], bfr[c], acc[r][c], 0, 0, 0);
        __builtin_amdgcn_s_setprio(0);
        __syncthreads();
        cur ^= 1;
    }
    for (int r = 0; r < 4; r++)
        for (int c = 0; c < 4; c++)
            for (int e = 0; e < 4; e++) {
                int row = m0 + wr + r * 16 + quad * 4 + e;
                int col = n0 + wc + c * 16 + ln;
                store_out(C, (size_t)row * N + col, acc[r][c][e]);
            }
}

// ---------------- smear: k_sm[bh][l][d] = (1-s)*k + s*k_prev  (head-major layout)
__global__ __launch_bounds__(256) void smear_kernel(const u16* __restrict__ qkvp,
                                                    const float* __restrict__ smear_f,
                                                    u16* __restrict__ k_sm) {
    int gid = blockIdx.x * 256 + threadIdx.x;
    int base = gid * 8;
    int bl = base >> 11;       // token index
    int c = base & 2047;
    int h = c >> 7;
    int d = c & 127;
    int l = bl & (L_SEQ - 1);
    int bb = bl >> 11;
    float s = 1.0f / (1.0f + __expf(-smear_f[h]));
    u16x8 cur = *(const u16x8*)&qkvp[(size_t)bl * 8192 + 2048 + c];
    u16x8 prv = {0, 0, 0, 0, 0, 0, 0, 0};
    if (l > 0) prv = *(const u16x8*)&qkvp[(size_t)(bl - 1) * 8192 + 2048 + c];
    u16x8 outv;
    for (int u = 0; u < 8; u++) {
        float kc = bf2f(cur[u]);
        float kp = bf2f(prv[u]);
        outv[u] = f2bf((1.0f - s) * kc + s * kp);
    }
    *(u16x8*)&k_sm[(((size_t)(bb * 16 + h)) * L_SEQ + l) * DH + d] = outv;
}

// ---------------- per-(b,h) transpose of V: v_t[bh,d,l] = qkvp[tok, 4096 + h*128 + d]
__global__ void vT_kernel(const u16* __restrict__ qkvp, u16* __restrict__ v_t) {
    __shared__ unsigned tile[32][33];
    int l0 = blockIdx.x * 32, d0 = blockIdx.y * 32;
    int bh = blockIdx.z;
    int bb = bh >> 4, h = bh & 15;
    int tx = threadIdx.x, ty = threadIdx.y;
    size_t tokb = (size_t)bb * L_SEQ;
    for (int j = 0; j < 32; j += 8)
        tile[ty + j][tx] = (unsigned)qkvp[(tokb + l0 + ty + j) * 8192 + 4096 + h * DH + d0 + tx];
    __syncthreads();
    for (int j = 0; j < 32; j += 8)
        v_t[((size_t)bh * DH + d0 + ty + j) * L_SEQ + l0 + tx] = (u16)tile[tx][ty + j];
}

// ---------------- flash attention + SiLU(p) gating
// Round-14: r6's tile pipeline (QK(t) -> PV(t-1) -> softmax(t) -> rescale) at
// r4's MEASURED-2-blocks/CU LDS budget: 74752 B. r6's 81920 B silently dropped
// to 1 block/CU (occupancy 11%) and regressed 1.7x -- size to the measured
// limit, not the spec limit. Single P buffer (per-wave private; DS ops from one
// wave are processed in order, so PV(t-1)'s reads of pw are serviced before
// softmax(t)'s overwrites). V staged with one-tile stagger into the V dbuf.
// O/l update sequence identical to serial version -> same absmax.
__global__ __launch_bounds__(256) void attn_kernel(const u16* __restrict__ qkvp,
                                                   const u16* __restrict__ k_sm,
                                                   const u16* __restrict__ v_t,
                                                   u16* __restrict__ ag2,
                                                   const float* __restrict__ log_scale) {
    __shared__ u16 k_s[16384];   // 2 bufs x [kt 0..3][jrow 0..63][32 k] (swizzled content)
    __shared__ u16 vt_s[16384];  // 2 bufs x [jt 0..1][d 0..127][32 j]  (swizzled content)
    __shared__ u16 p_s[4608];    // per-wave 16 x 72 (single buffer)
    int tid = threadIdx.x;
    // XCD clustering: lin%8 = XCD (round-robin dispatch); 4 heads per XCD.
    unsigned lin = blockIdx.x + 16u * blockIdx.y;
    unsigned xcd = lin & 7, tt = lin >> 3;
    int bh = (int)(xcd * 4 + (tt & 3));
    int pair = (int)(tt >> 2);
    int bb = bh >> 4, h = bh & 15;
    int w = tid >> 6, lane = tid & 63, quad = lane >> 4, ln = lane & 15;
    size_t tokb = (size_t)bb * L_SEQ;

    const float LOG2E = 1.44269504f;
    float inv = 1.0f / (__expf(2.0f * log_scale[h]) * sqrtf((float)DH));
    float scl = inv * LOG2E;
    float slope2 = ((h < 8) ? exp2f(-8.0f * (float)h / 7.0f) : 0.0f) * LOG2E;

    int lrow = lane >> 2, lcol = lane & 3;
    int lsw8 = (lcol ^ ((lrow >> 1) & 3)) * 8;  // write-side swizzle via global source addr
    int qsw = (quad ^ ((ln >> 1) & 3)) * 8;     // read-side swizzle (same involution)
    f32x4 zero4 = {0.f, 0.f, 0.f, 0.f};
    u16* pw = &p_s[w * 1152];
    const short ONE_BF = (short)0x3F80;
    bf16x8 ones = {ONE_BF, ONE_BF, ONE_BF, ONE_BF, ONE_BF, ONE_BF, ONE_BF, ONE_BF};

    for (int sidx = 0; sidx < 2; sidx++) {
        int ib = sidx == 0 ? (31 - pair) : pair;
        int i0 = ib * 64;
        int si = i0 + w * 16;
        int nt = i0 >> 6;   // tiles t = 0..nt

        // Q fragments straight from global (A-layout: m=ln, k=quad*8+..)
        bf16x8 qf[4];
        for (int kt = 0; kt < 4; kt++)
            qf[kt] = *(const bf16x8*)&qkvp[(tokb + si + ln) * 8192 + h * DH + kt * 32 + quad * 8];

        float m_i[4];
        for (int r = 0; r < 4; r++) m_i[r] = -1e30f;
        f32x4 o_acc[8], l_acc;
        for (int dt = 0; dt < 8; dt++) o_acc[dt] = zero4;
        l_acc = zero4;

        // staging pointers: advance by constant per staged tile (pre-swizzled source)
        const u16* kg[4];
        for (int g = 0; g < 4; g++)
            kg[g] = k_sm + ((size_t)bh * L_SEQ + g * 16 + lrow) * DH + w * 32 + lsw8;
        const u16* vg[4];
        int vloff[4];
        for (int q = 0; q < 4; q++) {
            int c = w * 4 + q;
            int jt = c >> 3, dg = c & 7;
            vg[q] = v_t + ((size_t)bh * DH + dg * 16 + lrow) * L_SEQ + jt * 32 + lsw8;
            vloff[q] = jt * 4096 + dg * 512;
        }

        // prologue: stage K(0) into kbuf[0]
        for (int g = 0; g < 4; g++) { gl_lds16(kg[g], &k_s[w * 2048 + g * 512]); kg[g] += 64 * DH; }
        __syncthreads();

        for (int t = 0; t <= nt; t++) {
            int j0 = t << 6;
            // phase 1: stage K(t+1) -> kbuf[(t+1)&1]; stage V(t) -> vbuf[t&1]
            if (t < nt) {
                int nb = ((t + 1) & 1) * 8192;
                for (int g = 0; g < 4; g++) { gl_lds16(kg[g], &k_s[nb + w * 2048 + g * 512]); kg[g] += 64 * DH; }
            }
            {
                int vb_ = (t & 1) * 8192;
                for (int q = 0; q < 4; q++) { gl_lds16(vg[q], &vt_s[vb_ + vloff[q]]); vg[q] += 64; }
            }
            const u16* kb = &k_s[(t & 1) * 8192];

            // phase 2: QK(t): 16 rows x 64 cols per wave
            f32x4 sc[4];
            for (int ct = 0; ct < 4; ct++) sc[ct] = zero4;
            __builtin_amdgcn_s_setprio(1);
            for (int kt = 0; kt < 4; kt++)
                for (int ct = 0; ct < 4; ct++) {
                    bf16x8 bfr = *(const bf16x8*)&kb[kt * 2048 + (ct * 16 + ln) * 32 + qsw];
                    sc[ct] = __builtin_amdgcn_mfma_f32_16x16x32_bf16(qf[kt], bfr, sc[ct], 0, 0, 0);
                }
            __builtin_amdgcn_s_setprio(0);

            // phase 3: PV(t-1) -- independent of softmax(t); MFMA drains under it.
            // Reads pw (written at t-1; barrier since) and vbuf[(t-1)&1].
            if (t > 0) {
                const u16* vbp = &vt_s[((t - 1) & 1) * 8192];
                __builtin_amdgcn_s_setprio(1);
                for (int ks = 0; ks < 2; ks++) {
                    bf16x8 pa = *(const bf16x8*)&pw[ln * 72 + ks * 32 + quad * 8];
                    l_acc = __builtin_amdgcn_mfma_f32_16x16x32_bf16(pa, ones, l_acc, 0, 0, 0);
                    for (int dt = 0; dt < 8; dt++) {
                        bf16x8 vf = *(const bf16x8*)&vbp[ks * 4096 + (dt * 16 + ln) * 32 + qsw];
                        o_acc[dt] = __builtin_amdgcn_mfma_f32_16x16x32_bf16(pa, vf, o_acc[dt], 0, 0, 0);
                    }
                }
                __builtin_amdgcn_s_setprio(0);
            }

            // phase 4: softmax(t) from sc; write P(t) into pw (in-order DS: the
            // PV reads above are serviced before these writes land)
            bool full = (j0 + 63 <= si);
            float s2[4][4];
            float aj0 = slope2 * (float)(j0 + ln);
            for (int ct = 0; ct < 4; ct++) {
                float ajv = aj0 + slope2 * (float)(16 * ct);
                int j = j0 + ct * 16 + ln;
                for (int r = 0; r < 4; r++) {
                    float v = fmaf(sc[ct][r], scl, ajv);
                    if (!full) {
                        int i = si + quad * 4 + r;
                        if (j > i) v = -3.0e38f;
                    }
                    s2[ct][r] = v;
                }
            }
            float alpha[4];
            bool any_resc = false;
            for (int r = 0; r < 4; r++) {
                float mr = fmaxf(fmaxf(s2[0][r], s2[1][r]), fmaxf(s2[2][r], s2[3][r]));
                mr = red16_max(mr);
                float mnew = fmaxf(m_i[r], mr);
                alpha[r] = exp2f(m_i[r] - mnew);
                any_resc |= (alpha[r] != 1.0f);
                m_i[r] = mnew;
                for (int ct = 0; ct < 4; ct++) {
                    float p = exp2f(s2[ct][r] - mnew);
                    u16 pb = (u16)(__float_as_uint(p) >> 16);  // trunc; consistent num/denom
                    pw[(quad * 4 + r) * 72 + ct * 16 + ln] = pb;
                }
            }
            // phase 5: rescale AFTER PV(t-1) accumulated (sequence: +PV(t-1), *alpha(t))
            if (__any(any_resc)) {
                for (int dt = 0; dt < 8; dt++) {
                    f32x4 o = o_acc[dt];
                    for (int r = 0; r < 4; r++) o[r] *= alpha[r];
                    o_acc[dt] = o;
                }
                for (int r = 0; r < 4; r++) l_acc[r] *= alpha[r];
            }
            __syncthreads();   // drains staged K(t+1)/V(t) + P writes
        }

        // epilogue: PV(nt), then normalize (rcp), SiLU(p) gate, store bf16
        {
            const u16* vbp = &vt_s[(nt & 1) * 8192];
            __builtin_amdgcn_s_setprio(1);
            for (int ks = 0; ks < 2; ks++) {
                bf16x8 pa = *(const bf16x8*)&pw[ln * 72 + ks * 32 + quad * 8];
                l_acc = __builtin_amdgcn_mfma_f32_16x16x32_bf16(pa, ones, l_acc, 0, 0, 0);
                for (int dt = 0; dt < 8; dt++) {
                    bf16x8 vf = *(const bf16x8*)&vbp[ks * 4096 + (dt * 16 + ln) * 32 + qsw];
                    o_acc[dt] = __builtin_amdgcn_mfma_f32_16x16x32_bf16(pa, vf, o_acc[dt], 0, 0, 0);
                }
            }
            __builtin_amdgcn_s_setprio(0);
        }

        float rinv[4];
        for (int r = 0; r < 4; r++) rinv[r] = __builtin_amdgcn_rcpf(l_acc[r]);
        for (int dt = 0; dt < 8; dt++)
            for (int r = 0; r < 4; r++) {
                int i = si + quad * 4 + r;
                int dcol = dt * 16 + ln;
                float o = o_acc[dt][r] * rinv[r];
                float pv = bf2f(qkvp[(tokb + i) * 8192 + 6144 + h * DH + dcol]);
                float gate = pv * __builtin_amdgcn_rcpf(1.0f + exp2f(-pv * LOG2E));
                ag2[(tokb + i) * 2048 + h * DH + dcol] = f2bf(gate * o);
            }
    }
}

extern "C" void kernel_launch(void* const* d_in, const int* in_sizes, int n_in,
                              void* d_out, int out_size, void* d_ws, size_t ws_size,
                              hipStream_t stream) {
    const float* x       = (const float*)d_in[0];
    const float* ln1_g   = (const float*)d_in[1];
    const float* ln1_b   = (const float*)d_in[2];
    const float* ln2_g   = (const float*)d_in[3];
    const float* ln2_b   = (const float*)d_in[4];
    const float* w_in    = (const float*)d_in[5];
    const float* w_out   = (const float*)d_in[6];
    const float* smear_f = (const float*)d_in[7];
    const float* logsc   = (const float*)d_in[8];
    float* out = (float*)d_out;
    char* ws = (char*)d_ws;

    // ws layout (bytes)
    u16* w_inT   = (u16*)(ws + 0);                       // 16 MB  [8192,1024]
    u16* w_outT  = (u16*)(ws + (size_t)16777216);        //  4 MB  [1024,2048]
    u16* lnA     = (u16*)(ws + (size_t)20971520);        //  8 MB  [4096,1024]
    u16* qkvp    = (u16*)(ws + (size_t)29360128);        // 64 MB  [4096,8192]
    u16* k_sm    = (u16*)(ws + (size_t)96468992);        // 16 MB  [bh][l][128]
    u16* ag2     = (u16*)(ws + (size_t)113246208);       // 16 MB  [4096,2048]
    float* out_pre = (float*)(ws + (size_t)96468992);    // alias k_sm (dead after attn)
    u16* v_t     = (u16*)(ws + 0);                       // alias w_inT (dead after gemm1)

    dim3 b32x8(32, 8);
    conv_transpose<<<dim3(8192 / 32, 1024 / 32), b32x8, 0, stream>>>(w_in, w_inT, 1024, 8192);
    conv_transpose<<<dim3(1024 / 32, 2048 / 32), b32x8, 0, stream>>>(w_out, w_outT, 2048, 1024);
    ln_fwd<<<NTOK, 256, 0, stream>>>(x, ln1_g, ln1_b, (void*)lnA, 1);
    gemm_bt<u16><<<dim3(8192 / 128, 4096 / 128), 256, 0, stream>>>(lnA, w_inT, qkvp, NTOK, 8192, 1024);
    smear_kernel<<<4096, 256, 0, stream>>>(qkvp, smear_f, k_sm);
    vT_kernel<<<dim3(L_SEQ / 32, DH / 32, 32), b32x8, 0, stream>>>(qkvp, v_t);
    attn_kernel<<<dim3(16, 32), 256, 0, stream>>>(qkvp, k_sm, v_t, ag2, logsc);
    gemm_bt<float><<<dim3(1024 / 128, 4096 / 128), 256, 0, stream>>>(ag2, w_outT, out_pre, NTOK, 1024, 2048);
    ln_fwd<<<NTOK, 256, 0, stream>>>(out_pre, ln2_g, ln2_b, (void*)out, 0);
}

// Round 8
// 358.183 us; speedup vs baseline: 1.2165x; 1.0156x over previous
//
#include <hip/hip_runtime.h>

typedef unsigned short u16;
typedef __attribute__((ext_vector_type(8))) short bf16x8;
typedef __attribute__((ext_vector_type(8))) unsigned short u16x8;
typedef __attribute__((ext_vector_type(4))) float f32x4;

#define L_SEQ 2048
#define NTOK 4096   // B*L
#define DMODEL 1024
#define DEXP 2048
#define NH 16
#define DH 128

__device__ __forceinline__ u16 f2bf(float f) {
    unsigned u = __float_as_uint(f);
    unsigned r = (u + 0x7FFFu + ((u >> 16) & 1u)) >> 16;
    return (u16)r;
}
__device__ __forceinline__ float bf2f(u16 h) {
    return __uint_as_float(((unsigned)h) << 16);
}

// async global->LDS, 16B per lane; LDS dest = wave-uniform base + lane*16
__device__ __forceinline__ void gl_lds16(const u16* g, u16* l) {
    __builtin_amdgcn_global_load_lds((const __attribute__((address_space(1))) void*)g,
                                     (__attribute__((address_space(3))) void*)l, 16, 0, 0);
}

// ---------------- convert + transpose fp32 -> bf16, out[c*R + r] = in[r*C + c]
__global__ void conv_transpose(const float* __restrict__ in, u16* __restrict__ out, int R, int C) {
    __shared__ unsigned tile[32][33];
    int c0 = blockIdx.x * 32, r0 = blockIdx.y * 32;
    int tx = threadIdx.x, ty = threadIdx.y;
    for (int j = 0; j < 32; j += 8)
        tile[ty + j][tx] = (unsigned)f2bf(in[(size_t)(r0 + ty + j) * C + c0 + tx]);
    __syncthreads();
    for (int j = 0; j < 32; j += 8)
        out[(size_t)(c0 + ty + j) * R + r0 + tx] = (u16)tile[tx][ty + j];
}

// ---------------- layernorm over 1024, out bf16 or fp32
__global__ __launch_bounds__(256) void ln_fwd(const float* __restrict__ x, const float* __restrict__ g,
                                              const float* __restrict__ bta, void* __restrict__ outp,
                                              int out_bf16) {
    int row = blockIdx.x;
    int t = threadIdx.x;
    const float* xr = x + (size_t)row * DMODEL;
    float4 xv = *(const float4*)&xr[t * 4];
    float s = xv.x + xv.y + xv.z + xv.w;
    float s2 = xv.x * xv.x + xv.y * xv.y + xv.z * xv.z + xv.w * xv.w;
    for (int off = 32; off >= 1; off >>= 1) {
        s += __shfl_xor(s, off);
        s2 += __shfl_xor(s2, off);
    }
    __shared__ float red[10];
    int w = t >> 6;
    if ((t & 63) == 0) { red[w] = s; red[4 + w] = s2; }
    __syncthreads();
    if (t == 0) {
        red[8] = red[0] + red[1] + red[2] + red[3];
        red[9] = red[4] + red[5] + red[6] + red[7];
    }
    __syncthreads();
    float mu = red[8] * (1.0f / DMODEL);
    float var = red[9] * (1.0f / DMODEL) - mu * mu;
    float rstd = rsqrtf(var + 1e-5f);
    float vals[4] = {xv.x, xv.y, xv.z, xv.w};
    for (int e = 0; e < 4; e++) {
        int c = t * 4 + e;
        float y = (vals[e] - mu) * rstd * g[c] + bta[c];
        if (out_bf16) ((u16*)outp)[(size_t)row * DMODEL + c] = f2bf(y);
        else          ((float*)outp)[(size_t)row * DMODEL + c] = y;
    }
}

// ---------------- GEMM (128^2, 2-phase): C[M,N] = A[M,K](bf16)*B, B as BT[N,K]
__device__ __forceinline__ void store_out(u16* C, size_t idx, float v) { C[idx] = f2bf(v); }
__device__ __forceinline__ void store_out(float* C, size_t idx, float v) { C[idx] = v; }

template <typename OutT>
__global__ __launch_bounds__(256) void gemm_bt(const u16* __restrict__ A, const u16* __restrict__ BT,
                                               OutT* __restrict__ C, int M, int N, int K) {
    __shared__ u16 a_s[2][4096];   // dbuf x 128 rows x 32 k (16-row chunks)
    __shared__ u16 b_s[2][4096];
    int tid = threadIdx.x;
    unsigned NX = gridDim.x;
    unsigned lin = blockIdx.x + NX * blockIdx.y;
    unsigned per = NX >> 3;                 // N-panels per XCD (NX % 8 == 0)
    unsigned xcd = lin & 7, t = lin >> 3;
    unsigned n_p = xcd * per + (t % per);
    unsigned m_p = t / per;
    int m0 = m_p * 128, n0 = n_p * 128;
    int w = tid >> 6, lane = tid & 63, quad = lane >> 4, ln = lane & 15;
    int wr = (w >> 1) * 64, wc = (w & 1) * 64;
    f32x4 zero4 = {0.f, 0.f, 0.f, 0.f};
    f32x4 acc[4][4];
    for (int r = 0; r < 4; r++)
        for (int c = 0; c < 4; c++) acc[r][c] = zero4;

    int lrow = lane >> 2, lseg = (lane & 3) * 8;
    const u16* Ag0 = A + (size_t)(m0 + 32 * w + lrow) * K + lseg;
    const u16* Ag1 = Ag0 + (size_t)16 * K;
    const u16* Bg0 = BT + (size_t)(n0 + 32 * w + lrow) * K + lseg;
    const u16* Bg1 = Bg0 + (size_t)16 * K;
    int lo0 = (2 * w) * 512, lo1 = (2 * w + 1) * 512;

    gl_lds16(Ag0, &a_s[0][lo0]);
    gl_lds16(Ag1, &a_s[0][lo1]);
    gl_lds16(Bg0, &b_s[0][lo0]);
    gl_lds16(Bg1, &b_s[0][lo1]);
    __syncthreads();

    int cur = 0;
    for (int k0 = 0; k0 < K; k0 += 32) {
        if (k0 + 32 < K) {
            int nb = cur ^ 1;
            gl_lds16(Ag0 + k0 + 32, &a_s[nb][lo0]);
            gl_lds16(Ag1 + k0 + 32, &a_s[nb][lo1]);
            gl_lds16(Bg0 + k0 + 32, &b_s[nb][lo0]);
            gl_lds16(Bg1 + k0 + 32, &b_s[nb][lo1]);
        }
        bf16x8 af[4], bfr[4];
        for (int r = 0; r < 4; r++) af[r]  = *(const bf16x8*)&a_s[cur][(wr + r * 16 + ln) * 32 + quad * 8];
        for (int c = 0; c < 4; c++) bfr[c] = *(const bf16x8*)&b_s[cur][(wc + c * 16 + ln) * 32 + quad * 8];
        __builtin_amdgcn_s_setprio(1);
        for (int r = 0; r < 4; r++)
            for (int c = 0; c < 4; c++)
                acc[r][c] = __builtin_amdgcn_mfma_f32_16x16x32_bf16(af[r], bfr[c], acc[r][c], 0, 0, 0);
        __builtin_amdgcn_s_setprio(0);
        __syncthreads();
        cur ^= 1;
    }
    for (int r = 0; r < 4; r++)
        for (int c = 0; c < 4; c++)
            for (int e = 0; e < 4; e++) {
                int row = m0 + wr + r * 16 + quad * 4 + e;
                int col = n0 + wc + c * 16 + ln;
                store_out(C, (size_t)row * N + col, acc[r][c][e]);
            }
}

// ---------------- smear: k_sm[bh][l][d] = (1-s)*k + s*k_prev  (head-major layout)
__global__ __launch_bounds__(256) void smear_kernel(const u16* __restrict__ qkvp,
                                                    const float* __restrict__ smear_f,
                                                    u16* __restrict__ k_sm) {
    int gid = blockIdx.x * 256 + threadIdx.x;
    int base = gid * 8;
    int bl = base >> 11;       // token index
    int c = base & 2047;
    int h = c >> 7;
    int d = c & 127;
    int l = bl & (L_SEQ - 1);
    int bb = bl >> 11;
    float s = 1.0f / (1.0f + __expf(-smear_f[h]));
    u16x8 cur = *(const u16x8*)&qkvp[(size_t)bl * 8192 + 2048 + c];
    u16x8 prv = {0, 0, 0, 0, 0, 0, 0, 0};
    if (l > 0) prv = *(const u16x8*)&qkvp[(size_t)(bl - 1) * 8192 + 2048 + c];
    u16x8 outv;
    for (int u = 0; u < 8; u++) {
        float kc = bf2f(cur[u]);
        float kp = bf2f(prv[u]);
        outv[u] = f2bf((1.0f - s) * kc + s * kp);
    }
    *(u16x8*)&k_sm[(((size_t)(bb * 16 + h)) * L_SEQ + l) * DH + d] = outv;
}

// ---------------- per-(b,h) transpose of V: v_t[bh,d,l] = qkvp[tok, 4096 + h*128 + d]
__global__ void vT_kernel(const u16* __restrict__ qkvp, u16* __restrict__ v_t) {
    __shared__ unsigned tile[32][33];
    int l0 = blockIdx.x * 32, d0 = blockIdx.y * 32;
    int bh = blockIdx.z;
    int bb = bh >> 4, h = bh & 15;
    int tx = threadIdx.x, ty = threadIdx.y;
    size_t tokb = (size_t)bb * L_SEQ;
    for (int j = 0; j < 32; j += 8)
        tile[ty + j][tx] = (unsigned)qkvp[(tokb + l0 + ty + j) * 8192 + 4096 + h * DH + d0 + tx];
    __syncthreads();
    for (int j = 0; j < 32; j += 8)
        v_t[((size_t)bh * DH + d0 + ty + j) * L_SEQ + l0 + tx] = (u16)tile[tx][ty + j];
}

// ---------------- flash attention + SiLU(p) gating
// Round-15: r4 serial structure (pipeline reverted: measured 106.6 vs 102) +
// SWAPPED-OPERAND QK^T. mfma(K_frag, Q_frag) uses the SAME register data as
// mfma(Q_frag, K_frag) (A-frag and B-frag lane layouts coincide here) but
// transposes the output: each lane owns ONE q-row (ln) and 16 k-cols
// (ct*16+quad*4+r). Softmax becomes: 15-fmax lane-local tree + 2 shfl_xor
// (was 4x 8-op DPP chains), per-lane scalar m/alpha (was 4), and P written as
// 4 packed ds_write_b64 (was 16 ds_write_b16; trunc pack preserved -> bitwise
// identical numerics). Cost: ALiBi addend table (+16 adds/tile, zero-slope
// heads pay ~nothing) and 4 __shfl to gather alpha for the rescale.
// PV, staging, K/V dbuf, swizzles, XCD clustering unchanged.
__global__ __launch_bounds__(256) void attn_kernel(const u16* __restrict__ qkvp,
                                                   const u16* __restrict__ k_sm,
                                                   const u16* __restrict__ v_t,
                                                   u16* __restrict__ ag2,
                                                   const float* __restrict__ log_scale) {
    __shared__ u16 k_s[16384];   // 2 bufs x [kt 0..3][jrow 0..63][32 k] (swizzled content)
    __shared__ u16 vt_s[16384];  // 2 bufs x [jt 0..1][d 0..127][32 j]  (swizzled content)
    __shared__ u16 p_s[4608];    // per-wave 16 x 72 (single buffer)
    int tid = threadIdx.x;
    // XCD clustering: lin%8 = XCD (round-robin dispatch); 4 heads per XCD.
    unsigned lin = blockIdx.x + 16u * blockIdx.y;
    unsigned xcd = lin & 7, tt = lin >> 3;
    int bh = (int)(xcd * 4 + (tt & 3));
    int pair = (int)(tt >> 2);
    int bb = bh >> 4, h = bh & 15;
    int w = tid >> 6, lane = tid & 63, quad = lane >> 4, ln = lane & 15;
    size_t tokb = (size_t)bb * L_SEQ;

    const float LOG2E = 1.44269504f;
    float inv = 1.0f / (__expf(2.0f * log_scale[h]) * sqrtf((float)DH));
    float scl = inv * LOG2E;
    float slope2 = ((h < 8) ? exp2f(-8.0f * (float)h / 7.0f) : 0.0f) * LOG2E;

    int lrow = lane >> 2, lcol = lane & 3;
    int lsw8 = (lcol ^ ((lrow >> 1) & 3)) * 8;  // write-side swizzle via global source addr
    int qsw = (quad ^ ((ln >> 1) & 3)) * 8;     // read-side swizzle (same involution)
    f32x4 zero4 = {0.f, 0.f, 0.f, 0.f};
    u16* pw = &p_s[w * 1152];
    const short ONE_BF = (short)0x3F80;
    bf16x8 ones = {ONE_BF, ONE_BF, ONE_BF, ONE_BF, ONE_BF, ONE_BF, ONE_BF, ONE_BF};

    for (int sidx = 0; sidx < 2; sidx++) {
        int ib = sidx == 0 ? (31 - pair) : pair;
        int i0 = ib * 64;
        int si = i0 + w * 16;
        int iq = si + ln;          // this lane's q-row (swapped layout)

        // Q fragments straight from global (same data serves as B-operand now)
        bf16x8 qf[4];
        for (int kt = 0; kt < 4; kt++)
            qf[kt] = *(const bf16x8*)&qkvp[(tokb + si + ln) * 8192 + h * DH + kt * 32 + quad * 8];

        float m_i = -1e30f;        // per-lane scalar (one q-row per lane)
        f32x4 o_acc[8], l_acc;
        for (int dt = 0; dt < 8; dt++) o_acc[dt] = zero4;
        l_acc = zero4;

        // ALiBi addend table: adt[ct][r] = slope2 * (j0 + ct*16 + quad*4 + r), j0=0
        float adt[4][4];
        for (int ct = 0; ct < 4; ct++)
            for (int r = 0; r < 4; r++)
                adt[ct][r] = slope2 * (float)(ct * 16 + quad * 4 + r);
        float astep = slope2 * 64.0f;

        // staging pointers: advance by constant per j-tile (pre-swizzled source)
        const u16* kg[4];
        for (int g = 0; g < 4; g++)
            kg[g] = k_sm + ((size_t)bh * L_SEQ + g * 16 + lrow) * DH + w * 32 + lsw8;
        const u16* vg[4];
        int vloff[4];
        for (int q = 0; q < 4; q++) {
            int c = w * 4 + q;
            int jt = c >> 3, dg = c & 7;
            vg[q] = v_t + ((size_t)bh * DH + dg * 16 + lrow) * L_SEQ + jt * 32 + lsw8;
            vloff[q] = jt * 4096 + dg * 512;
        }

        // prologue: stage j-tile 0 into buffer 0
        for (int g = 0; g < 4; g++) { gl_lds16(kg[g], &k_s[w * 2048 + g * 512]); kg[g] += 64 * DH; }
        for (int q = 0; q < 4; q++) { gl_lds16(vg[q], &vt_s[vloff[q]]); vg[q] += 64; }
        __syncthreads();

        int cur = 0;
        for (int j0 = 0; j0 <= i0; j0 += 64) {
            // stage NEXT tile into the other buffer; in flight across compute
            if (j0 + 64 <= i0) {
                int nb = (cur ^ 1) * 8192;
                for (int g = 0; g < 4; g++) { gl_lds16(kg[g], &k_s[nb + w * 2048 + g * 512]); kg[g] += 64 * DH; }
                for (int q = 0; q < 4; q++) { gl_lds16(vg[q], &vt_s[nb + vloff[q]]); vg[q] += 64; }
            }
            const u16* kb = &k_s[cur * 8192];
            const u16* vb = &vt_s[cur * 8192];

            // S^T = K Q^T: swapped operands, same fragment data. Output per lane:
            // sc[ct][r] = S[q = si+ln][k-col = j0 + ct*16 + quad*4 + r]
            f32x4 sc[4];
            for (int ct = 0; ct < 4; ct++) sc[ct] = zero4;
            __builtin_amdgcn_s_setprio(1);
            for (int kt = 0; kt < 4; kt++)
                for (int ct = 0; ct < 4; ct++) {
                    bf16x8 bfr = *(const bf16x8*)&kb[kt * 2048 + (ct * 16 + ln) * 32 + qsw];
                    sc[ct] = __builtin_amdgcn_mfma_f32_16x16x32_bf16(bfr, qf[kt], sc[ct], 0, 0, 0);
                }
            __builtin_amdgcn_s_setprio(0);

            bool full = (j0 + 63 <= si);
            float s2[4][4];
            for (int ct = 0; ct < 4; ct++)
                for (int r = 0; r < 4; r++) {
                    float v = fmaf(sc[ct][r], scl, adt[ct][r]);
                    if (!full) {
                        int j = j0 + ct * 16 + quad * 4 + r;
                        if (j > iq) v = -3.0e38f;
                    }
                    s2[ct][r] = v;
                }
            // row max: lane-local 16-value tree + cross-quad reduce
            float mr = s2[0][0];
            for (int ct = 0; ct < 4; ct++)
                for (int r = 0; r < 4; r++) mr = fmaxf(mr, s2[ct][r]);
            mr = fmaxf(mr, __shfl_xor(mr, 16));
            mr = fmaxf(mr, __shfl_xor(mr, 32));
            float mnew = fmaxf(m_i, mr);
            float alpha = exp2f(m_i - mnew);
            m_i = mnew;

            // P: exp2, trunc-pack pairs, 4x ds_write_b64 (row ln, cols ct*16+quad*4..+3)
            for (int ct = 0; ct < 4; ct++) {
                float p0 = exp2f(s2[ct][0] - mnew);
                float p1 = exp2f(s2[ct][1] - mnew);
                float p2 = exp2f(s2[ct][2] - mnew);
                float p3 = exp2f(s2[ct][3] - mnew);
                unsigned d0 = (__float_as_uint(p1) & 0xFFFF0000u) | (__float_as_uint(p0) >> 16);
                unsigned d1 = (__float_as_uint(p3) & 0xFFFF0000u) | (__float_as_uint(p2) >> 16);
                uint2 dd; dd.x = d0; dd.y = d1;
                *(uint2*)&pw[ln * 72 + ct * 16 + quad * 4] = dd;
            }
            for (int ct = 0; ct < 4; ct++)
                for (int r = 0; r < 4; r++) adt[ct][r] += astep;

            // rescale O/l: gather alpha for rows quad*4+e from lanes (quad<<4)+(quad*4+e)
            if (__any(alpha != 1.0f)) {
                float av[4];
                for (int e = 0; e < 4; e++) av[e] = __shfl(alpha, quad * 20 + e);
                for (int dt = 0; dt < 8; dt++) {
                    f32x4 o = o_acc[dt];
                    for (int e = 0; e < 4; e++) o[e] *= av[e];
                    o_acc[dt] = o;
                }
                for (int e = 0; e < 4; e++) l_acc[e] *= av[e];
            }
            asm volatile("s_waitcnt lgkmcnt(0)" ::: "memory");
            __builtin_amdgcn_s_setprio(1);
            for (int ks = 0; ks < 2; ks++) {
                bf16x8 pa = *(const bf16x8*)&pw[ln * 72 + ks * 32 + quad * 8];
                l_acc = __builtin_amdgcn_mfma_f32_16x16x32_bf16(pa, ones, l_acc, 0, 0, 0);
                for (int dt = 0; dt < 8; dt++) {
                    bf16x8 vf = *(const bf16x8*)&vb[ks * 4096 + (dt * 16 + ln) * 32 + qsw];
                    o_acc[dt] = __builtin_amdgcn_mfma_f32_16x16x32_bf16(pa, vf, o_acc[dt], 0, 0, 0);
                }
            }
            __builtin_amdgcn_s_setprio(0);
            __syncthreads();
            cur ^= 1;
        }

        // epilogue: normalize (rcp), SiLU(p) gate (exp2+rcp), store bf16
        float rinv[4];
        for (int r = 0; r < 4; r++) rinv[r] = __builtin_amdgcn_rcpf(l_acc[r]);
        for (int dt = 0; dt < 8; dt++)
            for (int r = 0; r < 4; r++) {
                int i = si + quad * 4 + r;
                int dcol = dt * 16 + ln;
                float o = o_acc[dt][r] * rinv[r];
                float pv = bf2f(qkvp[(tokb + i) * 8192 + 6144 + h * DH + dcol]);
                float gate = pv * __builtin_amdgcn_rcpf(1.0f + exp2f(-pv * LOG2E));
                ag2[(tokb + i) * 2048 + h * DH + dcol] = f2bf(gate * o);
            }
    }
}

extern "C" void kernel_launch(void* const* d_in, const int* in_sizes, int n_in,
                              void* d_out, int out_size, void* d_ws, size_t ws_size,
                              hipStream_t stream) {
    const float* x       = (const float*)d_in[0];
    const float* ln1_g   = (const float*)d_in[1];
    const float* ln1_b   = (const float*)d_in[2];
    const float* ln2_g   = (const float*)d_in[3];
    const float* ln2_b   = (const float*)d_in[4];
    const float* w_in    = (const float*)d_in[5];
    const float* w_out   = (const float*)d_in[6];
    const float* smear_f = (const float*)d_in[7];
    const float* logsc   = (const float*)d_in[8];
    float* out = (float*)d_out;
    char* ws = (char*)d_ws;

    // ws layout (bytes)
    u16* w_inT   = (u16*)(ws + 0);                       // 16 MB  [8192,1024]
    u16* w_outT  = (u16*)(ws + (size_t)16777216);        //  4 MB  [1024,2048]
    u16* lnA     = (u16*)(ws + (size_t)20971520);        //  8 MB  [4096,1024]
    u16* qkvp    = (u16*)(ws + (size_t)29360128);        // 64 MB  [4096,8192]
    u16* k_sm    = (u16*)(ws + (size_t)96468992);        // 16 MB  [bh][l][128]
    u16* ag2     = (u16*)(ws + (size_t)113246208);       // 16 MB  [4096,2048]
    float* out_pre = (float*)(ws + (size_t)96468992);    // alias k_sm (dead after attn)
    u16* v_t     = (u16*)(ws + 0);                       // alias w_inT (dead after gemm1)

    dim3 b32x8(32, 8);
    conv_transpose<<<dim3(8192 / 32, 1024 / 32), b32x8, 0, stream>>>(w_in, w_inT, 1024, 8192);
    conv_transpose<<<dim3(1024 / 32, 2048 / 32), b32x8, 0, stream>>>(w_out, w_outT, 2048, 1024);
    ln_fwd<<<NTOK, 256, 0, stream>>>(x, ln1_g, ln1_b, (void*)lnA, 1);
    gemm_bt<u16><<<dim3(8192 / 128, 4096 / 128), 256, 0, stream>>>(lnA, w_inT, qkvp, NTOK, 8192, 1024);
    smear_kernel<<<4096, 256, 0, stream>>>(qkvp, smear_f, k_sm);
    vT_kernel<<<dim3(L_SEQ / 32, DH / 32, 32), b32x8, 0, stream>>>(qkvp, v_t);
    attn_kernel<<<dim3(16, 32), 256, 0, stream>>>(qkvp, k_sm, v_t, ag2, logsc);
    gemm_bt<float><<<dim3(1024 / 128, 4096 / 128), 256, 0, stream>>>(ag2, w_outT, out_pre, NTOK, 1024, 2048);
    ln_fwd<<<NTOK, 256, 0, stream>>>(out_pre, ln2_g, ln2_b, (void*)out, 0);
}

// Round 9
// 355.673 us; speedup vs baseline: 1.2251x; 1.0071x over previous
//
#include <hip/hip_runtime.h>

typedef unsigned short u16;
typedef __attribute__((ext_vector_type(8))) short bf16x8;
typedef __attribute__((ext_vector_type(8))) unsigned short u16x8;
typedef __attribute__((ext_vector_type(4))) float f32x4;

#define L_SEQ 2048
#define NTOK 4096   // B*L
#define DMODEL 1024
#define DEXP 2048
#define NH 16
#define DH 128

__device__ __forceinline__ u16 f2bf(float f) {
    unsigned u = __float_as_uint(f);
    unsigned r = (u + 0x7FFFu + ((u >> 16) & 1u)) >> 16;
    return (u16)r;
}
__device__ __forceinline__ float bf2f(u16 h) {
    return __uint_as_float(((unsigned)h) << 16);
}

// async global->LDS, 16B per lane; LDS dest = wave-uniform base + lane*16
__device__ __forceinline__ void gl_lds16(const u16* g, u16* l) {
    __builtin_amdgcn_global_load_lds((const __attribute__((address_space(1))) void*)g,
                                     (__attribute__((address_space(3))) void*)l, 16, 0, 0);
}

// ---------------- convert + transpose fp32 -> bf16, out[c*R + r] = in[r*C + c]
__global__ void conv_transpose(const float* __restrict__ in, u16* __restrict__ out, int R, int C) {
    __shared__ unsigned tile[32][33];
    int c0 = blockIdx.x * 32, r0 = blockIdx.y * 32;
    int tx = threadIdx.x, ty = threadIdx.y;
    for (int j = 0; j < 32; j += 8)
        tile[ty + j][tx] = (unsigned)f2bf(in[(size_t)(r0 + ty + j) * C + c0 + tx]);
    __syncthreads();
    for (int j = 0; j < 32; j += 8)
        out[(size_t)(c0 + ty + j) * R + r0 + tx] = (u16)tile[tx][ty + j];
}

// ---------------- layernorm over 1024, out bf16 or fp32
__global__ __launch_bounds__(256) void ln_fwd(const float* __restrict__ x, const float* __restrict__ g,
                                              const float* __restrict__ bta, void* __restrict__ outp,
                                              int out_bf16) {
    int row = blockIdx.x;
    int t = threadIdx.x;
    const float* xr = x + (size_t)row * DMODEL;
    float4 xv = *(const float4*)&xr[t * 4];
    float s = xv.x + xv.y + xv.z + xv.w;
    float s2 = xv.x * xv.x + xv.y * xv.y + xv.z * xv.z + xv.w * xv.w;
    for (int off = 32; off >= 1; off >>= 1) {
        s += __shfl_xor(s, off);
        s2 += __shfl_xor(s2, off);
    }
    __shared__ float red[10];
    int w = t >> 6;
    if ((t & 63) == 0) { red[w] = s; red[4 + w] = s2; }
    __syncthreads();
    if (t == 0) {
        red[8] = red[0] + red[1] + red[2] + red[3];
        red[9] = red[4] + red[5] + red[6] + red[7];
    }
    __syncthreads();
    float mu = red[8] * (1.0f / DMODEL);
    float var = red[9] * (1.0f / DMODEL) - mu * mu;
    float rstd = rsqrtf(var + 1e-5f);
    float vals[4] = {xv.x, xv.y, xv.z, xv.w};
    for (int e = 0; e < 4; e++) {
        int c = t * 4 + e;
        float y = (vals[e] - mu) * rstd * g[c] + bta[c];
        if (out_bf16) ((u16*)outp)[(size_t)row * DMODEL + c] = f2bf(y);
        else          ((float*)outp)[(size_t)row * DMODEL + c] = y;
    }
}

// ---------------- GEMM (128^2, 2-phase): C[M,N] = A[M,K](bf16)*B, B as BT[N,K]
__device__ __forceinline__ void store_out(u16* C, size_t idx, float v) { C[idx] = f2bf(v); }
__device__ __forceinline__ void store_out(float* C, size_t idx, float v) { C[idx] = v; }

// Round-16: two-sided XOR swizzle on the LDS tiles (same involution as attn's
// K/V tiles, verified there). Was: row stride 64B -> 8-way bank conflict on
// ds_read_b128 (8.39M conflict-cycles/dispatch = ~14% of gemm1 time). Now:
// global SOURCE segment = (lane&3)^((lrow>>1)&3) with linear LDS dest
// (global_load_lds requirement), read side quad^((ln>>1)&3) -> 2-way (free).
template <typename OutT>
__global__ __launch_bounds__(256) void gemm_bt(const u16* __restrict__ A, const u16* __restrict__ BT,
                                               OutT* __restrict__ C, int M, int N, int K) {
    __shared__ u16 a_s[2][4096];   // dbuf x 128 rows x 32 k (16-row chunks, seg-swizzled)
    __shared__ u16 b_s[2][4096];
    int tid = threadIdx.x;
    unsigned NX = gridDim.x;
    unsigned lin = blockIdx.x + NX * blockIdx.y;
    unsigned per = NX >> 3;                 // N-panels per XCD (NX % 8 == 0)
    unsigned xcd = lin & 7, t = lin >> 3;
    unsigned n_p = xcd * per + (t % per);
    unsigned m_p = t / per;
    int m0 = m_p * 128, n0 = n_p * 128;
    int w = tid >> 6, lane = tid & 63, quad = lane >> 4, ln = lane & 15;
    int wr = (w >> 1) * 64, wc = (w & 1) * 64;
    f32x4 zero4 = {0.f, 0.f, 0.f, 0.f};
    f32x4 acc[4][4];
    for (int r = 0; r < 4; r++)
        for (int c = 0; c < 4; c++) acc[r][c] = zero4;

    int lrow = lane >> 2;
    int lseg = ((lane & 3) ^ ((lrow >> 1) & 3)) * 8;   // write-side swizzle via global source
    int qsw = (quad ^ ((ln >> 1) & 3)) * 8;            // read-side (same involution)
    const u16* Ag0 = A + (size_t)(m0 + 32 * w + lrow) * K + lseg;
    const u16* Ag1 = Ag0 + (size_t)16 * K;
    const u16* Bg0 = BT + (size_t)(n0 + 32 * w + lrow) * K + lseg;
    const u16* Bg1 = Bg0 + (size_t)16 * K;
    int lo0 = (2 * w) * 512, lo1 = (2 * w + 1) * 512;

    gl_lds16(Ag0, &a_s[0][lo0]);
    gl_lds16(Ag1, &a_s[0][lo1]);
    gl_lds16(Bg0, &b_s[0][lo0]);
    gl_lds16(Bg1, &b_s[0][lo1]);
    __syncthreads();

    int cur = 0;
    for (int k0 = 0; k0 < K; k0 += 32) {
        if (k0 + 32 < K) {
            int nb = cur ^ 1;
            gl_lds16(Ag0 + k0 + 32, &a_s[nb][lo0]);
            gl_lds16(Ag1 + k0 + 32, &a_s[nb][lo1]);
            gl_lds16(Bg0 + k0 + 32, &b_s[nb][lo0]);
            gl_lds16(Bg1 + k0 + 32, &b_s[nb][lo1]);
        }
        bf16x8 af[4], bfr[4];
        for (int r = 0; r < 4; r++) af[r]  = *(const bf16x8*)&a_s[cur][(wr + r * 16 + ln) * 32 + qsw];
        for (int c = 0; c < 4; c++) bfr[c] = *(const bf16x8*)&b_s[cur][(wc + c * 16 + ln) * 32 + qsw];
        __builtin_amdgcn_s_setprio(1);
        for (int r = 0; r < 4; r++)
            for (int c = 0; c < 4; c++)
                acc[r][c] = __builtin_amdgcn_mfma_f32_16x16x32_bf16(af[r], bfr[c], acc[r][c], 0, 0, 0);
        __builtin_amdgcn_s_setprio(0);
        __syncthreads();
        cur ^= 1;
    }
    for (int r = 0; r < 4; r++)
        for (int c = 0; c < 4; c++)
            for (int e = 0; e < 4; e++) {
                int row = m0 + wr + r * 16 + quad * 4 + e;
                int col = n0 + wc + c * 16 + ln;
                store_out(C, (size_t)row * N + col, acc[r][c][e]);
            }
}

// ---------------- smear: k_sm[bh][l][d] = (1-s)*k + s*k_prev  (head-major layout)
__global__ __launch_bounds__(256) void smear_kernel(const u16* __restrict__ qkvp,
                                                    const float* __restrict__ smear_f,
                                                    u16* __restrict__ k_sm) {
    int gid = blockIdx.x * 256 + threadIdx.x;
    int base = gid * 8;
    int bl = base >> 11;       // token index
    int c = base & 2047;
    int h = c >> 7;
    int d = c & 127;
    int l = bl & (L_SEQ - 1);
    int bb = bl >> 11;
    float s = 1.0f / (1.0f + __expf(-smear_f[h]));
    u16x8 cur = *(const u16x8*)&qkvp[(size_t)bl * 8192 + 2048 + c];
    u16x8 prv = {0, 0, 0, 0, 0, 0, 0, 0};
    if (l > 0) prv = *(const u16x8*)&qkvp[(size_t)(bl - 1) * 8192 + 2048 + c];
    u16x8 outv;
    for (int u = 0; u < 8; u++) {
        float kc = bf2f(cur[u]);
        float kp = bf2f(prv[u]);
        outv[u] = f2bf((1.0f - s) * kc + s * kp);
    }
    *(u16x8*)&k_sm[(((size_t)(bb * 16 + h)) * L_SEQ + l) * DH + d] = outv;
}

// ---------------- per-(b,h) transpose of V: v_t[bh,d,l] = qkvp[tok, 4096 + h*128 + d]
__global__ void vT_kernel(const u16* __restrict__ qkvp, u16* __restrict__ v_t) {
    __shared__ unsigned tile[32][33];
    int l0 = blockIdx.x * 32, d0 = blockIdx.y * 32;
    int bh = blockIdx.z;
    int bb = bh >> 4, h = bh & 15;
    int tx = threadIdx.x, ty = threadIdx.y;
    size_t tokb = (size_t)bb * L_SEQ;
    for (int j = 0; j < 32; j += 8)
        tile[ty + j][tx] = (unsigned)qkvp[(tokb + l0 + ty + j) * 8192 + 4096 + h * DH + d0 + tx];
    __syncthreads();
    for (int j = 0; j < 32; j += 8)
        v_t[((size_t)bh * DH + d0 + ty + j) * L_SEQ + l0 + tx] = (u16)tile[tx][ty + j];
}

// ---------------- flash attention + SiLU(p) gating (round-8 version, unchanged:
// serial structure + swapped-operand QK^T, measured 95.5 us)
__global__ __launch_bounds__(256) void attn_kernel(const u16* __restrict__ qkvp,
                                                   const u16* __restrict__ k_sm,
                                                   const u16* __restrict__ v_t,
                                                   u16* __restrict__ ag2,
                                                   const float* __restrict__ log_scale) {
    __shared__ u16 k_s[16384];   // 2 bufs x [kt 0..3][jrow 0..63][32 k] (swizzled content)
    __shared__ u16 vt_s[16384];  // 2 bufs x [jt 0..1][d 0..127][32 j]  (swizzled content)
    __shared__ u16 p_s[4608];    // per-wave 16 x 72 (single buffer)
    int tid = threadIdx.x;
    // XCD clustering: lin%8 = XCD (round-robin dispatch); 4 heads per XCD.
    unsigned lin = blockIdx.x + 16u * blockIdx.y;
    unsigned xcd = lin & 7, tt = lin >> 3;
    int bh = (int)(xcd * 4 + (tt & 3));
    int pair = (int)(tt >> 2);
    int bb = bh >> 4, h = bh & 15;
    int w = tid >> 6, lane = tid & 63, quad = lane >> 4, ln = lane & 15;
    size_t tokb = (size_t)bb * L_SEQ;

    const float LOG2E = 1.44269504f;
    float inv = 1.0f / (__expf(2.0f * log_scale[h]) * sqrtf((float)DH));
    float scl = inv * LOG2E;
    float slope2 = ((h < 8) ? exp2f(-8.0f * (float)h / 7.0f) : 0.0f) * LOG2E;

    int lrow = lane >> 2, lcol = lane & 3;
    int lsw8 = (lcol ^ ((lrow >> 1) & 3)) * 8;  // write-side swizzle via global source addr
    int qsw = (quad ^ ((ln >> 1) & 3)) * 8;     // read-side swizzle (same involution)
    f32x4 zero4 = {0.f, 0.f, 0.f, 0.f};
    u16* pw = &p_s[w * 1152];
    const short ONE_BF = (short)0x3F80;
    bf16x8 ones = {ONE_BF, ONE_BF, ONE_BF, ONE_BF, ONE_BF, ONE_BF, ONE_BF, ONE_BF};

    for (int sidx = 0; sidx < 2; sidx++) {
        int ib = sidx == 0 ? (31 - pair) : pair;
        int i0 = ib * 64;
        int si = i0 + w * 16;
        int iq = si + ln;          // this lane's q-row (swapped layout)

        // Q fragments straight from global (same data serves as B-operand now)
        bf16x8 qf[4];
        for (int kt = 0; kt < 4; kt++)
            qf[kt] = *(const bf16x8*)&qkvp[(tokb + si + ln) * 8192 + h * DH + kt * 32 + quad * 8];

        float m_i = -1e30f;        // per-lane scalar (one q-row per lane)
        f32x4 o_acc[8], l_acc;
        for (int dt = 0; dt < 8; dt++) o_acc[dt] = zero4;
        l_acc = zero4;

        // ALiBi addend table: adt[ct][r] = slope2 * (j0 + ct*16 + quad*4 + r), j0=0
        float adt[4][4];
        for (int ct = 0; ct < 4; ct++)
            for (int r = 0; r < 4; r++)
                adt[ct][r] = slope2 * (float)(ct * 16 + quad * 4 + r);
        float astep = slope2 * 64.0f;

        // staging pointers: advance by constant per j-tile (pre-swizzled source)
        const u16* kg[4];
        for (int g = 0; g < 4; g++)
            kg[g] = k_sm + ((size_t)bh * L_SEQ + g * 16 + lrow) * DH + w * 32 + lsw8;
        const u16* vg[4];
        int vloff[4];
        for (int q = 0; q < 4; q++) {
            int c = w * 4 + q;
            int jt = c >> 3, dg = c & 7;
            vg[q] = v_t + ((size_t)bh * DH + dg * 16 + lrow) * L_SEQ + jt * 32 + lsw8;
            vloff[q] = jt * 4096 + dg * 512;
        }

        // prologue: stage j-tile 0 into buffer 0
        for (int g = 0; g < 4; g++) { gl_lds16(kg[g], &k_s[w * 2048 + g * 512]); kg[g] += 64 * DH; }
        for (int q = 0; q < 4; q++) { gl_lds16(vg[q], &vt_s[vloff[q]]); vg[q] += 64; }
        __syncthreads();

        int cur = 0;
        for (int j0 = 0; j0 <= i0; j0 += 64) {
            // stage NEXT tile into the other buffer; in flight across compute
            if (j0 + 64 <= i0) {
                int nb = (cur ^ 1) * 8192;
                for (int g = 0; g < 4; g++) { gl_lds16(kg[g], &k_s[nb + w * 2048 + g * 512]); kg[g] += 64 * DH; }
                for (int q = 0; q < 4; q++) { gl_lds16(vg[q], &vt_s[nb + vloff[q]]); vg[q] += 64; }
            }
            const u16* kb = &k_s[cur * 8192];
            const u16* vb = &vt_s[cur * 8192];

            // S^T = K Q^T: swapped operands, same fragment data. Output per lane:
            // sc[ct][r] = S[q = si+ln][k-col = j0 + ct*16 + quad*4 + r]
            f32x4 sc[4];
            for (int ct = 0; ct < 4; ct++) sc[ct] = zero4;
            __builtin_amdgcn_s_setprio(1);
            for (int kt = 0; kt < 4; kt++)
                for (int ct = 0; ct < 4; ct++) {
                    bf16x8 bfr = *(const bf16x8*)&kb[kt * 2048 + (ct * 16 + ln) * 32 + qsw];
                    sc[ct] = __builtin_amdgcn_mfma_f32_16x16x32_bf16(bfr, qf[kt], sc[ct], 0, 0, 0);
                }
            __builtin_amdgcn_s_setprio(0);

            bool full = (j0 + 63 <= si);
            float s2[4][4];
            for (int ct = 0; ct < 4; ct++)
                for (int r = 0; r < 4; r++) {
                    float v = fmaf(sc[ct][r], scl, adt[ct][r]);
                    if (!full) {
                        int j = j0 + ct * 16 + quad * 4 + r;
                        if (j > iq) v = -3.0e38f;
                    }
                    s2[ct][r] = v;
                }
            // row max: lane-local 16-value tree + cross-quad reduce
            float mr = s2[0][0];
            for (int ct = 0; ct < 4; ct++)
                for (int r = 0; r < 4; r++) mr = fmaxf(mr, s2[ct][r]);
            mr = fmaxf(mr, __shfl_xor(mr, 16));
            mr = fmaxf(mr, __shfl_xor(mr, 32));
            float mnew = fmaxf(m_i, mr);
            float alpha = exp2f(m_i - mnew);
            m_i = mnew;

            // P: exp2, trunc-pack pairs, 4x ds_write_b64 (row ln, cols ct*16+quad*4..+3)
            for (int ct = 0; ct < 4; ct++) {
                float p0 = exp2f(s2[ct][0] - mnew);
                float p1 = exp2f(s2[ct][1] - mnew);
                float p2 = exp2f(s2[ct][2] - mnew);
                float p3 = exp2f(s2[ct][3] - mnew);
                unsigned d0 = (__float_as_uint(p1) & 0xFFFF0000u) | (__float_as_uint(p0) >> 16);
                unsigned d1 = (__float_as_uint(p3) & 0xFFFF0000u) | (__float_as_uint(p2) >> 16);
                uint2 dd; dd.x = d0; dd.y = d1;
                *(uint2*)&pw[ln * 72 + ct * 16 + quad * 4] = dd;
            }
            for (int ct = 0; ct < 4; ct++)
                for (int r = 0; r < 4; r++) adt[ct][r] += astep;

            // rescale O/l: gather alpha for rows quad*4+e from lanes (quad<<4)+(quad*4+e)
            if (__any(alpha != 1.0f)) {
                float av[4];
                for (int e = 0; e < 4; e++) av[e] = __shfl(alpha, quad * 20 + e);
                for (int dt = 0; dt < 8; dt++) {
                    f32x4 o = o_acc[dt];
                    for (int e = 0; e < 4; e++) o[e] *= av[e];
                    o_acc[dt] = o;
                }
                for (int e = 0; e < 4; e++) l_acc[e] *= av[e];
            }
            asm volatile("s_waitcnt lgkmcnt(0)" ::: "memory");
            __builtin_amdgcn_s_setprio(1);
            for (int ks = 0; ks < 2; ks++) {
                bf16x8 pa = *(const bf16x8*)&pw[ln * 72 + ks * 32 + quad * 8];
                l_acc = __builtin_amdgcn_mfma_f32_16x16x32_bf16(pa, ones, l_acc, 0, 0, 0);
                for (int dt = 0; dt < 8; dt++) {
                    bf16x8 vf = *(const bf16x8*)&vb[ks * 4096 + (dt * 16 + ln) * 32 + qsw];
                    o_acc[dt] = __builtin_amdgcn_mfma_f32_16x16x32_bf16(pa, vf, o_acc[dt], 0, 0, 0);
                }
            }
            __builtin_amdgcn_s_setprio(0);
            __syncthreads();
            cur ^= 1;
        }

        // epilogue: normalize (rcp), SiLU(p) gate (exp2+rcp), store bf16
        float rinv[4];
        for (int r = 0; r < 4; r++) rinv[r] = __builtin_amdgcn_rcpf(l_acc[r]);
        for (int dt = 0; dt < 8; dt++)
            for (int r = 0; r < 4; r++) {
                int i = si + quad * 4 + r;
                int dcol = dt * 16 + ln;
                float o = o_acc[dt][r] * rinv[r];
                float pv = bf2f(qkvp[(tokb + i) * 8192 + 6144 + h * DH + dcol]);
                float gate = pv * __builtin_amdgcn_rcpf(1.0f + exp2f(-pv * LOG2E));
                ag2[(tokb + i) * 2048 + h * DH + dcol] = f2bf(gate * o);
            }
    }
}

extern "C" void kernel_launch(void* const* d_in, const int* in_sizes, int n_in,
                              void* d_out, int out_size, void* d_ws, size_t ws_size,
                              hipStream_t stream) {
    const float* x       = (const float*)d_in[0];
    const float* ln1_g   = (const float*)d_in[1];
    const float* ln1_b   = (const float*)d_in[2];
    const float* ln2_g   = (const float*)d_in[3];
    const float* ln2_b   = (const float*)d_in[4];
    const float* w_in    = (const float*)d_in[5];
    const float* w_out   = (const float*)d_in[6];
    const float* smear_f = (const float*)d_in[7];
    const float* logsc   = (const float*)d_in[8];
    float* out = (float*)d_out;
    char* ws = (char*)d_ws;

    // ws layout (bytes)
    u16* w_inT   = (u16*)(ws + 0);                       // 16 MB  [8192,1024]
    u16* w_outT  = (u16*)(ws + (size_t)16777216);        //  4 MB  [1024,2048]
    u16* lnA     = (u16*)(ws + (size_t)20971520);        //  8 MB  [4096,1024]
    u16* qkvp    = (u16*)(ws + (size_t)29360128);        // 64 MB  [4096,8192]
    u16* k_sm    = (u16*)(ws + (size_t)96468992);        // 16 MB  [bh][l][128]
    u16* ag2     = (u16*)(ws + (size_t)113246208);       // 16 MB  [4096,2048]
    float* out_pre = (float*)(ws + (size_t)96468992);    // alias k_sm (dead after attn)
    u16* v_t     = (u16*)(ws + 0);                       // alias w_inT (dead after gemm1)

    dim3 b32x8(32, 8);
    conv_transpose<<<dim3(8192 / 32, 1024 / 32), b32x8, 0, stream>>>(w_in, w_inT, 1024, 8192);
    conv_transpose<<<dim3(1024 / 32, 2048 / 32), b32x8, 0, stream>>>(w_out, w_outT, 2048, 1024);
    ln_fwd<<<NTOK, 256, 0, stream>>>(x, ln1_g, ln1_b, (void*)lnA, 1);
    gemm_bt<u16><<<dim3(8192 / 128, 4096 / 128), 256, 0, stream>>>(lnA, w_inT, qkvp, NTOK, 8192, 1024);
    smear_kernel<<<4096, 256, 0, stream>>>(qkvp, smear_f, k_sm);
    vT_kernel<<<dim3(L_SEQ / 32, DH / 32, 32), b32x8, 0, stream>>>(qkvp, v_t);
    attn_kernel<<<dim3(16, 32), 256, 0, stream>>>(qkvp, k_sm, v_t, ag2, logsc);
    gemm_bt<float><<<dim3(1024 / 128, 4096 / 128), 256, 0, stream>>>(ag2, w_outT, out_pre, NTOK, 1024, 2048);
    ln_fwd<<<NTOK, 256, 0, stream>>>(out_pre, ln2_g, ln2_b, (void*)out, 0);
}

// Round 10
// 345.958 us; speedup vs baseline: 1.2595x; 1.0281x over previous
//
#include <hip/hip_runtime.h>

typedef unsigned short u16;
typedef __attribute__((ext_vector_type(8))) short bf16x8;
typedef __attribute__((ext_vector_type(8))) unsigned short u16x8;
typedef __attribute__((ext_vector_type(4))) float f32x4;

#define L_SEQ 2048
#define NTOK 4096   // B*L
#define DMODEL 1024
#define DEXP 2048
#define NH 16
#define DH 128

__device__ __forceinline__ u16 f2bf(float f) {
    unsigned u = __float_as_uint(f);
    unsigned r = (u + 0x7FFFu + ((u >> 16) & 1u)) >> 16;
    return (u16)r;
}
__device__ __forceinline__ float bf2f(u16 h) {
    return __uint_as_float(((unsigned)h) << 16);
}

// async global->LDS, 16B per lane; LDS dest = wave-uniform base + lane*16
__device__ __forceinline__ void gl_lds16(const u16* g, u16* l) {
    __builtin_amdgcn_global_load_lds((const __attribute__((address_space(1))) void*)g,
                                     (__attribute__((address_space(3))) void*)l, 16, 0, 0);
}

// ---------------- convert + transpose fp32 -> bf16, out[c*R + r] = in[r*C + c]
__global__ void conv_transpose(const float* __restrict__ in, u16* __restrict__ out, int R, int C) {
    __shared__ unsigned tile[32][33];
    int c0 = blockIdx.x * 32, r0 = blockIdx.y * 32;
    int tx = threadIdx.x, ty = threadIdx.y;
    for (int j = 0; j < 32; j += 8)
        tile[ty + j][tx] = (unsigned)f2bf(in[(size_t)(r0 + ty + j) * C + c0 + tx]);
    __syncthreads();
    for (int j = 0; j < 32; j += 8)
        out[(size_t)(c0 + ty + j) * R + r0 + tx] = (u16)tile[tx][ty + j];
}

// ---------------- layernorm over 1024, out bf16 or fp32
__global__ __launch_bounds__(256) void ln_fwd(const float* __restrict__ x, const float* __restrict__ g,
                                              const float* __restrict__ bta, void* __restrict__ outp,
                                              int out_bf16) {
    int row = blockIdx.x;
    int t = threadIdx.x;
    const float* xr = x + (size_t)row * DMODEL;
    float4 xv = *(const float4*)&xr[t * 4];
    float s = xv.x + xv.y + xv.z + xv.w;
    float s2 = xv.x * xv.x + xv.y * xv.y + xv.z * xv.z + xv.w * xv.w;
    for (int off = 32; off >= 1; off >>= 1) {
        s += __shfl_xor(s, off);
        s2 += __shfl_xor(s2, off);
    }
    __shared__ float red[10];
    int w = t >> 6;
    if ((t & 63) == 0) { red[w] = s; red[4 + w] = s2; }
    __syncthreads();
    if (t == 0) {
        red[8] = red[0] + red[1] + red[2] + red[3];
        red[9] = red[4] + red[5] + red[6] + red[7];
    }
    __syncthreads();
    float mu = red[8] * (1.0f / DMODEL);
    float var = red[9] * (1.0f / DMODEL) - mu * mu;
    float rstd = rsqrtf(var + 1e-5f);
    float vals[4] = {xv.x, xv.y, xv.z, xv.w};
    for (int e = 0; e < 4; e++) {
        int c = t * 4 + e;
        float y = (vals[e] - mu) * rstd * g[c] + bta[c];
        if (out_bf16) ((u16*)outp)[(size_t)row * DMODEL + c] = f2bf(y);
        else          ((float*)outp)[(size_t)row * DMODEL + c] = y;
    }
}

// ---------------- GEMM (128^2, 2-phase): C[M,N] = A[M,K](bf16)*B, B as BT[N,K]
__device__ __forceinline__ void store_out(u16* C, size_t idx, float v) { C[idx] = f2bf(v); }
__device__ __forceinline__ void store_out(float* C, size_t idx, float v) { C[idx] = v; }

// Two-sided XOR swizzle (r9-verified: conflicts 8.39M -> gone from top-5).
template <typename OutT>
__global__ __launch_bounds__(256) void gemm_bt(const u16* __restrict__ A, const u16* __restrict__ BT,
                                               OutT* __restrict__ C, int M, int N, int K) {
    __shared__ u16 a_s[2][4096];   // dbuf x 128 rows x 32 k (16-row chunks, seg-swizzled)
    __shared__ u16 b_s[2][4096];
    int tid = threadIdx.x;
    unsigned NX = gridDim.x;
    unsigned lin = blockIdx.x + NX * blockIdx.y;
    unsigned per = NX >> 3;                 // N-panels per XCD (NX % 8 == 0)
    unsigned xcd = lin & 7, t = lin >> 3;
    unsigned n_p = xcd * per + (t % per);
    unsigned m_p = t / per;
    int m0 = m_p * 128, n0 = n_p * 128;
    int w = tid >> 6, lane = tid & 63, quad = lane >> 4, ln = lane & 15;
    int wr = (w >> 1) * 64, wc = (w & 1) * 64;
    f32x4 zero4 = {0.f, 0.f, 0.f, 0.f};
    f32x4 acc[4][4];
    for (int r = 0; r < 4; r++)
        for (int c = 0; c < 4; c++) acc[r][c] = zero4;

    int lrow = lane >> 2;
    int lseg = ((lane & 3) ^ ((lrow >> 1) & 3)) * 8;   // write-side swizzle via global source
    int qsw = (quad ^ ((ln >> 1) & 3)) * 8;            // read-side (same involution)
    const u16* Ag0 = A + (size_t)(m0 + 32 * w + lrow) * K + lseg;
    const u16* Ag1 = Ag0 + (size_t)16 * K;
    const u16* Bg0 = BT + (size_t)(n0 + 32 * w + lrow) * K + lseg;
    const u16* Bg1 = Bg0 + (size_t)16 * K;
    int lo0 = (2 * w) * 512, lo1 = (2 * w + 1) * 512;

    gl_lds16(Ag0, &a_s[0][lo0]);
    gl_lds16(Ag1, &a_s[0][lo1]);
    gl_lds16(Bg0, &b_s[0][lo0]);
    gl_lds16(Bg1, &b_s[0][lo1]);
    __syncthreads();

    int cur = 0;
    for (int k0 = 0; k0 < K; k0 += 32) {
        if (k0 + 32 < K) {
            int nb = cur ^ 1;
            gl_lds16(Ag0 + k0 + 32, &a_s[nb][lo0]);
            gl_lds16(Ag1 + k0 + 32, &a_s[nb][lo1]);
            gl_lds16(Bg0 + k0 + 32, &b_s[nb][lo0]);
            gl_lds16(Bg1 + k0 + 32, &b_s[nb][lo1]);
        }
        bf16x8 af[4], bfr[4];
        for (int r = 0; r < 4; r++) af[r]  = *(const bf16x8*)&a_s[cur][(wr + r * 16 + ln) * 32 + qsw];
        for (int c = 0; c < 4; c++) bfr[c] = *(const bf16x8*)&b_s[cur][(wc + c * 16 + ln) * 32 + qsw];
        __builtin_amdgcn_s_setprio(1);
        for (int r = 0; r < 4; r++)
            for (int c = 0; c < 4; c++)
                acc[r][c] = __builtin_amdgcn_mfma_f32_16x16x32_bf16(af[r], bfr[c], acc[r][c], 0, 0, 0);
        __builtin_amdgcn_s_setprio(0);
        __syncthreads();
        cur ^= 1;
    }
    for (int r = 0; r < 4; r++)
        for (int c = 0; c < 4; c++)
            for (int e = 0; e < 4; e++) {
                int row = m0 + wr + r * 16 + quad * 4 + e;
                int col = n0 + wc + c * 16 + ln;
                store_out(C, (size_t)row * N + col, acc[r][c][e]);
            }
}

// ---------------- GEMM2 variant: 64x128 tile -> 512 blocks = 2 blocks/CU
// (128^2 gave only 256 blocks = 1 block/CU -> latency-exposed K chain).
// Wave w: 64 rows x 32 cols (wc = w*32). Same 2-phase + swizzle + XCD remap.
__global__ __launch_bounds__(256) void gemm_bt64(const u16* __restrict__ A, const u16* __restrict__ BT,
                                                 float* __restrict__ C, int M, int N, int K) {
    __shared__ u16 a_s[2][2048];   // dbuf x 64 rows x 32 k (16-row chunks)
    __shared__ u16 b_s[2][4096];   // dbuf x 128 rows x 32 k
    int tid = threadIdx.x;
    unsigned NX = gridDim.x;       // N/128 = 8
    unsigned lin = blockIdx.x + NX * blockIdx.y;
    unsigned per = NX >> 3;
    unsigned xcd = lin & 7, t = lin >> 3;
    unsigned n_p = xcd * per + (t % per);
    unsigned m_p = t / per;
    int m0 = m_p * 64, n0 = n_p * 128;
    int w = tid >> 6, lane = tid & 63, quad = lane >> 4, ln = lane & 15;
    int wc = w * 32;
    f32x4 zero4 = {0.f, 0.f, 0.f, 0.f};
    f32x4 acc[4][2];
    for (int r = 0; r < 4; r++)
        for (int c = 0; c < 2; c++) acc[r][c] = zero4;

    int lrow = lane >> 2;
    int lseg = ((lane & 3) ^ ((lrow >> 1) & 3)) * 8;
    int qsw = (quad ^ ((ln >> 1) & 3)) * 8;
    const u16* Ag  = A + (size_t)(m0 + 16 * w + lrow) * K + lseg;   // wave w stages A chunk w
    const u16* Bg0 = BT + (size_t)(n0 + 32 * w + lrow) * K + lseg;
    const u16* Bg1 = Bg0 + (size_t)16 * K;
    int la = w * 512;
    int lb0 = (2 * w) * 512, lb1 = (2 * w + 1) * 512;

    gl_lds16(Ag, &a_s[0][la]);
    gl_lds16(Bg0, &b_s[0][lb0]);
    gl_lds16(Bg1, &b_s[0][lb1]);
    __syncthreads();

    int cur = 0;
    for (int k0 = 0; k0 < K; k0 += 32) {
        if (k0 + 32 < K) {
            int nb = cur ^ 1;
            gl_lds16(Ag + k0 + 32, &a_s[nb][la]);
            gl_lds16(Bg0 + k0 + 32, &b_s[nb][lb0]);
            gl_lds16(Bg1 + k0 + 32, &b_s[nb][lb1]);
        }
        bf16x8 af[4], bfr[2];
        for (int r = 0; r < 4; r++) af[r]  = *(const bf16x8*)&a_s[cur][(r * 16 + ln) * 32 + qsw];
        for (int c = 0; c < 2; c++) bfr[c] = *(const bf16x8*)&b_s[cur][(wc + c * 16 + ln) * 32 + qsw];
        __builtin_amdgcn_s_setprio(1);
        for (int r = 0; r < 4; r++)
            for (int c = 0; c < 2; c++)
                acc[r][c] = __builtin_amdgcn_mfma_f32_16x16x32_bf16(af[r], bfr[c], acc[r][c], 0, 0, 0);
        __builtin_amdgcn_s_setprio(0);
        __syncthreads();
        cur ^= 1;
    }
    for (int r = 0; r < 4; r++)
        for (int c = 0; c < 2; c++)
            for (int e = 0; e < 4; e++) {
                int row = m0 + r * 16 + quad * 4 + e;
                int col = n0 + wc + c * 16 + ln;
                C[(size_t)row * N + col] = acc[r][c][e];
            }
}

// ---------------- smear: k_sm[bh][l][d] = (1-s)*k + s*k_prev  (head-major layout)
__global__ __launch_bounds__(256) void smear_kernel(const u16* __restrict__ qkvp,
                                                    const float* __restrict__ smear_f,
                                                    u16* __restrict__ k_sm) {
    int gid = blockIdx.x * 256 + threadIdx.x;
    int base = gid * 8;
    int bl = base >> 11;       // token index
    int c = base & 2047;
    int h = c >> 7;
    int d = c & 127;
    int l = bl & (L_SEQ - 1);
    int bb = bl >> 11;
    float s = 1.0f / (1.0f + __expf(-smear_f[h]));
    u16x8 cur = *(const u16x8*)&qkvp[(size_t)bl * 8192 + 2048 + c];
    u16x8 prv = {0, 0, 0, 0, 0, 0, 0, 0};
    if (l > 0) prv = *(const u16x8*)&qkvp[(size_t)(bl - 1) * 8192 + 2048 + c];
    u16x8 outv;
    for (int u = 0; u < 8; u++) {
        float kc = bf2f(cur[u]);
        float kp = bf2f(prv[u]);
        outv[u] = f2bf((1.0f - s) * kc + s * kp);
    }
    *(u16x8*)&k_sm[(((size_t)(bb * 16 + h)) * L_SEQ + l) * DH + d] = outv;
}

// ---------------- per-(b,h) transpose of V: v_t[bh,d,l] = qkvp[tok, 4096 + h*128 + d]
__global__ void vT_kernel(const u16* __restrict__ qkvp, u16* __restrict__ v_t) {
    __shared__ unsigned tile[32][33];
    int l0 = blockIdx.x * 32, d0 = blockIdx.y * 32;
    int bh = blockIdx.z;
    int bb = bh >> 4, h = bh & 15;
    int tx = threadIdx.x, ty = threadIdx.y;
    size_t tokb = (size_t)bb * L_SEQ;
    for (int j = 0; j < 32; j += 8)
        tile[ty + j][tx] = (unsigned)qkvp[(tokb + l0 + ty + j) * 8192 + 4096 + h * DH + d0 + tx];
    __syncthreads();
    for (int j = 0; j < 32; j += 8)
        v_t[((size_t)bh * DH + d0 + ty + j) * L_SEQ + l0 + tx] = (u16)tile[tx][ty + j];
}

// ---------------- flash attention + SiLU(p) gating
// Round-17: r9 structure (serial + swapped-operand QK^T, 95 us) + VALU diet:
// (a) adt-shift: ALiBi addend table FIXED; running max tracked in shifted
//     domain (mshift -= astep scalar) -- replaces 16 adds/iter with 1 sub.
//     Algebraically identical (uniform shift commutes with max/sub).
// (b) v_perm_b32 pack: 1 inst per bf16-pair (bit-identical to and/or/shift).
// (c) max3-shaped reduction tree (clang fuses fmaxf triples to v_max3_f32).
__global__ __launch_bounds__(256) void attn_kernel(const u16* __restrict__ qkvp,
                                                   const u16* __restrict__ k_sm,
                                                   const u16* __restrict__ v_t,
                                                   u16* __restrict__ ag2,
                                                   const float* __restrict__ log_scale) {
    __shared__ u16 k_s[16384];   // 2 bufs x [kt 0..3][jrow 0..63][32 k] (swizzled content)
    __shared__ u16 vt_s[16384];  // 2 bufs x [jt 0..1][d 0..127][32 j]  (swizzled content)
    __shared__ u16 p_s[4608];    // per-wave 16 x 72 (single buffer)
    int tid = threadIdx.x;
    // XCD clustering: lin%8 = XCD (round-robin dispatch); 4 heads per XCD.
    unsigned lin = blockIdx.x + 16u * blockIdx.y;
    unsigned xcd = lin & 7, tt = lin >> 3;
    int bh = (int)(xcd * 4 + (tt & 3));
    int pair = (int)(tt >> 2);
    int bb = bh >> 4, h = bh & 15;
    int w = tid >> 6, lane = tid & 63, quad = lane >> 4, ln = lane & 15;
    size_t tokb = (size_t)bb * L_SEQ;

    const float LOG2E = 1.44269504f;
    float inv = 1.0f / (__expf(2.0f * log_scale[h]) * sqrtf((float)DH));
    float scl = inv * LOG2E;
    float slope2 = ((h < 8) ? exp2f(-8.0f * (float)h / 7.0f) : 0.0f) * LOG2E;

    int lrow = lane >> 2, lcol = lane & 3;
    int lsw8 = (lcol ^ ((lrow >> 1) & 3)) * 8;  // write-side swizzle via global source addr
    int qsw = (quad ^ ((ln >> 1) & 3)) * 8;     // read-side swizzle (same involution)
    f32x4 zero4 = {0.f, 0.f, 0.f, 0.f};
    u16* pw = &p_s[w * 1152];
    const short ONE_BF = (short)0x3F80;
    bf16x8 ones = {ONE_BF, ONE_BF, ONE_BF, ONE_BF, ONE_BF, ONE_BF, ONE_BF, ONE_BF};

    for (int sidx = 0; sidx < 2; sidx++) {
        int ib = sidx == 0 ? (31 - pair) : pair;
        int i0 = ib * 64;
        int si = i0 + w * 16;
        int iq = si + ln;          // this lane's q-row (swapped layout)

        // Q fragments straight from global (same data serves as B-operand now)
        bf16x8 qf[4];
        for (int kt = 0; kt < 4; kt++)
            qf[kt] = *(const bf16x8*)&qkvp[(tokb + si + ln) * 8192 + h * DH + kt * 32 + quad * 8];

        // shifted-domain running max: m_true(t) = mshift(t) + slope2*j0(t)
        float mshift = -1e30f;
        float astep = slope2 * 64.0f;
        f32x4 o_acc[8], l_acc;
        for (int dt = 0; dt < 8; dt++) o_acc[dt] = zero4;
        l_acc = zero4;

        // FIXED ALiBi base table (no per-iter increment)
        float adt0[4][4];
        for (int ct = 0; ct < 4; ct++)
            for (int r = 0; r < 4; r++)
                adt0[ct][r] = slope2 * (float)(ct * 16 + quad * 4 + r);

        // staging pointers: advance by constant per j-tile (pre-swizzled source)
        const u16* kg[4];
        for (int g = 0; g < 4; g++)
            kg[g] = k_sm + ((size_t)bh * L_SEQ + g * 16 + lrow) * DH + w * 32 + lsw8;
        const u16* vg[4];
        int vloff[4];
        for (int q = 0; q < 4; q++) {
            int c = w * 4 + q;
            int jt = c >> 3, dg = c & 7;
            vg[q] = v_t + ((size_t)bh * DH + dg * 16 + lrow) * L_SEQ + jt * 32 + lsw8;
            vloff[q] = jt * 4096 + dg * 512;
        }

        // prologue: stage j-tile 0 into buffer 0
        for (int g = 0; g < 4; g++) { gl_lds16(kg[g], &k_s[w * 2048 + g * 512]); kg[g] += 64 * DH; }
        for (int q = 0; q < 4; q++) { gl_lds16(vg[q], &vt_s[vloff[q]]); vg[q] += 64; }
        __syncthreads();

        int cur = 0;
        for (int j0 = 0; j0 <= i0; j0 += 64) {
            // stage NEXT tile into the other buffer; in flight across compute
            if (j0 + 64 <= i0) {
                int nb = (cur ^ 1) * 8192;
                for (int g = 0; g < 4; g++) { gl_lds16(kg[g], &k_s[nb + w * 2048 + g * 512]); kg[g] += 64 * DH; }
                for (int q = 0; q < 4; q++) { gl_lds16(vg[q], &vt_s[nb + vloff[q]]); vg[q] += 64; }
            }
            const u16* kb = &k_s[cur * 8192];
            const u16* vb = &vt_s[cur * 8192];

            // S^T = K Q^T: swapped operands. Lane: sc[ct][r] = S[si+ln][j0 + ct*16 + quad*4 + r]
            f32x4 sc[4];
            for (int ct = 0; ct < 4; ct++) sc[ct] = zero4;
            __builtin_amdgcn_s_setprio(1);
            for (int kt = 0; kt < 4; kt++)
                for (int ct = 0; ct < 4; ct++) {
                    bf16x8 bfr = *(const bf16x8*)&kb[kt * 2048 + (ct * 16 + ln) * 32 + qsw];
                    sc[ct] = __builtin_amdgcn_mfma_f32_16x16x32_bf16(bfr, qf[kt], sc[ct], 0, 0, 0);
                }
            __builtin_amdgcn_s_setprio(0);

            // shifted scores: s_true = s2 + slope2*j0 (uniform) -- never materialized
            bool full = (j0 + 63 <= si);
            float s2[4][4];
            for (int ct = 0; ct < 4; ct++)
                for (int r = 0; r < 4; r++) {
                    float v = fmaf(sc[ct][r], scl, adt0[ct][r]);
                    if (!full) {
                        int j = j0 + ct * 16 + quad * 4 + r;
                        if (j > iq) v = -3.0e38f;
                    }
                    s2[ct][r] = v;
                }
            // row max in shifted domain: max3-shaped tree + cross-quad reduce
            float x0 = fmaxf(fmaxf(s2[0][0], s2[0][1]), s2[0][2]);
            float x1 = fmaxf(fmaxf(s2[0][3], s2[1][0]), s2[1][1]);
            float x2 = fmaxf(fmaxf(s2[1][2], s2[1][3]), s2[2][0]);
            float x3 = fmaxf(fmaxf(s2[2][1], s2[2][2]), s2[2][3]);
            float x4 = fmaxf(fmaxf(s2[3][0], s2[3][1]), s2[3][2]);
            float y0 = fmaxf(fmaxf(x0, x1), x2);
            float y1 = fmaxf(fmaxf(x3, x4), s2[3][3]);
            float mr = fmaxf(y0, y1);
            mr = fmaxf(mr, __shfl_xor(mr, 16));
            mr = fmaxf(mr, __shfl_xor(mr, 32));
            // shifted-domain update: m_old_shift(this iter) = mshift - astep
            float msh_old = mshift - astep;
            float mnew = fmaxf(msh_old, mr);
            float alpha = exp2f(msh_old - mnew);
            mshift = mnew;

            // P: exp2 in shifted domain, v_perm pack, 4x ds_write_b64
            for (int ct = 0; ct < 4; ct++) {
                float p0 = exp2f(s2[ct][0] - mnew);
                float p1 = exp2f(s2[ct][1] - mnew);
                float p2 = exp2f(s2[ct][2] - mnew);
                float p3 = exp2f(s2[ct][3] - mnew);
                unsigned d0 = __builtin_amdgcn_perm(__float_as_uint(p1), __float_as_uint(p0), 0x07060302u);
                unsigned d1 = __builtin_amdgcn_perm(__float_as_uint(p3), __float_as_uint(p2), 0x07060302u);
                uint2 dd; dd.x = d0; dd.y = d1;
                *(uint2*)&pw[ln * 72 + ct * 16 + quad * 4] = dd;
            }

            // rescale O/l: gather alpha for rows quad*4+e from lanes (quad*16)+(quad*4+e)
            if (__any(alpha != 1.0f)) {
                float av[4];
                for (int e = 0; e < 4; e++) av[e] = __shfl(alpha, quad * 20 + e);
                for (int dt = 0; dt < 8; dt++) {
                    f32x4 o = o_acc[dt];
                    for (int e = 0; e < 4; e++) o[e] *= av[e];
                    o_acc[dt] = o;
                }
                for (int e = 0; e < 4; e++) l_acc[e] *= av[e];
            }
            asm volatile("s_waitcnt lgkmcnt(0)" ::: "memory");
            __builtin_amdgcn_s_setprio(1);
            for (int ks = 0; ks < 2; ks++) {
                bf16x8 pa = *(const bf16x8*)&pw[ln * 72 + ks * 32 + quad * 8];
                l_acc = __builtin_amdgcn_mfma_f32_16x16x32_bf16(pa, ones, l_acc, 0, 0, 0);
                for (int dt = 0; dt < 8; dt++) {
                    bf16x8 vf = *(const bf16x8*)&vb[ks * 4096 + (dt * 16 + ln) * 32 + qsw];
                    o_acc[dt] = __builtin_amdgcn_mfma_f32_16x16x32_bf16(pa, vf, o_acc[dt], 0, 0, 0);
                }
            }
            __builtin_amdgcn_s_setprio(0);
            __syncthreads();
            cur ^= 1;
        }

        // epilogue: normalize (rcp), SiLU(p) gate (exp2+rcp), store bf16
        float rinv[4];
        for (int r = 0; r < 4; r++) rinv[r] = __builtin_amdgcn_rcpf(l_acc[r]);
        for (int dt = 0; dt < 8; dt++)
            for (int r = 0; r < 4; r++) {
                int i = si + quad * 4 + r;
                int dcol = dt * 16 + ln;
                float o = o_acc[dt][r] * rinv[r];
                float pv = bf2f(qkvp[(tokb + i) * 8192 + 6144 + h * DH + dcol]);
                float gate = pv * __builtin_amdgcn_rcpf(1.0f + exp2f(-pv * LOG2E));
                ag2[(tokb + i) * 2048 + h * DH + dcol] = f2bf(gate * o);
            }
    }
}

extern "C" void kernel_launch(void* const* d_in, const int* in_sizes, int n_in,
                              void* d_out, int out_size, void* d_ws, size_t ws_size,
                              hipStream_t stream) {
    const float* x       = (const float*)d_in[0];
    const float* ln1_g   = (const float*)d_in[1];
    const float* ln1_b   = (const float*)d_in[2];
    const float* ln2_g   = (const float*)d_in[3];
    const float* ln2_b   = (const float*)d_in[4];
    const float* w_in    = (const float*)d_in[5];
    const float* w_out   = (const float*)d_in[6];
    const float* smear_f = (const float*)d_in[7];
    const float* logsc   = (const float*)d_in[8];
    float* out = (float*)d_out;
    char* ws = (char*)d_ws;

    // ws layout (bytes)
    u16* w_inT   = (u16*)(ws + 0);                       // 16 MB  [8192,1024]
    u16* w_outT  = (u16*)(ws + (size_t)16777216);        //  4 MB  [1024,2048]
    u16* lnA     = (u16*)(ws + (size_t)20971520);        //  8 MB  [4096,1024]
    u16* qkvp    = (u16*)(ws + (size_t)29360128);        // 64 MB  [4096,8192]
    u16* k_sm    = (u16*)(ws + (size_t)96468992);        // 16 MB  [bh][l][128]
    u16* ag2     = (u16*)(ws + (size_t)113246208);       // 16 MB  [4096,2048]
    float* out_pre = (float*)(ws + (size_t)96468992);    // alias k_sm (dead after attn)
    u16* v_t     = (u16*)(ws + 0);                       // alias w_inT (dead after gemm1)

    dim3 b32x8(32, 8);
    conv_transpose<<<dim3(8192 / 32, 1024 / 32), b32x8, 0, stream>>>(w_in, w_inT, 1024, 8192);
    conv_transpose<<<dim3(1024 / 32, 2048 / 32), b32x8, 0, stream>>>(w_out, w_outT, 2048, 1024);
    ln_fwd<<<NTOK, 256, 0, stream>>>(x, ln1_g, ln1_b, (void*)lnA, 1);
    gemm_bt<u16><<<dim3(8192 / 128, 4096 / 128), 256, 0, stream>>>(lnA, w_inT, qkvp, NTOK, 8192, 1024);
    smear_kernel<<<4096, 256, 0, stream>>>(qkvp, smear_f, k_sm);
    vT_kernel<<<dim3(L_SEQ / 32, DH / 32, 32), b32x8, 0, stream>>>(qkvp, v_t);
    attn_kernel<<<dim3(16, 32), 256, 0, stream>>>(qkvp, k_sm, v_t, ag2, logsc);
    gemm_bt64<<<dim3(1024 / 128, 4096 / 64), 256, 0, stream>>>(ag2, w_outT, out_pre, NTOK, 1024, 2048);
    ln_fwd<<<NTOK, 256, 0, stream>>>(out_pre, ln2_g, ln2_b, (void*)out, 0);
}

// Round 11
// 344.694 us; speedup vs baseline: 1.2641x; 1.0037x over previous
//
#include <hip/hip_runtime.h>

typedef unsigned short u16;
typedef __attribute__((ext_vector_type(8))) short bf16x8;
typedef __attribute__((ext_vector_type(8))) unsigned short u16x8;
typedef __attribute__((ext_vector_type(4))) float f32x4;

#define L_SEQ 2048
#define NTOK 4096   // B*L
#define DMODEL 1024
#define DEXP 2048
#define NH 16
#define DH 128

__device__ __forceinline__ u16 f2bf(float f) {
    unsigned u = __float_as_uint(f);
    unsigned r = (u + 0x7FFFu + ((u >> 16) & 1u)) >> 16;
    return (u16)r;
}
__device__ __forceinline__ float bf2f(u16 h) {
    return __uint_as_float(((unsigned)h) << 16);
}

// async global->LDS, 16B per lane; LDS dest = wave-uniform base + lane*16
__device__ __forceinline__ void gl_lds16(const u16* g, u16* l) {
    __builtin_amdgcn_global_load_lds((const __attribute__((address_space(1))) void*)g,
                                     (__attribute__((address_space(3))) void*)l, 16, 0, 0);
}

// ---------------- convert + transpose fp32 -> bf16, out[c*R + r] = in[r*C + c]
__global__ void conv_transpose(const float* __restrict__ in, u16* __restrict__ out, int R, int C) {
    __shared__ unsigned tile[32][33];
    int c0 = blockIdx.x * 32, r0 = blockIdx.y * 32;
    int tx = threadIdx.x, ty = threadIdx.y;
    for (int j = 0; j < 32; j += 8)
        tile[ty + j][tx] = (unsigned)f2bf(in[(size_t)(r0 + ty + j) * C + c0 + tx]);
    __syncthreads();
    for (int j = 0; j < 32; j += 8)
        out[(size_t)(c0 + ty + j) * R + r0 + tx] = (u16)tile[tx][ty + j];
}

// ---------------- layernorm over 1024, out bf16 or fp32
__global__ __launch_bounds__(256) void ln_fwd(const float* __restrict__ x, const float* __restrict__ g,
                                              const float* __restrict__ bta, void* __restrict__ outp,
                                              int out_bf16) {
    int row = blockIdx.x;
    int t = threadIdx.x;
    const float* xr = x + (size_t)row * DMODEL;
    float4 xv = *(const float4*)&xr[t * 4];
    float s = xv.x + xv.y + xv.z + xv.w;
    float s2 = xv.x * xv.x + xv.y * xv.y + xv.z * xv.z + xv.w * xv.w;
    for (int off = 32; off >= 1; off >>= 1) {
        s += __shfl_xor(s, off);
        s2 += __shfl_xor(s2, off);
    }
    __shared__ float red[10];
    int w = t >> 6;
    if ((t & 63) == 0) { red[w] = s; red[4 + w] = s2; }
    __syncthreads();
    if (t == 0) {
        red[8] = red[0] + red[1] + red[2] + red[3];
        red[9] = red[4] + red[5] + red[6] + red[7];
    }
    __syncthreads();
    float mu = red[8] * (1.0f / DMODEL);
    float var = red[9] * (1.0f / DMODEL) - mu * mu;
    float rstd = rsqrtf(var + 1e-5f);
    float vals[4] = {xv.x, xv.y, xv.z, xv.w};
    for (int e = 0; e < 4; e++) {
        int c = t * 4 + e;
        float y = (vals[e] - mu) * rstd * g[c] + bta[c];
        if (out_bf16) ((u16*)outp)[(size_t)row * DMODEL + c] = f2bf(y);
        else          ((float*)outp)[(size_t)row * DMODEL + c] = y;
    }
}

// ---------------- GEMM1: 256x256 tile, BK=64, 8 waves, TRUE 8-phase schedule
// (m201 template, correctly ported this time). Phase = block-C quadrant
// (zigzag (0,0)->(0,1)->(1,1)->(1,0)); per phase: 12 ds_read_b128 + ONE
// half-tile stage (2 gl_lds16/thread) + barrier + lgkm0 + 16 MFMA + barrier.
// Stage choreography (half staged right after its last reader):
//   A1(t+1)@P1, B0(t+1)@P2, A0(t+2)@P3, B1(t+2)@P4; gate vmcnt(4) at P4 only
//   (the 4 allowed-outstanding loads = exactly the t+2 halves staged this
//   tile; all of tile t+1 is older hence complete). Loads never drain to 0.
// Full 3-bit seg-XOR swizzle (source-side write, (ks*4+quad)^(ln&7) read).
// K accumulation order per acc cell identical to the old kernel -> same absmax.
// LDS = 2buf x 2half x 128x64 x {A,B} x 2B = 131072 B -> 1 block/CU, 8 waves.
__global__ __launch_bounds__(512, 2) void gemm_8ph(const u16* __restrict__ A, const u16* __restrict__ BT,
                                                   u16* __restrict__ C, int M, int N, int K) {
    __shared__ u16 a_s[32768];   // [buf2][half2][row128][seg8][8]
    __shared__ u16 b_s[32768];
    int tid = threadIdx.x;
    int w = tid >> 6, lane = tid & 63, quad = lane >> 4, ln = lane & 15;
    int lsw = ln & 7;
    int awrow = (w >> 2) * 64 + ln;   // wave row base within A-half (+fr*16)
    int bwcol = (w & 3) * 32 + ln;    // wave col base within B-half (+fc*16)

    unsigned lin = blockIdx.x + gridDim.x * blockIdx.y;   // gridDim.x = N/256
    unsigned per = gridDim.x >> 3;
    unsigned xcd = lin & 7, tt = lin >> 3;
    unsigned n_p = xcd * per + (tt % per);
    unsigned m_p = tt / per;
    int m0 = m_p * 256, n0 = n_p * 256;

    // staging source pointers: slot s = j*512+tid -> (row = s>>3, seg = s&7);
    // fetch global column-seg (seg ^ (row&7)) so linear-LDS + XOR-read works.
    const u16 *Ah0[2], *Ah1[2], *Bh0[2], *Bh1[2];
    int ldoff[2];
#pragma unroll
    for (int j = 0; j < 2; j++) {
        int s = j * 512 + tid;
        int row = s >> 3, seg = s & 7;
        int sw = seg ^ (row & 7);
        Ah0[j] = A + (size_t)(m0 + row) * K + sw * 8;
        Ah1[j] = A + (size_t)(m0 + 128 + row) * K + sw * 8;
        Bh0[j] = BT + (size_t)(n0 + row) * K + sw * 8;
        Bh1[j] = BT + (size_t)(n0 + 128 + row) * K + sw * 8;
        ldoff[j] = (j * 512 + w * 64) * 8;
    }

    f32x4 zero4 = {0.f, 0.f, 0.f, 0.f};
    f32x4 acc[4][4][2];   // [quadrant QM*2+QN][fr][fc]
#pragma unroll
    for (int q = 0; q < 4; q++)
#pragma unroll
        for (int fr = 0; fr < 4; fr++)
#pragma unroll
            for (int fc = 0; fc < 2; fc++) acc[q][fr][fc] = zero4;

#define G1_STAGE(MS, PTRS, B, H, T)                                                   \
    do {                                                                              \
        _Pragma("unroll") for (int j = 0; j < 2; j++)                                 \
            gl_lds16(PTRS[j] + (size_t)(T) * 64, &MS[((B)*2 + (H)) * 8192 + ldoff[j]]); \
    } while (0)

#define G1_PHASE(BUF, QM, QN, STAGE_STMT, TAILGATE)                                   \
    do {                                                                              \
        bf16x8 af_[4][2], bf_[2][2];                                                  \
        _Pragma("unroll") for (int fr = 0; fr < 4; fr++)                              \
        _Pragma("unroll") for (int ks = 0; ks < 2; ks++)                              \
            af_[fr][ks] = *(const bf16x8*)&a_s[((BUF)*2 + (QM)) * 8192 +              \
                (awrow + fr * 16) * 64 + (((ks * 4 + quad) ^ lsw) * 8)];              \
        _Pragma("unroll") for (int fc = 0; fc < 2; fc++)                              \
        _Pragma("unroll") for (int ks = 0; ks < 2; ks++)                              \
            bf_[fc][ks] = *(const bf16x8*)&b_s[((BUF)*2 + (QN)) * 8192 +              \
                (bwcol + fc * 16) * 64 + (((ks * 4 + quad) ^ lsw) * 8)];              \
        STAGE_STMT;                                                                   \
        __builtin_amdgcn_s_barrier();                                                 \
        asm volatile("s_waitcnt lgkmcnt(0)" ::: "memory");                            \
        __builtin_amdgcn_sched_barrier(0);                                            \
        __builtin_amdgcn_s_setprio(1);                                                \
        _Pragma("unroll") for (int fr = 0; fr < 4; fr++)                              \
        _Pragma("unroll") for (int fc = 0; fc < 2; fc++)                              \
        _Pragma("unroll") for (int ks = 0; ks < 2; ks++)                              \
            acc[(QM)*2 + (QN)][fr][fc] = __builtin_amdgcn_mfma_f32_16x16x32_bf16(     \
                af_[fr][ks], bf_[fc][ks], acc[(QM)*2 + (QN)][fr][fc], 0, 0, 0);       \
        __builtin_amdgcn_s_setprio(0);                                                \
        TAILGATE;                                                                     \
        __builtin_amdgcn_s_barrier();                                                 \
    } while (0)

    int NT = K >> 6;   // 16

    // prologue: tile0 all 4 halves + A0(1), B1(1); tile0 complete, 2 halves in flight
    G1_STAGE(a_s, Ah0, 0, 0, 0);
    G1_STAGE(a_s, Ah1, 0, 1, 0);
    G1_STAGE(b_s, Bh0, 0, 0, 0);
    G1_STAGE(b_s, Bh1, 0, 1, 0);
    G1_STAGE(a_s, Ah0, 1, 0, 1);
    G1_STAGE(b_s, Bh1, 1, 1, 1);
    asm volatile("s_waitcnt vmcnt(4)" ::: "memory");
    __builtin_amdgcn_s_barrier();

    for (int t = 0; t < NT; t++) {
        int buf = t & 1, nb = buf ^ 1;
        // P1: Q(0,0) reads A0,B0 | stage A1(t+1) (its old data last read at (t-1).P4)
        G1_PHASE(buf, 0, 0, { if (t + 1 < NT) G1_STAGE(a_s, Ah1, nb, 1, t + 1); }, {});
        // P2: Q(0,1) reads A0,B1 | stage B0(t+1) (last read (t-1).P4)
        G1_PHASE(buf, 0, 1, { if (t + 1 < NT) G1_STAGE(b_s, Bh0, nb, 0, t + 1); }, {});
        // P3: Q(1,1) reads A1,B1 | stage A0(t+2) (this tile's A0 last read at P2)
        G1_PHASE(buf, 1, 1, { if (t + 2 < NT) G1_STAGE(a_s, Ah0, buf, 0, t + 2); }, {});
        // P4: Q(1,0) reads A1,B0 | stage B1(t+2) (this tile's B1 last read at P3);
        // counted gate: 4 outstanding = exactly the t+2 halves staged at P3/P4.
        G1_PHASE(buf, 1, 0, { if (t + 2 < NT) G1_STAGE(b_s, Bh1, buf, 1, t + 2); },
                 {
                     if (t + 2 < NT) asm volatile("s_waitcnt vmcnt(4)" ::: "memory");
                     else            asm volatile("s_waitcnt vmcnt(0)" ::: "memory");
                 });
    }

#undef G1_STAGE
#undef G1_PHASE

#pragma unroll
    for (int QM = 0; QM < 2; QM++)
#pragma unroll
        for (int QN = 0; QN < 2; QN++)
#pragma unroll
            for (int fr = 0; fr < 4; fr++)
#pragma unroll
                for (int fc = 0; fc < 2; fc++)
#pragma unroll
                    for (int e = 0; e < 4; e++) {
                        int row = m0 + QM * 128 + (w >> 2) * 64 + fr * 16 + quad * 4 + e;
                        int col = n0 + QN * 128 + (w & 3) * 32 + fc * 16 + ln;
                        C[(size_t)row * N + col] = f2bf(acc[QM * 2 + QN][fr][fc][e]);
                    }
}

// ---------------- GEMM2 variant: 64x128 tile -> 512 blocks = 2 blocks/CU
// Wave w: 64 rows x 32 cols. 2-phase + swizzle + XCD remap (r10, verified).
__global__ __launch_bounds__(256) void gemm_bt64(const u16* __restrict__ A, const u16* __restrict__ BT,
                                                 float* __restrict__ C, int M, int N, int K) {
    __shared__ u16 a_s[2][2048];   // dbuf x 64 rows x 32 k (16-row chunks)
    __shared__ u16 b_s[2][4096];   // dbuf x 128 rows x 32 k
    int tid = threadIdx.x;
    unsigned NX = gridDim.x;       // N/128 = 8
    unsigned lin = blockIdx.x + NX * blockIdx.y;
    unsigned per = NX >> 3;
    unsigned xcd = lin & 7, t = lin >> 3;
    unsigned n_p = xcd * per + (t % per);
    unsigned m_p = t / per;
    int m0 = m_p * 64, n0 = n_p * 128;
    int w = tid >> 6, lane = tid & 63, quad = lane >> 4, ln = lane & 15;
    int wc = w * 32;
    f32x4 zero4 = {0.f, 0.f, 0.f, 0.f};
    f32x4 acc[4][2];
    for (int r = 0; r < 4; r++)
        for (int c = 0; c < 2; c++) acc[r][c] = zero4;

    int lrow = lane >> 2;
    int lseg = ((lane & 3) ^ ((lrow >> 1) & 3)) * 8;
    int qsw = (quad ^ ((ln >> 1) & 3)) * 8;
    const u16* Ag  = A + (size_t)(m0 + 16 * w + lrow) * K + lseg;   // wave w stages A chunk w
    const u16* Bg0 = BT + (size_t)(n0 + 32 * w + lrow) * K + lseg;
    const u16* Bg1 = Bg0 + (size_t)16 * K;
    int la = w * 512;
    int lb0 = (2 * w) * 512, lb1 = (2 * w + 1) * 512;

    gl_lds16(Ag, &a_s[0][la]);
    gl_lds16(Bg0, &b_s[0][lb0]);
    gl_lds16(Bg1, &b_s[0][lb1]);
    __syncthreads();

    int cur = 0;
    for (int k0 = 0; k0 < K; k0 += 32) {
        if (k0 + 32 < K) {
            int nb = cur ^ 1;
            gl_lds16(Ag + k0 + 32, &a_s[nb][la]);
            gl_lds16(Bg0 + k0 + 32, &b_s[nb][lb0]);
            gl_lds16(Bg1 + k0 + 32, &b_s[nb][lb1]);
        }
        bf16x8 af[4], bfr[2];
        for (int r = 0; r < 4; r++) af[r]  = *(const bf16x8*)&a_s[cur][(r * 16 + ln) * 32 + qsw];
        for (int c = 0; c < 2; c++) bfr[c] = *(const bf16x8*)&b_s[cur][(wc + c * 16 + ln) * 32 + qsw];
        __builtin_amdgcn_s_setprio(1);
        for (int r = 0; r < 4; r++)
            for (int c = 0; c < 2; c++)
                acc[r][c] = __builtin_amdgcn_mfma_f32_16x16x32_bf16(af[r], bfr[c], acc[r][c], 0, 0, 0);
        __builtin_amdgcn_s_setprio(0);
        __syncthreads();
        cur ^= 1;
    }
    for (int r = 0; r < 4; r++)
        for (int c = 0; c < 2; c++)
            for (int e = 0; e < 4; e++) {
                int row = m0 + r * 16 + quad * 4 + e;
                int col = n0 + wc + c * 16 + ln;
                C[(size_t)row * N + col] = acc[r][c][e];
            }
}

// ---------------- smear: k_sm[bh][l][d] = (1-s)*k + s*k_prev  (head-major layout)
__global__ __launch_bounds__(256) void smear_kernel(const u16* __restrict__ qkvp,
                                                    const float* __restrict__ smear_f,
                                                    u16* __restrict__ k_sm) {
    int gid = blockIdx.x * 256 + threadIdx.x;
    int base = gid * 8;
    int bl = base >> 11;       // token index
    int c = base & 2047;
    int h = c >> 7;
    int d = c & 127;
    int l = bl & (L_SEQ - 1);
    int bb = bl >> 11;
    float s = 1.0f / (1.0f + __expf(-smear_f[h]));
    u16x8 cur = *(const u16x8*)&qkvp[(size_t)bl * 8192 + 2048 + c];
    u16x8 prv = {0, 0, 0, 0, 0, 0, 0, 0};
    if (l > 0) prv = *(const u16x8*)&qkvp[(size_t)(bl - 1) * 8192 + 2048 + c];
    u16x8 outv;
    for (int u = 0; u < 8; u++) {
        float kc = bf2f(cur[u]);
        float kp = bf2f(prv[u]);
        outv[u] = f2bf((1.0f - s) * kc + s * kp);
    }
    *(u16x8*)&k_sm[(((size_t)(bb * 16 + h)) * L_SEQ + l) * DH + d] = outv;
}

// ---------------- per-(b,h) transpose of V: v_t[bh,d,l] = qkvp[tok, 4096 + h*128 + d]
__global__ void vT_kernel(const u16* __restrict__ qkvp, u16* __restrict__ v_t) {
    __shared__ unsigned tile[32][33];
    int l0 = blockIdx.x * 32, d0 = blockIdx.y * 32;
    int bh = blockIdx.z;
    int bb = bh >> 4, h = bh & 15;
    int tx = threadIdx.x, ty = threadIdx.y;
    size_t tokb = (size_t)bb * L_SEQ;
    for (int j = 0; j < 32; j += 8)
        tile[ty + j][tx] = (unsigned)qkvp[(tokb + l0 + ty + j) * 8192 + 4096 + h * DH + d0 + tx];
    __syncthreads();
    for (int j = 0; j < 32; j += 8)
        v_t[((size_t)bh * DH + d0 + ty + j) * L_SEQ + l0 + tx] = (u16)tile[tx][ty + j];
}

// ---------------- flash attention + SiLU(p) gating (round-10 version, unchanged:
// serial + swapped-operand QK^T + adt-shift + v_perm pack + max3 tree, <93 us)
__global__ __launch_bounds__(256) void attn_kernel(const u16* __restrict__ qkvp,
                                                   const u16* __restrict__ k_sm,
                                                   const u16* __restrict__ v_t,
                                                   u16* __restrict__ ag2,
                                                   const float* __restrict__ log_scale) {
    __shared__ u16 k_s[16384];   // 2 bufs x [kt 0..3][jrow 0..63][32 k] (swizzled content)
    __shared__ u16 vt_s[16384];  // 2 bufs x [jt 0..1][d 0..127][32 j]  (swizzled content)
    __shared__ u16 p_s[4608];    // per-wave 16 x 72 (single buffer)
    int tid = threadIdx.x;
    // XCD clustering: lin%8 = XCD (round-robin dispatch); 4 heads per XCD.
    unsigned lin = blockIdx.x + 16u * blockIdx.y;
    unsigned xcd = lin & 7, tt = lin >> 3;
    int bh = (int)(xcd * 4 + (tt & 3));
    int pair = (int)(tt >> 2);
    int bb = bh >> 4, h = bh & 15;
    int w = tid >> 6, lane = tid & 63, quad = lane >> 4, ln = lane & 15;
    size_t tokb = (size_t)bb * L_SEQ;

    const float LOG2E = 1.44269504f;
    float inv = 1.0f / (__expf(2.0f * log_scale[h]) * sqrtf((float)DH));
    float scl = inv * LOG2E;
    float slope2 = ((h < 8) ? exp2f(-8.0f * (float)h / 7.0f) : 0.0f) * LOG2E;

    int lrow = lane >> 2, lcol = lane & 3;
    int lsw8 = (lcol ^ ((lrow >> 1) & 3)) * 8;  // write-side swizzle via global source addr
    int qsw = (quad ^ ((ln >> 1) & 3)) * 8;     // read-side swizzle (same involution)
    f32x4 zero4 = {0.f, 0.f, 0.f, 0.f};
    u16* pw = &p_s[w * 1152];
    const short ONE_BF = (short)0x3F80;
    bf16x8 ones = {ONE_BF, ONE_BF, ONE_BF, ONE_BF, ONE_BF, ONE_BF, ONE_BF, ONE_BF};

    for (int sidx = 0; sidx < 2; sidx++) {
        int ib = sidx == 0 ? (31 - pair) : pair;
        int i0 = ib * 64;
        int si = i0 + w * 16;
        int iq = si + ln;          // this lane's q-row (swapped layout)

        // Q fragments straight from global (same data serves as B-operand now)
        bf16x8 qf[4];
        for (int kt = 0; kt < 4; kt++)
            qf[kt] = *(const bf16x8*)&qkvp[(tokb + si + ln) * 8192 + h * DH + kt * 32 + quad * 8];

        // shifted-domain running max: m_true(t) = mshift(t) + slope2*j0(t)
        float mshift = -1e30f;
        float astep = slope2 * 64.0f;
        f32x4 o_acc[8], l_acc;
        for (int dt = 0; dt < 8; dt++) o_acc[dt] = zero4;
        l_acc = zero4;

        // FIXED ALiBi base table (no per-iter increment)
        float adt0[4][4];
        for (int ct = 0; ct < 4; ct++)
            for (int r = 0; r < 4; r++)
                adt0[ct][r] = slope2 * (float)(ct * 16 + quad * 4 + r);

        // staging pointers: advance by constant per j-tile (pre-swizzled source)
        const u16* kg[4];
        for (int g = 0; g < 4; g++)
            kg[g] = k_sm + ((size_t)bh * L_SEQ + g * 16 + lrow) * DH + w * 32 + lsw8;
        const u16* vg[4];
        int vloff[4];
        for (int q = 0; q < 4; q++) {
            int c = w * 4 + q;
            int jt = c >> 3, dg = c & 7;
            vg[q] = v_t + ((size_t)bh * DH + dg * 16 + lrow) * L_SEQ + jt * 32 + lsw8;
            vloff[q] = jt * 4096 + dg * 512;
        }

        // prologue: stage j-tile 0 into buffer 0
        for (int g = 0; g < 4; g++) { gl_lds16(kg[g], &k_s[w * 2048 + g * 512]); kg[g] += 64 * DH; }
        for (int q = 0; q < 4; q++) { gl_lds16(vg[q], &vt_s[vloff[q]]); vg[q] += 64; }
        __syncthreads();

        int cur = 0;
        for (int j0 = 0; j0 <= i0; j0 += 64) {
            // stage NEXT tile into the other buffer; in flight across compute
            if (j0 + 64 <= i0) {
                int nb = (cur ^ 1) * 8192;
                for (int g = 0; g < 4; g++) { gl_lds16(kg[g], &k_s[nb + w * 2048 + g * 512]); kg[g] += 64 * DH; }
                for (int q = 0; q < 4; q++) { gl_lds16(vg[q], &vt_s[nb + vloff[q]]); vg[q] += 64; }
            }
            const u16* kb = &k_s[cur * 8192];
            const u16* vb = &vt_s[cur * 8192];

            // S^T = K Q^T: swapped operands. Lane: sc[ct][r] = S[si+ln][j0 + ct*16 + quad*4 + r]
            f32x4 sc[4];
            for (int ct = 0; ct < 4; ct++) sc[ct] = zero4;
            __builtin_amdgcn_s_setprio(1);
            for (int kt = 0; kt < 4; kt++)
                for (int ct = 0; ct < 4; ct++) {
                    bf16x8 bfr = *(const bf16x8*)&kb[kt * 2048 + (ct * 16 + ln) * 32 + qsw];
                    sc[ct] = __builtin_amdgcn_mfma_f32_16x16x32_bf16(bfr, qf[kt], sc[ct], 0, 0, 0);
                }
            __builtin_amdgcn_s_setprio(0);

            // shifted scores: s_true = s2 + slope2*j0 (uniform) -- never materialized
            bool full = (j0 + 63 <= si);
            float s2[4][4];
            for (int ct = 0; ct < 4; ct++)
                for (int r = 0; r < 4; r++) {
                    float v = fmaf(sc[ct][r], scl, adt0[ct][r]);
                    if (!full) {
                        int j = j0 + ct * 16 + quad * 4 + r;
                        if (j > iq) v = -3.0e38f;
                    }
                    s2[ct][r] = v;
                }
            // row max in shifted domain: max3-shaped tree + cross-quad reduce
            float x0 = fmaxf(fmaxf(s2[0][0], s2[0][1]), s2[0][2]);
            float x1 = fmaxf(fmaxf(s2[0][3], s2[1][0]), s2[1][1]);
            float x2 = fmaxf(fmaxf(s2[1][2], s2[1][3]), s2[2][0]);
            float x3 = fmaxf(fmaxf(s2[2][1], s2[2][2]), s2[2][3]);
            float x4 = fmaxf(fmaxf(s2[3][0], s2[3][1]), s2[3][2]);
            float y0 = fmaxf(fmaxf(x0, x1), x2);
            float y1 = fmaxf(fmaxf(x3, x4), s2[3][3]);
            float mr = fmaxf(y0, y1);
            mr = fmaxf(mr, __shfl_xor(mr, 16));
            mr = fmaxf(mr, __shfl_xor(mr, 32));
            // shifted-domain update: m_old_shift(this iter) = mshift - astep
            float msh_old = mshift - astep;
            float mnew = fmaxf(msh_old, mr);
            float alpha = exp2f(msh_old - mnew);
            mshift = mnew;

            // P: exp2 in shifted domain, v_perm pack, 4x ds_write_b64
            for (int ct = 0; ct < 4; ct++) {
                float p0 = exp2f(s2[ct][0] - mnew);
                float p1 = exp2f(s2[ct][1] - mnew);
                float p2 = exp2f(s2[ct][2] - mnew);
                float p3 = exp2f(s2[ct][3] - mnew);
                unsigned d0 = __builtin_amdgcn_perm(__float_as_uint(p1), __float_as_uint(p0), 0x07060302u);
                unsigned d1 = __builtin_amdgcn_perm(__float_as_uint(p3), __float_as_uint(p2), 0x07060302u);
                uint2 dd; dd.x = d0; dd.y = d1;
                *(uint2*)&pw[ln * 72 + ct * 16 + quad * 4] = dd;
            }

            // rescale O/l: gather alpha for rows quad*4+e from lanes (quad*16)+(quad*4+e)
            if (__any(alpha != 1.0f)) {
                float av[4];
                for (int e = 0; e < 4; e++) av[e] = __shfl(alpha, quad * 20 + e);
                for (int dt = 0; dt < 8; dt++) {
                    f32x4 o = o_acc[dt];
                    for (int e = 0; e < 4; e++) o[e] *= av[e];
                    o_acc[dt] = o;
                }
                for (int e = 0; e < 4; e++) l_acc[e] *= av[e];
            }
            asm volatile("s_waitcnt lgkmcnt(0)" ::: "memory");
            __builtin_amdgcn_s_setprio(1);
            for (int ks = 0; ks < 2; ks++) {
                bf16x8 pa = *(const bf16x8*)&pw[ln * 72 + ks * 32 + quad * 8];
                l_acc = __builtin_amdgcn_mfma_f32_16x16x32_bf16(pa, ones, l_acc, 0, 0, 0);
                for (int dt = 0; dt < 8; dt++) {
                    bf16x8 vf = *(const bf16x8*)&vb[ks * 4096 + (dt * 16 + ln) * 32 + qsw];
                    o_acc[dt] = __builtin_amdgcn_mfma_f32_16x16x32_bf16(pa, vf, o_acc[dt], 0, 0, 0);
                }
            }
            __builtin_amdgcn_s_setprio(0);
            __syncthreads();
            cur ^= 1;
        }

        // epilogue: normalize (rcp), SiLU(p) gate (exp2+rcp), store bf16
        float rinv[4];
        for (int r = 0; r < 4; r++) rinv[r] = __builtin_amdgcn_rcpf(l_acc[r]);
        for (int dt = 0; dt < 8; dt++)
            for (int r = 0; r < 4; r++) {
                int i = si + quad * 4 + r;
                int dcol = dt * 16 + ln;
                float o = o_acc[dt][r] * rinv[r];
                float pv = bf2f(qkvp[(tokb + i) * 8192 + 6144 + h * DH + dcol]);
                float gate = pv * __builtin_amdgcn_rcpf(1.0f + exp2f(-pv * LOG2E));
                ag2[(tokb + i) * 2048 + h * DH + dcol] = f2bf(gate * o);
            }
    }
}

extern "C" void kernel_launch(void* const* d_in, const int* in_sizes, int n_in,
                              void* d_out, int out_size, void* d_ws, size_t ws_size,
                              hipStream_t stream) {
    const float* x       = (const float*)d_in[0];
    const float* ln1_g   = (const float*)d_in[1];
    const float* ln1_b   = (const float*)d_in[2];
    const float* ln2_g   = (const float*)d_in[3];
    const float* ln2_b   = (const float*)d_in[4];
    const float* w_in    = (const float*)d_in[5];
    const float* w_out   = (const float*)d_in[6];
    const float* smear_f = (const float*)d_in[7];
    const float* logsc   = (const float*)d_in[8];
    float* out = (float*)d_out;
    char* ws = (char*)d_ws;

    // ws layout (bytes)
    u16* w_inT   = (u16*)(ws + 0);                       // 16 MB  [8192,1024]
    u16* w_outT  = (u16*)(ws + (size_t)16777216);        //  4 MB  [1024,2048]
    u16* lnA     = (u16*)(ws + (size_t)20971520);        //  8 MB  [4096,1024]
    u16* qkvp    = (u16*)(ws + (size_t)29360128);        // 64 MB  [4096,8192]
    u16* k_sm    = (u16*)(ws + (size_t)96468992);        // 16 MB  [bh][l][128]
    u16* ag2     = (u16*)(ws + (size_t)113246208);       // 16 MB  [4096,2048]
    float* out_pre = (float*)(ws + (size_t)96468992);    // alias k_sm (dead after attn)
    u16* v_t     = (u16*)(ws + 0);                       // alias w_inT (dead after gemm1)

    dim3 b32x8(32, 8);
    conv_transpose<<<dim3(8192 / 32, 1024 / 32), b32x8, 0, stream>>>(w_in, w_inT, 1024, 8192);
    conv_transpose<<<dim3(1024 / 32, 2048 / 32), b32x8, 0, stream>>>(w_out, w_outT, 2048, 1024);
    ln_fwd<<<NTOK, 256, 0, stream>>>(x, ln1_g, ln1_b, (void*)lnA, 1);
    gemm_8ph<<<dim3(8192 / 256, 4096 / 256), 512, 0, stream>>>(lnA, w_inT, qkvp, NTOK, 8192, 1024);
    smear_kernel<<<4096, 256, 0, stream>>>(qkvp, smear_f, k_sm);
    vT_kernel<<<dim3(L_SEQ / 32, DH / 32, 32), b32x8, 0, stream>>>(qkvp, v_t);
    attn_kernel<<<dim3(16, 32), 256, 0, stream>>>(qkvp, k_sm, v_t, ag2, logsc);
    gemm_bt64<<<dim3(1024 / 128, 4096 / 64), 256, 0, stream>>>(ag2, w_outT, out_pre, NTOK, 1024, 2048);
    ln_fwd<<<NTOK, 256, 0, stream>>>(out_pre, ln2_g, ln2_b, (void*)out, 0);
}

// Round 12
// 335.735 us; speedup vs baseline: 1.2978x; 1.0267x over previous
//
#include <hip/hip_runtime.h>

typedef unsigned short u16;
typedef __attribute__((ext_vector_type(8))) short bf16x8;
typedef __attribute__((ext_vector_type(8))) unsigned short u16x8;
typedef __attribute__((ext_vector_type(4))) float f32x4;

#define L_SEQ 2048
#define NTOK 4096   // B*L
#define DMODEL 1024
#define DEXP 2048
#define NH 16
#define DH 128

__device__ __forceinline__ u16 f2bf(float f) {
    unsigned u = __float_as_uint(f);
    unsigned r = (u + 0x7FFFu + ((u >> 16) & 1u)) >> 16;
    return (u16)r;
}
__device__ __forceinline__ float bf2f(u16 h) {
    return __uint_as_float(((unsigned)h) << 16);
}

// async global->LDS, 16B per lane; LDS dest = wave-uniform base + lane*16
__device__ __forceinline__ void gl_lds16(const u16* g, u16* l) {
    __builtin_amdgcn_global_load_lds((const __attribute__((address_space(1))) void*)g,
                                     (__attribute__((address_space(3))) void*)l, 16, 0, 0);
}

// ---------------- convert + transpose fp32 -> bf16, out[c*R + r] = in[r*C + c]
__global__ void conv_transpose(const float* __restrict__ in, u16* __restrict__ out, int R, int C) {
    __shared__ unsigned tile[32][33];
    int c0 = blockIdx.x * 32, r0 = blockIdx.y * 32;
    int tx = threadIdx.x, ty = threadIdx.y;
    for (int j = 0; j < 32; j += 8)
        tile[ty + j][tx] = (unsigned)f2bf(in[(size_t)(r0 + ty + j) * C + c0 + tx]);
    __syncthreads();
    for (int j = 0; j < 32; j += 8)
        out[(size_t)(c0 + ty + j) * R + r0 + tx] = (u16)tile[tx][ty + j];
}

// ---------------- layernorm over 1024, out bf16 or fp32
__global__ __launch_bounds__(256) void ln_fwd(const float* __restrict__ x, const float* __restrict__ g,
                                              const float* __restrict__ bta, void* __restrict__ outp,
                                              int out_bf16) {
    int row = blockIdx.x;
    int t = threadIdx.x;
    const float* xr = x + (size_t)row * DMODEL;
    float4 xv = *(const float4*)&xr[t * 4];
    float s = xv.x + xv.y + xv.z + xv.w;
    float s2 = xv.x * xv.x + xv.y * xv.y + xv.z * xv.z + xv.w * xv.w;
    for (int off = 32; off >= 1; off >>= 1) {
        s += __shfl_xor(s, off);
        s2 += __shfl_xor(s2, off);
    }
    __shared__ float red[10];
    int w = t >> 6;
    if ((t & 63) == 0) { red[w] = s; red[4 + w] = s2; }
    __syncthreads();
    if (t == 0) {
        red[8] = red[0] + red[1] + red[2] + red[3];
        red[9] = red[4] + red[5] + red[6] + red[7];
    }
    __syncthreads();
    float mu = red[8] * (1.0f / DMODEL);
    float var = red[9] * (1.0f / DMODEL) - mu * mu;
    float rstd = rsqrtf(var + 1e-5f);
    float vals[4] = {xv.x, xv.y, xv.z, xv.w};
    for (int e = 0; e < 4; e++) {
        int c = t * 4 + e;
        float y = (vals[e] - mu) * rstd * g[c] + bta[c];
        if (out_bf16) ((u16*)outp)[(size_t)row * DMODEL + c] = f2bf(y);
        else          ((float*)outp)[(size_t)row * DMODEL + c] = y;
    }
}

// ---------------- GEMM1: 256x256 tile, BK=64, 8 waves, 8-phase zigzag schedule
// Round-12: OPERAND-REGISTER REUSE across zigzag phases (the m201 template's
// actual point: "4 or 8 ds_read_b128"/phase, not 12). P1 loads A0+B0 (12),
// P2 reuses af (loads B1, 4), P3 reuses bf (loads A1, 8), P4 reuses af
// (loads B0, 4): 28 reads/K-tile vs 48 -- removes the ~1.9x LDS-read
// overcommit vs the MFMA pipe that capped r11 at ~750 TF.
// Staging choreography unchanged: A1(t+1)@P1, B0(t+1)@P2, A0(t+2)@P3,
// B1(t+2)@P4, vmcnt(4) gate at P4 only. Accumulation order per acc cell
// identical -> absmax must stay 0.03125.
__global__ __launch_bounds__(512, 2) void gemm_8ph(const u16* __restrict__ A, const u16* __restrict__ BT,
                                                   u16* __restrict__ C, int M, int N, int K) {
    __shared__ u16 a_s[32768];   // [buf2][half2][row128][seg8][8]
    __shared__ u16 b_s[32768];
    int tid = threadIdx.x;
    int w = tid >> 6, lane = tid & 63, quad = lane >> 4, ln = lane & 15;
    int lsw = ln & 7;
    int awrow = (w >> 2) * 64 + ln;   // wave row base within A-half (+fr*16)
    int bwcol = (w & 3) * 32 + ln;    // wave col base within B-half (+fc*16)

    unsigned lin = blockIdx.x + gridDim.x * blockIdx.y;   // gridDim.x = N/256
    unsigned per = gridDim.x >> 3;
    unsigned xcd = lin & 7, tt = lin >> 3;
    unsigned n_p = xcd * per + (tt % per);
    unsigned m_p = tt / per;
    int m0 = m_p * 256, n0 = n_p * 256;

    // staging source pointers: slot s = j*512+tid -> (row = s>>3, seg = s&7);
    // fetch global column-seg (seg ^ (row&7)) so linear-LDS + XOR-read works.
    const u16 *Ah0[2], *Ah1[2], *Bh0[2], *Bh1[2];
    int ldoff[2];
#pragma unroll
    for (int j = 0; j < 2; j++) {
        int s = j * 512 + tid;
        int row = s >> 3, seg = s & 7;
        int sw = seg ^ (row & 7);
        Ah0[j] = A + (size_t)(m0 + row) * K + sw * 8;
        Ah1[j] = A + (size_t)(m0 + 128 + row) * K + sw * 8;
        Bh0[j] = BT + (size_t)(n0 + row) * K + sw * 8;
        Bh1[j] = BT + (size_t)(n0 + 128 + row) * K + sw * 8;
        ldoff[j] = (j * 512 + w * 64) * 8;
    }

    f32x4 zero4 = {0.f, 0.f, 0.f, 0.f};
    f32x4 acc[4][4][2];   // [quadrant QM*2+QN][fr][fc]
#pragma unroll
    for (int q = 0; q < 4; q++)
#pragma unroll
        for (int fr = 0; fr < 4; fr++)
#pragma unroll
            for (int fc = 0; fc < 2; fc++) acc[q][fr][fc] = zero4;

    bf16x8 af_[4][2], bf_[2][2];   // live across phases (zigzag reuse)

#define G1_STAGE(MS, PTRS, B, H, T)                                                   \
    do {                                                                              \
        _Pragma("unroll") for (int j = 0; j < 2; j++)                                 \
            gl_lds16(PTRS[j] + (size_t)(T) * 64, &MS[((B)*2 + (H)) * 8192 + ldoff[j]]); \
    } while (0)

#define G1_PHASE(BUF, QM, QN, DOA, DOB, STAGE_STMT, TAILGATE)                         \
    do {                                                                              \
        if (DOA) {                                                                    \
            _Pragma("unroll") for (int fr = 0; fr < 4; fr++)                          \
            _Pragma("unroll") for (int ks = 0; ks < 2; ks++)                          \
                af_[fr][ks] = *(const bf16x8*)&a_s[((BUF)*2 + (QM)) * 8192 +          \
                    (awrow + fr * 16) * 64 + (((ks * 4 + quad) ^ lsw) * 8)];          \
        }                                                                             \
        if (DOB) {                                                                    \
            _Pragma("unroll") for (int fc = 0; fc < 2; fc++)                          \
            _Pragma("unroll") for (int ks = 0; ks < 2; ks++)                          \
                bf_[fc][ks] = *(const bf16x8*)&b_s[((BUF)*2 + (QN)) * 8192 +          \
                    (bwcol + fc * 16) * 64 + (((ks * 4 + quad) ^ lsw) * 8)];          \
        }                                                                             \
        STAGE_STMT;                                                                   \
        __builtin_amdgcn_s_barrier();                                                 \
        asm volatile("s_waitcnt lgkmcnt(0)" ::: "memory");                            \
        __builtin_amdgcn_sched_barrier(0);                                            \
        __builtin_amdgcn_s_setprio(1);                                                \
        _Pragma("unroll") for (int fr = 0; fr < 4; fr++)                              \
        _Pragma("unroll") for (int fc = 0; fc < 2; fc++)                              \
        _Pragma("unroll") for (int ks = 0; ks < 2; ks++)                              \
            acc[(QM)*2 + (QN)][fr][fc] = __builtin_amdgcn_mfma_f32_16x16x32_bf16(     \
                af_[fr][ks], bf_[fc][ks], acc[(QM)*2 + (QN)][fr][fc], 0, 0, 0);       \
        __builtin_amdgcn_s_setprio(0);                                                \
        TAILGATE;                                                                     \
        __builtin_amdgcn_s_barrier();                                                 \
    } while (0)

    int NT = K >> 6;   // 16

    // prologue: tile0 all 4 halves + A0(1), B1(1); tile0 complete, 2 halves in flight
    G1_STAGE(a_s, Ah0, 0, 0, 0);
    G1_STAGE(a_s, Ah1, 0, 1, 0);
    G1_STAGE(b_s, Bh0, 0, 0, 0);
    G1_STAGE(b_s, Bh1, 0, 1, 0);
    G1_STAGE(a_s, Ah0, 1, 0, 1);
    G1_STAGE(b_s, Bh1, 1, 1, 1);
    asm volatile("s_waitcnt vmcnt(4)" ::: "memory");
    __builtin_amdgcn_s_barrier();

    for (int t = 0; t < NT; t++) {
        int buf = t & 1, nb = buf ^ 1;
        // P1: Q(0,0) loads A0+B0 | stage A1(t+1) (last read at (t-1).P4)
        G1_PHASE(buf, 0, 0, 1, 1, { if (t + 1 < NT) G1_STAGE(a_s, Ah1, nb, 1, t + 1); }, {});
        // P2: Q(0,1) reuses af(A0), loads B1 | stage B0(t+1)
        G1_PHASE(buf, 0, 1, 0, 1, { if (t + 1 < NT) G1_STAGE(b_s, Bh0, nb, 0, t + 1); }, {});
        // P3: Q(1,1) loads A1, reuses bf(B1) | stage A0(t+2) (A0 last LDS-read at P1)
        G1_PHASE(buf, 1, 1, 1, 0, { if (t + 2 < NT) G1_STAGE(a_s, Ah0, buf, 0, t + 2); }, {});
        // P4: Q(1,0) reuses af(A1), loads B0 | stage B1(t+2) (B1 last read at P3);
        // counted gate: 4 outstanding = exactly the t+2 halves staged at P3/P4.
        G1_PHASE(buf, 1, 0, 0, 1, { if (t + 2 < NT) G1_STAGE(b_s, Bh1, buf, 1, t + 2); },
                 {
                     if (t + 2 < NT) asm volatile("s_waitcnt vmcnt(4)" ::: "memory");
                     else            asm volatile("s_waitcnt vmcnt(0)" ::: "memory");
                 });
    }

#undef G1_STAGE
#undef G1_PHASE

#pragma unroll
    for (int QM = 0; QM < 2; QM++)
#pragma unroll
        for (int QN = 0; QN < 2; QN++)
#pragma unroll
            for (int fr = 0; fr < 4; fr++)
#pragma unroll
                for (int fc = 0; fc < 2; fc++)
#pragma unroll
                    for (int e = 0; e < 4; e++) {
                        int row = m0 + QM * 128 + (w >> 2) * 64 + fr * 16 + quad * 4 + e;
                        int col = n0 + QN * 128 + (w & 3) * 32 + fc * 16 + ln;
                        C[(size_t)row * N + col] = f2bf(acc[QM * 2 + QN][fr][fc][e]);
                    }
}

// ---------------- GEMM2 variant: 64x128 tile -> 512 blocks = 2 blocks/CU
// Wave w: 64 rows x 32 cols. 2-phase + swizzle + XCD remap (r10, verified).
__global__ __launch_bounds__(256) void gemm_bt64(const u16* __restrict__ A, const u16* __restrict__ BT,
                                                 float* __restrict__ C, int M, int N, int K) {
    __shared__ u16 a_s[2][2048];   // dbuf x 64 rows x 32 k (16-row chunks)
    __shared__ u16 b_s[2][4096];   // dbuf x 128 rows x 32 k
    int tid = threadIdx.x;
    unsigned NX = gridDim.x;       // N/128 = 8
    unsigned lin = blockIdx.x + NX * blockIdx.y;
    unsigned per = NX >> 3;
    unsigned xcd = lin & 7, t = lin >> 3;
    unsigned n_p = xcd * per + (t % per);
    unsigned m_p = t / per;
    int m0 = m_p * 64, n0 = n_p * 128;
    int w = tid >> 6, lane = tid & 63, quad = lane >> 4, ln = lane & 15;
    int wc = w * 32;
    f32x4 zero4 = {0.f, 0.f, 0.f, 0.f};
    f32x4 acc[4][2];
    for (int r = 0; r < 4; r++)
        for (int c = 0; c < 2; c++) acc[r][c] = zero4;

    int lrow = lane >> 2;
    int lseg = ((lane & 3) ^ ((lrow >> 1) & 3)) * 8;
    int qsw = (quad ^ ((ln >> 1) & 3)) * 8;
    const u16* Ag  = A + (size_t)(m0 + 16 * w + lrow) * K + lseg;   // wave w stages A chunk w
    const u16* Bg0 = BT + (size_t)(n0 + 32 * w + lrow) * K + lseg;
    const u16* Bg1 = Bg0 + (size_t)16 * K;
    int la = w * 512;
    int lb0 = (2 * w) * 512, lb1 = (2 * w + 1) * 512;

    gl_lds16(Ag, &a_s[0][la]);
    gl_lds16(Bg0, &b_s[0][lb0]);
    gl_lds16(Bg1, &b_s[0][lb1]);
    __syncthreads();

    int cur = 0;
    for (int k0 = 0; k0 < K; k0 += 32) {
        if (k0 + 32 < K) {
            int nb = cur ^ 1;
            gl_lds16(Ag + k0 + 32, &a_s[nb][la]);
            gl_lds16(Bg0 + k0 + 32, &b_s[nb][lb0]);
            gl_lds16(Bg1 + k0 + 32, &b_s[nb][lb1]);
        }
        bf16x8 af[4], bfr[2];
        for (int r = 0; r < 4; r++) af[r]  = *(const bf16x8*)&a_s[cur][(r * 16 + ln) * 32 + qsw];
        for (int c = 0; c < 2; c++) bfr[c] = *(const bf16x8*)&b_s[cur][(wc + c * 16 + ln) * 32 + qsw];
        __builtin_amdgcn_s_setprio(1);
        for (int r = 0; r < 4; r++)
            for (int c = 0; c < 2; c++)
                acc[r][c] = __builtin_amdgcn_mfma_f32_16x16x32_bf16(af[r], bfr[c], acc[r][c], 0, 0, 0);
        __builtin_amdgcn_s_setprio(0);
        __syncthreads();
        cur ^= 1;
    }
    for (int r = 0; r < 4; r++)
        for (int c = 0; c < 2; c++)
            for (int e = 0; e < 4; e++) {
                int row = m0 + r * 16 + quad * 4 + e;
                int col = n0 + wc + c * 16 + ln;
                C[(size_t)row * N + col] = acc[r][c][e];
            }
}

// ---------------- smear: k_sm[bh][l][d] = (1-s)*k + s*k_prev  (head-major layout)
__global__ __launch_bounds__(256) void smear_kernel(const u16* __restrict__ qkvp,
                                                    const float* __restrict__ smear_f,
                                                    u16* __restrict__ k_sm) {
    int gid = blockIdx.x * 256 + threadIdx.x;
    int base = gid * 8;
    int bl = base >> 11;       // token index
    int c = base & 2047;
    int h = c >> 7;
    int d = c & 127;
    int l = bl & (L_SEQ - 1);
    int bb = bl >> 11;
    float s = 1.0f / (1.0f + __expf(-smear_f[h]));
    u16x8 cur = *(const u16x8*)&qkvp[(size_t)bl * 8192 + 2048 + c];
    u16x8 prv = {0, 0, 0, 0, 0, 0, 0, 0};
    if (l > 0) prv = *(const u16x8*)&qkvp[(size_t)(bl - 1) * 8192 + 2048 + c];
    u16x8 outv;
    for (int u = 0; u < 8; u++) {
        float kc = bf2f(cur[u]);
        float kp = bf2f(prv[u]);
        outv[u] = f2bf((1.0f - s) * kc + s * kp);
    }
    *(u16x8*)&k_sm[(((size_t)(bb * 16 + h)) * L_SEQ + l) * DH + d] = outv;
}

// ---------------- per-(b,h) transpose of V: v_t[bh,d,l] = qkvp[tok, 4096 + h*128 + d]
__global__ void vT_kernel(const u16* __restrict__ qkvp, u16* __restrict__ v_t) {
    __shared__ unsigned tile[32][33];
    int l0 = blockIdx.x * 32, d0 = blockIdx.y * 32;
    int bh = blockIdx.z;
    int bb = bh >> 4, h = bh & 15;
    int tx = threadIdx.x, ty = threadIdx.y;
    size_t tokb = (size_t)bb * L_SEQ;
    for (int j = 0; j < 32; j += 8)
        tile[ty + j][tx] = (unsigned)qkvp[(tokb + l0 + ty + j) * 8192 + 4096 + h * DH + d0 + tx];
    __syncthreads();
    for (int j = 0; j < 32; j += 8)
        v_t[((size_t)bh * DH + d0 + ty + j) * L_SEQ + l0 + tx] = (u16)tile[tx][ty + j];
}

// ---------------- flash attention + SiLU(p) gating (round-10 version, unchanged:
// serial + swapped-operand QK^T + adt-shift + v_perm pack + max3 tree, ~93.7 us)
__global__ __launch_bounds__(256) void attn_kernel(const u16* __restrict__ qkvp,
                                                   const u16* __restrict__ k_sm,
                                                   const u16* __restrict__ v_t,
                                                   u16* __restrict__ ag2,
                                                   const float* __restrict__ log_scale) {
    __shared__ u16 k_s[16384];   // 2 bufs x [kt 0..3][jrow 0..63][32 k] (swizzled content)
    __shared__ u16 vt_s[16384];  // 2 bufs x [jt 0..1][d 0..127][32 j]  (swizzled content)
    __shared__ u16 p_s[4608];    // per-wave 16 x 72 (single buffer)
    int tid = threadIdx.x;
    // XCD clustering: lin%8 = XCD (round-robin dispatch); 4 heads per XCD.
    unsigned lin = blockIdx.x + 16u * blockIdx.y;
    unsigned xcd = lin & 7, tt = lin >> 3;
    int bh = (int)(xcd * 4 + (tt & 3));
    int pair = (int)(tt >> 2);
    int bb = bh >> 4, h = bh & 15;
    int w = tid >> 6, lane = tid & 63, quad = lane >> 4, ln = lane & 15;
    size_t tokb = (size_t)bb * L_SEQ;

    const float LOG2E = 1.44269504f;
    float inv = 1.0f / (__expf(2.0f * log_scale[h]) * sqrtf((float)DH));
    float scl = inv * LOG2E;
    float slope2 = ((h < 8) ? exp2f(-8.0f * (float)h / 7.0f) : 0.0f) * LOG2E;

    int lrow = lane >> 2, lcol = lane & 3;
    int lsw8 = (lcol ^ ((lrow >> 1) & 3)) * 8;  // write-side swizzle via global source addr
    int qsw = (quad ^ ((ln >> 1) & 3)) * 8;     // read-side swizzle (same involution)
    f32x4 zero4 = {0.f, 0.f, 0.f, 0.f};
    u16* pw = &p_s[w * 1152];
    const short ONE_BF = (short)0x3F80;
    bf16x8 ones = {ONE_BF, ONE_BF, ONE_BF, ONE_BF, ONE_BF, ONE_BF, ONE_BF, ONE_BF};

    for (int sidx = 0; sidx < 2; sidx++) {
        int ib = sidx == 0 ? (31 - pair) : pair;
        int i0 = ib * 64;
        int si = i0 + w * 16;
        int iq = si + ln;          // this lane's q-row (swapped layout)

        // Q fragments straight from global (same data serves as B-operand now)
        bf16x8 qf[4];
        for (int kt = 0; kt < 4; kt++)
            qf[kt] = *(const bf16x8*)&qkvp[(tokb + si + ln) * 8192 + h * DH + kt * 32 + quad * 8];

        // shifted-domain running max: m_true(t) = mshift(t) + slope2*j0(t)
        float mshift = -1e30f;
        float astep = slope2 * 64.0f;
        f32x4 o_acc[8], l_acc;
        for (int dt = 0; dt < 8; dt++) o_acc[dt] = zero4;
        l_acc = zero4;

        // FIXED ALiBi base table (no per-iter increment)
        float adt0[4][4];
        for (int ct = 0; ct < 4; ct++)
            for (int r = 0; r < 4; r++)
                adt0[ct][r] = slope2 * (float)(ct * 16 + quad * 4 + r);

        // staging pointers: advance by constant per j-tile (pre-swizzled source)
        const u16* kg[4];
        for (int g = 0; g < 4; g++)
            kg[g] = k_sm + ((size_t)bh * L_SEQ + g * 16 + lrow) * DH + w * 32 + lsw8;
        const u16* vg[4];
        int vloff[4];
        for (int q = 0; q < 4; q++) {
            int c = w * 4 + q;
            int jt = c >> 3, dg = c & 7;
            vg[q] = v_t + ((size_t)bh * DH + dg * 16 + lrow) * L_SEQ + jt * 32 + lsw8;
            vloff[q] = jt * 4096 + dg * 512;
        }

        // prologue: stage j-tile 0 into buffer 0
        for (int g = 0; g < 4; g++) { gl_lds16(kg[g], &k_s[w * 2048 + g * 512]); kg[g] += 64 * DH; }
        for (int q = 0; q < 4; q++) { gl_lds16(vg[q], &vt_s[vloff[q]]); vg[q] += 64; }
        __syncthreads();

        int cur = 0;
        for (int j0 = 0; j0 <= i0; j0 += 64) {
            // stage NEXT tile into the other buffer; in flight across compute
            if (j0 + 64 <= i0) {
                int nb = (cur ^ 1) * 8192;
                for (int g = 0; g < 4; g++) { gl_lds16(kg[g], &k_s[nb + w * 2048 + g * 512]); kg[g] += 64 * DH; }
                for (int q = 0; q < 4; q++) { gl_lds16(vg[q], &vt_s[nb + vloff[q]]); vg[q] += 64; }
            }
            const u16* kb = &k_s[cur * 8192];
            const u16* vb = &vt_s[cur * 8192];

            // S^T = K Q^T: swapped operands. Lane: sc[ct][r] = S[si+ln][j0 + ct*16 + quad*4 + r]
            f32x4 sc[4];
            for (int ct = 0; ct < 4; ct++) sc[ct] = zero4;
            __builtin_amdgcn_s_setprio(1);
            for (int kt = 0; kt < 4; kt++)
                for (int ct = 0; ct < 4; ct++) {
                    bf16x8 bfr = *(const bf16x8*)&kb[kt * 2048 + (ct * 16 + ln) * 32 + qsw];
                    sc[ct] = __builtin_amdgcn_mfma_f32_16x16x32_bf16(bfr, qf[kt], sc[ct], 0, 0, 0);
                }
            __builtin_amdgcn_s_setprio(0);

            // shifted scores: s_true = s2 + slope2*j0 (uniform) -- never materialized
            bool full = (j0 + 63 <= si);
            float s2[4][4];
            for (int ct = 0; ct < 4; ct++)
                for (int r = 0; r < 4; r++) {
                    float v = fmaf(sc[ct][r], scl, adt0[ct][r]);
                    if (!full) {
                        int j = j0 + ct * 16 + quad * 4 + r;
                        if (j > iq) v = -3.0e38f;
                    }
                    s2[ct][r] = v;
                }
            // row max in shifted domain: max3-shaped tree + cross-quad reduce
            float x0 = fmaxf(fmaxf(s2[0][0], s2[0][1]), s2[0][2]);
            float x1 = fmaxf(fmaxf(s2[0][3], s2[1][0]), s2[1][1]);
            float x2 = fmaxf(fmaxf(s2[1][2], s2[1][3]), s2[2][0]);
            float x3 = fmaxf(fmaxf(s2[2][1], s2[2][2]), s2[2][3]);
            float x4 = fmaxf(fmaxf(s2[3][0], s2[3][1]), s2[3][2]);
            float y0 = fmaxf(fmaxf(x0, x1), x2);
            float y1 = fmaxf(fmaxf(x3, x4), s2[3][3]);
            float mr = fmaxf(y0, y1);
            mr = fmaxf(mr, __shfl_xor(mr, 16));
            mr = fmaxf(mr, __shfl_xor(mr, 32));
            // shifted-domain update: m_old_shift(this iter) = mshift - astep
            float msh_old = mshift - astep;
            float mnew = fmaxf(msh_old, mr);
            float alpha = exp2f(msh_old - mnew);
            mshift = mnew;

            // P: exp2 in shifted domain, v_perm pack, 4x ds_write_b64
            for (int ct = 0; ct < 4; ct++) {
                float p0 = exp2f(s2[ct][0] - mnew);
                float p1 = exp2f(s2[ct][1] - mnew);
                float p2 = exp2f(s2[ct][2] - mnew);
                float p3 = exp2f(s2[ct][3] - mnew);
                unsigned d0 = __builtin_amdgcn_perm(__float_as_uint(p1), __float_as_uint(p0), 0x07060302u);
                unsigned d1 = __builtin_amdgcn_perm(__float_as_uint(p3), __float_as_uint(p2), 0x07060302u);
                uint2 dd; dd.x = d0; dd.y = d1;
                *(uint2*)&pw[ln * 72 + ct * 16 + quad * 4] = dd;
            }

            // rescale O/l: gather alpha for rows quad*4+e from lanes (quad*16)+(quad*4+e)
            if (__any(alpha != 1.0f)) {
                float av[4];
                for (int e = 0; e < 4; e++) av[e] = __shfl(alpha, quad * 20 + e);
                for (int dt = 0; dt < 8; dt++) {
                    f32x4 o = o_acc[dt];
                    for (int e = 0; e < 4; e++) o[e] *= av[e];
                    o_acc[dt] = o;
                }
                for (int e = 0; e < 4; e++) l_acc[e] *= av[e];
            }
            asm volatile("s_waitcnt lgkmcnt(0)" ::: "memory");
            __builtin_amdgcn_s_setprio(1);
            for (int ks = 0; ks < 2; ks++) {
                bf16x8 pa = *(const bf16x8*)&pw[ln * 72 + ks * 32 + quad * 8];
                l_acc = __builtin_amdgcn_mfma_f32_16x16x32_bf16(pa, ones, l_acc, 0, 0, 0);
                for (int dt = 0; dt < 8; dt++) {
                    bf16x8 vf = *(const bf16x8*)&vb[ks * 4096 + (dt * 16 + ln) * 32 + qsw];
                    o_acc[dt] = __builtin_amdgcn_mfma_f32_16x16x32_bf16(pa, vf, o_acc[dt], 0, 0, 0);
                }
            }
            __builtin_amdgcn_s_setprio(0);
            __syncthreads();
            cur ^= 1;
        }

        // epilogue: normalize (rcp), SiLU(p) gate (exp2+rcp), store bf16
        float rinv[4];
        for (int r = 0; r < 4; r++) rinv[r] = __builtin_amdgcn_rcpf(l_acc[r]);
        for (int dt = 0; dt < 8; dt++)
            for (int r = 0; r < 4; r++) {
                int i = si + quad * 4 + r;
                int dcol = dt * 16 + ln;
                float o = o_acc[dt][r] * rinv[r];
                float pv = bf2f(qkvp[(tokb + i) * 8192 + 6144 + h * DH + dcol]);
                float gate = pv * __builtin_amdgcn_rcpf(1.0f + exp2f(-pv * LOG2E));
                ag2[(tokb + i) * 2048 + h * DH + dcol] = f2bf(gate * o);
            }
    }
}

extern "C" void kernel_launch(void* const* d_in, const int* in_sizes, int n_in,
                              void* d_out, int out_size, void* d_ws, size_t ws_size,
                              hipStream_t stream) {
    const float* x       = (const float*)d_in[0];
    const float* ln1_g   = (const float*)d_in[1];
    const float* ln1_b   = (const float*)d_in[2];
    const float* ln2_g   = (const float*)d_in[3];
    const float* ln2_b   = (const float*)d_in[4];
    const float* w_in    = (const float*)d_in[5];
    const float* w_out   = (const float*)d_in[6];
    const float* smear_f = (const float*)d_in[7];
    const float* logsc   = (const float*)d_in[8];
    float* out = (float*)d_out;
    char* ws = (char*)d_ws;

    // ws layout (bytes)
    u16* w_inT   = (u16*)(ws + 0);                       // 16 MB  [8192,1024]
    u16* w_outT  = (u16*)(ws + (size_t)16777216);        //  4 MB  [1024,2048]
    u16* lnA     = (u16*)(ws + (size_t)20971520);        //  8 MB  [4096,1024]
    u16* qkvp    = (u16*)(ws + (size_t)29360128);        // 64 MB  [4096,8192]
    u16* k_sm    = (u16*)(ws + (size_t)96468992);        // 16 MB  [bh][l][128]
    u16* ag2     = (u16*)(ws + (size_t)113246208);       // 16 MB  [4096,2048]
    float* out_pre = (float*)(ws + (size_t)96468992);    // alias k_sm (dead after attn)
    u16* v_t     = (u16*)(ws + 0);                       // alias w_inT (dead after gemm1)

    dim3 b32x8(32, 8);
    conv_transpose<<<dim3(8192 / 32, 1024 / 32), b32x8, 0, stream>>>(w_in, w_inT, 1024, 8192);
    conv_transpose<<<dim3(1024 / 32, 2048 / 32), b32x8, 0, stream>>>(w_out, w_outT, 2048, 1024);
    ln_fwd<<<NTOK, 256, 0, stream>>>(x, ln1_g, ln1_b, (void*)lnA, 1);
    gemm_8ph<<<dim3(8192 / 256, 4096 / 256), 512, 0, stream>>>(lnA, w_inT, qkvp, NTOK, 8192, 1024);
    smear_kernel<<<4096, 256, 0, stream>>>(qkvp, smear_f, k_sm);
    vT_kernel<<<dim3(L_SEQ / 32, DH / 32, 32), b32x8, 0, stream>>>(qkvp, v_t);
    attn_kernel<<<dim3(16, 32), 256, 0, stream>>>(qkvp, k_sm, v_t, ag2, logsc);
    gemm_bt64<<<dim3(1024 / 128, 4096 / 64), 256, 0, stream>>>(ag2, w_outT, out_pre, NTOK, 1024, 2048);
    ln_fwd<<<NTOK, 256, 0, stream>>>(out_pre, ln2_g, ln2_b, (void*)out, 0);
}

// Round 13
// 330.957 us; speedup vs baseline: 1.3165x; 1.0144x over previous
//
#include <hip/hip_runtime.h>

typedef unsigned short u16;
typedef __attribute__((ext_vector_type(8))) short bf16x8;
typedef __attribute__((ext_vector_type(8))) unsigned short u16x8;
typedef __attribute__((ext_vector_type(4))) float f32x4;

#define L_SEQ 2048
#define NTOK 4096   // B*L
#define DMODEL 1024
#define DEXP 2048
#define NH 16
#define DH 128

__device__ __forceinline__ u16 f2bf(float f) {
    unsigned u = __float_as_uint(f);
    unsigned r = (u + 0x7FFFu + ((u >> 16) & 1u)) >> 16;
    return (u16)r;
}
__device__ __forceinline__ float bf2f(u16 h) {
    return __uint_as_float(((unsigned)h) << 16);
}

// async global->LDS, 16B per lane; LDS dest = wave-uniform base + lane*16
__device__ __forceinline__ void gl_lds16(const u16* g, u16* l) {
    __builtin_amdgcn_global_load_lds((const __attribute__((address_space(1))) void*)g,
                                     (__attribute__((address_space(3))) void*)l, 16, 0, 0);
}

// ---------------- convert + transpose fp32 -> bf16, out[c*R + r] = in[r*C + c]
__global__ void conv_transpose(const float* __restrict__ in, u16* __restrict__ out, int R, int C) {
    __shared__ unsigned tile[32][33];
    int c0 = blockIdx.x * 32, r0 = blockIdx.y * 32;
    int tx = threadIdx.x, ty = threadIdx.y;
    for (int j = 0; j < 32; j += 8)
        tile[ty + j][tx] = (unsigned)f2bf(in[(size_t)(r0 + ty + j) * C + c0 + tx]);
    __syncthreads();
    for (int j = 0; j < 32; j += 8)
        out[(size_t)(c0 + ty + j) * R + r0 + tx] = (u16)tile[tx][ty + j];
}

// ---------------- layernorm over 1024, out bf16 or fp32
__global__ __launch_bounds__(256) void ln_fwd(const float* __restrict__ x, const float* __restrict__ g,
                                              const float* __restrict__ bta, void* __restrict__ outp,
                                              int out_bf16) {
    int row = blockIdx.x;
    int t = threadIdx.x;
    const float* xr = x + (size_t)row * DMODEL;
    float4 xv = *(const float4*)&xr[t * 4];
    float s = xv.x + xv.y + xv.z + xv.w;
    float s2 = xv.x * xv.x + xv.y * xv.y + xv.z * xv.z + xv.w * xv.w;
    for (int off = 32; off >= 1; off >>= 1) {
        s += __shfl_xor(s, off);
        s2 += __shfl_xor(s2, off);
    }
    __shared__ float red[10];
    int w = t >> 6;
    if ((t & 63) == 0) { red[w] = s; red[4 + w] = s2; }
    __syncthreads();
    if (t == 0) {
        red[8] = red[0] + red[1] + red[2] + red[3];
        red[9] = red[4] + red[5] + red[6] + red[7];
    }
    __syncthreads();
    float mu = red[8] * (1.0f / DMODEL);
    float var = red[9] * (1.0f / DMODEL) - mu * mu;
    float rstd = rsqrtf(var + 1e-5f);
    float vals[4] = {xv.x, xv.y, xv.z, xv.w};
    for (int e = 0; e < 4; e++) {
        int c = t * 4 + e;
        float y = (vals[e] - mu) * rstd * g[c] + bta[c];
        if (out_bf16) ((u16*)outp)[(size_t)row * DMODEL + c] = f2bf(y);
        else          ((float*)outp)[(size_t)row * DMODEL + c] = y;
    }
}

// ---------------- GEMM1: 256x256 tile, BK=64, 8 waves, 8-phase zigzag schedule
// with operand-register reuse (r12, verified: ~83 us / absmax 0.03125).
__global__ __launch_bounds__(512, 2) void gemm_8ph(const u16* __restrict__ A, const u16* __restrict__ BT,
                                                   u16* __restrict__ C, int M, int N, int K) {
    __shared__ u16 a_s[32768];   // [buf2][half2][row128][seg8][8]
    __shared__ u16 b_s[32768];
    int tid = threadIdx.x;
    int w = tid >> 6, lane = tid & 63, quad = lane >> 4, ln = lane & 15;
    int lsw = ln & 7;
    int awrow = (w >> 2) * 64 + ln;   // wave row base within A-half (+fr*16)
    int bwcol = (w & 3) * 32 + ln;    // wave col base within B-half (+fc*16)

    unsigned lin = blockIdx.x + gridDim.x * blockIdx.y;   // gridDim.x = N/256
    unsigned per = gridDim.x >> 3;
    unsigned xcd = lin & 7, tt = lin >> 3;
    unsigned n_p = xcd * per + (tt % per);
    unsigned m_p = tt / per;
    int m0 = m_p * 256, n0 = n_p * 256;

    const u16 *Ah0[2], *Ah1[2], *Bh0[2], *Bh1[2];
    int ldoff[2];
#pragma unroll
    for (int j = 0; j < 2; j++) {
        int s = j * 512 + tid;
        int row = s >> 3, seg = s & 7;
        int sw = seg ^ (row & 7);
        Ah0[j] = A + (size_t)(m0 + row) * K + sw * 8;
        Ah1[j] = A + (size_t)(m0 + 128 + row) * K + sw * 8;
        Bh0[j] = BT + (size_t)(n0 + row) * K + sw * 8;
        Bh1[j] = BT + (size_t)(n0 + 128 + row) * K + sw * 8;
        ldoff[j] = (j * 512 + w * 64) * 8;
    }

    f32x4 zero4 = {0.f, 0.f, 0.f, 0.f};
    f32x4 acc[4][4][2];   // [quadrant QM*2+QN][fr][fc]
#pragma unroll
    for (int q = 0; q < 4; q++)
#pragma unroll
        for (int fr = 0; fr < 4; fr++)
#pragma unroll
            for (int fc = 0; fc < 2; fc++) acc[q][fr][fc] = zero4;

    bf16x8 af_[4][2], bf_[2][2];   // live across phases (zigzag reuse)

#define G1_STAGE(MS, PTRS, B, H, T)                                                   \
    do {                                                                              \
        _Pragma("unroll") for (int j = 0; j < 2; j++)                                 \
            gl_lds16(PTRS[j] + (size_t)(T) * 64, &MS[((B)*2 + (H)) * 8192 + ldoff[j]]); \
    } while (0)

#define G1_PHASE(BUF, QM, QN, DOA, DOB, STAGE_STMT, TAILGATE)                         \
    do {                                                                              \
        if (DOA) {                                                                    \
            _Pragma("unroll") for (int fr = 0; fr < 4; fr++)                          \
            _Pragma("unroll") for (int ks = 0; ks < 2; ks++)                          \
                af_[fr][ks] = *(const bf16x8*)&a_s[((BUF)*2 + (QM)) * 8192 +          \
                    (awrow + fr * 16) * 64 + (((ks * 4 + quad) ^ lsw) * 8)];          \
        }                                                                             \
        if (DOB) {                                                                    \
            _Pragma("unroll") for (int fc = 0; fc < 2; fc++)                          \
            _Pragma("unroll") for (int ks = 0; ks < 2; ks++)                          \
                bf_[fc][ks] = *(const bf16x8*)&b_s[((BUF)*2 + (QN)) * 8192 +          \
                    (bwcol + fc * 16) * 64 + (((ks * 4 + quad) ^ lsw) * 8)];          \
        }                                                                             \
        STAGE_STMT;                                                                   \
        __builtin_amdgcn_s_barrier();                                                 \
        asm volatile("s_waitcnt lgkmcnt(0)" ::: "memory");                            \
        __builtin_amdgcn_sched_barrier(0);                                            \
        __builtin_amdgcn_s_setprio(1);                                                \
        _Pragma("unroll") for (int fr = 0; fr < 4; fr++)                              \
        _Pragma("unroll") for (int fc = 0; fc < 2; fc++)                              \
        _Pragma("unroll") for (int ks = 0; ks < 2; ks++)                              \
            acc[(QM)*2 + (QN)][fr][fc] = __builtin_amdgcn_mfma_f32_16x16x32_bf16(     \
                af_[fr][ks], bf_[fc][ks], acc[(QM)*2 + (QN)][fr][fc], 0, 0, 0);       \
        __builtin_amdgcn_s_setprio(0);                                                \
        TAILGATE;                                                                     \
        __builtin_amdgcn_s_barrier();                                                 \
    } while (0)

    int NT = K >> 6;   // 16

    G1_STAGE(a_s, Ah0, 0, 0, 0);
    G1_STAGE(a_s, Ah1, 0, 1, 0);
    G1_STAGE(b_s, Bh0, 0, 0, 0);
    G1_STAGE(b_s, Bh1, 0, 1, 0);
    G1_STAGE(a_s, Ah0, 1, 0, 1);
    G1_STAGE(b_s, Bh1, 1, 1, 1);
    asm volatile("s_waitcnt vmcnt(4)" ::: "memory");
    __builtin_amdgcn_s_barrier();

    for (int t = 0; t < NT; t++) {
        int buf = t & 1, nb = buf ^ 1;
        G1_PHASE(buf, 0, 0, 1, 1, { if (t + 1 < NT) G1_STAGE(a_s, Ah1, nb, 1, t + 1); }, {});
        G1_PHASE(buf, 0, 1, 0, 1, { if (t + 1 < NT) G1_STAGE(b_s, Bh0, nb, 0, t + 1); }, {});
        G1_PHASE(buf, 1, 1, 1, 0, { if (t + 2 < NT) G1_STAGE(a_s, Ah0, buf, 0, t + 2); }, {});
        G1_PHASE(buf, 1, 0, 0, 1, { if (t + 2 < NT) G1_STAGE(b_s, Bh1, buf, 1, t + 2); },
                 {
                     if (t + 2 < NT) asm volatile("s_waitcnt vmcnt(4)" ::: "memory");
                     else            asm volatile("s_waitcnt vmcnt(0)" ::: "memory");
                 });
    }

#undef G1_STAGE
#undef G1_PHASE

#pragma unroll
    for (int QM = 0; QM < 2; QM++)
#pragma unroll
        for (int QN = 0; QN < 2; QN++)
#pragma unroll
            for (int fr = 0; fr < 4; fr++)
#pragma unroll
                for (int fc = 0; fc < 2; fc++)
#pragma unroll
                    for (int e = 0; e < 4; e++) {
                        int row = m0 + QM * 128 + (w >> 2) * 64 + fr * 16 + quad * 4 + e;
                        int col = n0 + QN * 128 + (w & 3) * 32 + fc * 16 + ln;
                        C[(size_t)row * N + col] = f2bf(acc[QM * 2 + QN][fr][fc][e]);
                    }
}

// ---------------- GEMM2: 64x128 tile, BK=64 (round-13: was BK=32 -> 64
// iterations x 2 barriers with only 8 MFMA/phase, maximally barrier-bound;
// BK=64 halves barrier/stage-issue count, 16 MFMA/phase). 512 blocks =
// 2 blocks/CU; LDS 48KB dbuf (96KB/CU, fits). 3-bit seg-XOR swizzle.
// K-accumulation stays ascending in 32-steps -> absmax unchanged.
__global__ __launch_bounds__(256) void gemm_bt64(const u16* __restrict__ A, const u16* __restrict__ BT,
                                                 float* __restrict__ C, int M, int N, int K) {
    __shared__ u16 a_s[2][4096];   // dbuf x [row64][seg8][8]
    __shared__ u16 b_s[2][8192];   // dbuf x [row128][seg8][8]
    int tid = threadIdx.x;
    unsigned NX = gridDim.x;       // N/128 = 8
    unsigned lin = blockIdx.x + NX * blockIdx.y;
    unsigned per = NX >> 3;
    unsigned xcd = lin & 7, t = lin >> 3;
    unsigned n_p = xcd * per + (t % per);
    unsigned m_p = t / per;
    int m0 = m_p * 64, n0 = n_p * 128;
    int w = tid >> 6, lane = tid & 63, quad = lane >> 4, ln = lane & 15;
    int wc = w * 32, lsw = ln & 7;
    f32x4 zero4 = {0.f, 0.f, 0.f, 0.f};
    f32x4 acc[4][2];
    for (int r = 0; r < 4; r++)
        for (int c = 0; c < 2; c++) acc[r][c] = zero4;

    // staging: slot s covers (row = s>>3, seg = s&7); source seg pre-XOR'd
    const u16* Ag[2];
    int aoff[2];
#pragma unroll
    for (int j = 0; j < 2; j++) {
        int s = j * 256 + tid;
        int row = s >> 3, seg = s & 7;
        Ag[j] = A + (size_t)(m0 + row) * K + (seg ^ (row & 7)) * 8;
        aoff[j] = s * 8;
    }
    const u16* Bg[4];
    int boff[4];
#pragma unroll
    for (int j = 0; j < 4; j++) {
        int s = j * 256 + tid;
        int row = s >> 3, seg = s & 7;
        Bg[j] = BT + (size_t)(n0 + row) * K + (seg ^ (row & 7)) * 8;
        boff[j] = s * 8;
    }

    for (int j = 0; j < 2; j++) gl_lds16(Ag[j], &a_s[0][aoff[j]]);
    for (int j = 0; j < 4; j++) gl_lds16(Bg[j], &b_s[0][boff[j]]);
    __syncthreads();

    int cur = 0;
    for (int k0 = 0; k0 < K; k0 += 64) {
        if (k0 + 64 < K) {
            int nb = cur ^ 1;
            for (int j = 0; j < 2; j++) gl_lds16(Ag[j] + k0 + 64, &a_s[nb][aoff[j]]);
            for (int j = 0; j < 4; j++) gl_lds16(Bg[j] + k0 + 64, &b_s[nb][boff[j]]);
        }
        bf16x8 af[4][2], bfr[2][2];
#pragma unroll
        for (int r = 0; r < 4; r++)
#pragma unroll
            for (int ks = 0; ks < 2; ks++)
                af[r][ks] = *(const bf16x8*)&a_s[cur][(r * 16 + ln) * 64 + (((ks * 4 + quad) ^ lsw) * 8)];
#pragma unroll
        for (int c = 0; c < 2; c++)
#pragma unroll
            for (int ks = 0; ks < 2; ks++)
                bfr[c][ks] = *(const bf16x8*)&b_s[cur][(wc + c * 16 + ln) * 64 + (((ks * 4 + quad) ^ lsw) * 8)];
        __builtin_amdgcn_s_setprio(1);
#pragma unroll
        for (int r = 0; r < 4; r++)
#pragma unroll
            for (int c = 0; c < 2; c++)
#pragma unroll
                for (int ks = 0; ks < 2; ks++)
                    acc[r][c] = __builtin_amdgcn_mfma_f32_16x16x32_bf16(af[r][ks], bfr[c][ks], acc[r][c], 0, 0, 0);
        __builtin_amdgcn_s_setprio(0);
        __syncthreads();
        cur ^= 1;
    }
    for (int r = 0; r < 4; r++)
        for (int c = 0; c < 2; c++)
            for (int e = 0; e < 4; e++) {
                int row = m0 + r * 16 + quad * 4 + e;
                int col = n0 + wc + c * 16 + ln;
                C[(size_t)row * N + col] = acc[r][c][e];
            }
}

// ---------------- fused per-(b,h) V-transpose + K-smear (round-13: one launch
// instead of two; both read qkvp, both BW-trivial).
// blockIdx.y < 4: v_t[bh,d,l] = qkvp[tok, 4096 + h*128 + d]  (32x32 tile)
// blockIdx.y ==4: k_sm[bh][l][d] = (1-s)*k + s*k_prev        (32 l x 128 d chunk)
__global__ void vT_smear(const u16* __restrict__ qkvp, const float* __restrict__ smear_f,
                         u16* __restrict__ v_t, u16* __restrict__ k_sm) {
    __shared__ unsigned tile[32][33];
    int bh = blockIdx.z;
    int bb = bh >> 4, h = bh & 15;
    int tx = threadIdx.x, ty = threadIdx.y;
    size_t tokb = (size_t)bb * L_SEQ;
    if (blockIdx.y < 4) {
        int l0 = blockIdx.x * 32, d0 = blockIdx.y * 32;
        for (int j = 0; j < 32; j += 8)
            tile[ty + j][tx] = (unsigned)qkvp[(tokb + l0 + ty + j) * 8192 + 4096 + h * DH + d0 + tx];
        __syncthreads();
        for (int j = 0; j < 32; j += 8)
            v_t[((size_t)bh * DH + d0 + ty + j) * L_SEQ + l0 + tx] = (u16)tile[tx][ty + j];
    } else {
        int l0 = blockIdx.x * 32;
        int tid = ty * 32 + tx;
        float s = 1.0f / (1.0f + __expf(-smear_f[h]));
        for (int p = 0; p < 2; p++) {
            int v = tid + p * 256;       // 0..511
            int lr = v >> 4;             // 0..31
            int d = (v & 15) * 8;
            int l = l0 + lr;
            u16x8 cur = *(const u16x8*)&qkvp[(tokb + l) * 8192 + 2048 + h * DH + d];
            u16x8 prv = {0, 0, 0, 0, 0, 0, 0, 0};
            if (l > 0) prv = *(const u16x8*)&qkvp[(tokb + l - 1) * 8192 + 2048 + h * DH + d];
            u16x8 outv;
            for (int u = 0; u < 8; u++) {
                float kc = bf2f(cur[u]);
                float kp = bf2f(prv[u]);
                outv[u] = f2bf((1.0f - s) * kc + s * kp);
            }
            *(u16x8*)&k_sm[(((size_t)bh) * L_SEQ + l) * DH + d] = outv;
        }
    }
}

// ---------------- flash attention + SiLU(p) gating (round-12 version, unchanged:
// serial + swapped-operand QK^T + adt-shift + v_perm pack + max3 tree, ~93 us)
__global__ __launch_bounds__(256) void attn_kernel(const u16* __restrict__ qkvp,
                                                   const u16* __restrict__ k_sm,
                                                   const u16* __restrict__ v_t,
                                                   u16* __restrict__ ag2,
                                                   const float* __restrict__ log_scale) {
    __shared__ u16 k_s[16384];   // 2 bufs x [kt 0..3][jrow 0..63][32 k] (swizzled content)
    __shared__ u16 vt_s[16384];  // 2 bufs x [jt 0..1][d 0..127][32 j]  (swizzled content)
    __shared__ u16 p_s[4608];    // per-wave 16 x 72 (single buffer)
    int tid = threadIdx.x;
    // XCD clustering: lin%8 = XCD (round-robin dispatch); 4 heads per XCD.
    unsigned lin = blockIdx.x + 16u * blockIdx.y;
    unsigned xcd = lin & 7, tt = lin >> 3;
    int bh = (int)(xcd * 4 + (tt & 3));
    int pair = (int)(tt >> 2);
    int bb = bh >> 4, h = bh & 15;
    int w = tid >> 6, lane = tid & 63, quad = lane >> 4, ln = lane & 15;
    size_t tokb = (size_t)bb * L_SEQ;

    const float LOG2E = 1.44269504f;
    float inv = 1.0f / (__expf(2.0f * log_scale[h]) * sqrtf((float)DH));
    float scl = inv * LOG2E;
    float slope2 = ((h < 8) ? exp2f(-8.0f * (float)h / 7.0f) : 0.0f) * LOG2E;

    int lrow = lane >> 2, lcol = lane & 3;
    int lsw8 = (lcol ^ ((lrow >> 1) & 3)) * 8;  // write-side swizzle via global source addr
    int qsw = (quad ^ ((ln >> 1) & 3)) * 8;     // read-side swizzle (same involution)
    f32x4 zero4 = {0.f, 0.f, 0.f, 0.f};
    u16* pw = &p_s[w * 1152];
    const short ONE_BF = (short)0x3F80;
    bf16x8 ones = {ONE_BF, ONE_BF, ONE_BF, ONE_BF, ONE_BF, ONE_BF, ONE_BF, ONE_BF};

    for (int sidx = 0; sidx < 2; sidx++) {
        int ib = sidx == 0 ? (31 - pair) : pair;
        int i0 = ib * 64;
        int si = i0 + w * 16;
        int iq = si + ln;          // this lane's q-row (swapped layout)

        // Q fragments straight from global (same data serves as B-operand now)
        bf16x8 qf[4];
        for (int kt = 0; kt < 4; kt++)
            qf[kt] = *(const bf16x8*)&qkvp[(tokb + si + ln) * 8192 + h * DH + kt * 32 + quad * 8];

        // shifted-domain running max: m_true(t) = mshift(t) + slope2*j0(t)
        float mshift = -1e30f;
        float astep = slope2 * 64.0f;
        f32x4 o_acc[8], l_acc;
        for (int dt = 0; dt < 8; dt++) o_acc[dt] = zero4;
        l_acc = zero4;

        // FIXED ALiBi base table (no per-iter increment)
        float adt0[4][4];
        for (int ct = 0; ct < 4; ct++)
            for (int r = 0; r < 4; r++)
                adt0[ct][r] = slope2 * (float)(ct * 16 + quad * 4 + r);

        // staging pointers: advance by constant per j-tile (pre-swizzled source)
        const u16* kg[4];
        for (int g = 0; g < 4; g++)
            kg[g] = k_sm + ((size_t)bh * L_SEQ + g * 16 + lrow) * DH + w * 32 + lsw8;
        const u16* vg[4];
        int vloff[4];
        for (int q = 0; q < 4; q++) {
            int c = w * 4 + q;
            int jt = c >> 3, dg = c & 7;
            vg[q] = v_t + ((size_t)bh * DH + dg * 16 + lrow) * L_SEQ + jt * 32 + lsw8;
            vloff[q] = jt * 4096 + dg * 512;
        }

        // prologue: stage j-tile 0 into buffer 0
        for (int g = 0; g < 4; g++) { gl_lds16(kg[g], &k_s[w * 2048 + g * 512]); kg[g] += 64 * DH; }
        for (int q = 0; q < 4; q++) { gl_lds16(vg[q], &vt_s[vloff[q]]); vg[q] += 64; }
        __syncthreads();

        int cur = 0;
        for (int j0 = 0; j0 <= i0; j0 += 64) {
            // stage NEXT tile into the other buffer; in flight across compute
            if (j0 + 64 <= i0) {
                int nb = (cur ^ 1) * 8192;
                for (int g = 0; g < 4; g++) { gl_lds16(kg[g], &k_s[nb + w * 2048 + g * 512]); kg[g] += 64 * DH; }
                for (int q = 0; q < 4; q++) { gl_lds16(vg[q], &vt_s[nb + vloff[q]]); vg[q] += 64; }
            }
            const u16* kb = &k_s[cur * 8192];
            const u16* vb = &vt_s[cur * 8192];

            // S^T = K Q^T: swapped operands. Lane: sc[ct][r] = S[si+ln][j0 + ct*16 + quad*4 + r]
            f32x4 sc[4];
            for (int ct = 0; ct < 4; ct++) sc[ct] = zero4;
            __builtin_amdgcn_s_setprio(1);
            for (int kt = 0; kt < 4; kt++)
                for (int ct = 0; ct < 4; ct++) {
                    bf16x8 bfr = *(const bf16x8*)&kb[kt * 2048 + (ct * 16 + ln) * 32 + qsw];
                    sc[ct] = __builtin_amdgcn_mfma_f32_16x16x32_bf16(bfr, qf[kt], sc[ct], 0, 0, 0);
                }
            __builtin_amdgcn_s_setprio(0);

            // shifted scores: s_true = s2 + slope2*j0 (uniform) -- never materialized
            bool full = (j0 + 63 <= si);
            float s2[4][4];
            for (int ct = 0; ct < 4; ct++)
                for (int r = 0; r < 4; r++) {
                    float v = fmaf(sc[ct][r], scl, adt0[ct][r]);
                    if (!full) {
                        int j = j0 + ct * 16 + quad * 4 + r;
                        if (j > iq) v = -3.0e38f;
                    }
                    s2[ct][r] = v;
                }
            // row max in shifted domain: max3-shaped tree + cross-quad reduce
            float x0 = fmaxf(fmaxf(s2[0][0], s2[0][1]), s2[0][2]);
            float x1 = fmaxf(fmaxf(s2[0][3], s2[1][0]), s2[1][1]);
            float x2 = fmaxf(fmaxf(s2[1][2], s2[1][3]), s2[2][0]);
            float x3 = fmaxf(fmaxf(s2[2][1], s2[2][2]), s2[2][3]);
            float x4 = fmaxf(fmaxf(s2[3][0], s2[3][1]), s2[3][2]);
            float y0 = fmaxf(fmaxf(x0, x1), x2);
            float y1 = fmaxf(fmaxf(x3, x4), s2[3][3]);
            float mr = fmaxf(y0, y1);
            mr = fmaxf(mr, __shfl_xor(mr, 16));
            mr = fmaxf(mr, __shfl_xor(mr, 32));
            // shifted-domain update: m_old_shift(this iter) = mshift - astep
            float msh_old = mshift - astep;
            float mnew = fmaxf(msh_old, mr);
            float alpha = exp2f(msh_old - mnew);
            mshift = mnew;

            // P: exp2 in shifted domain, v_perm pack, 4x ds_write_b64
            for (int ct = 0; ct < 4; ct++) {
                float p0 = exp2f(s2[ct][0] - mnew);
                float p1 = exp2f(s2[ct][1] - mnew);
                float p2 = exp2f(s2[ct][2] - mnew);
                float p3 = exp2f(s2[ct][3] - mnew);
                unsigned d0 = __builtin_amdgcn_perm(__float_as_uint(p1), __float_as_uint(p0), 0x07060302u);
                unsigned d1 = __builtin_amdgcn_perm(__float_as_uint(p3), __float_as_uint(p2), 0x07060302u);
                uint2 dd; dd.x = d0; dd.y = d1;
                *(uint2*)&pw[ln * 72 + ct * 16 + quad * 4] = dd;
            }

            // rescale O/l: gather alpha for rows quad*4+e from lanes (quad*16)+(quad*4+e)
            if (__any(alpha != 1.0f)) {
                float av[4];
                for (int e = 0; e < 4; e++) av[e] = __shfl(alpha, quad * 20 + e);
                for (int dt = 0; dt < 8; dt++) {
                    f32x4 o = o_acc[dt];
                    for (int e = 0; e < 4; e++) o[e] *= av[e];
                    o_acc[dt] = o;
                }
                for (int e = 0; e < 4; e++) l_acc[e] *= av[e];
            }
            asm volatile("s_waitcnt lgkmcnt(0)" ::: "memory");
            __builtin_amdgcn_s_setprio(1);
            for (int ks = 0; ks < 2; ks++) {
                bf16x8 pa = *(const bf16x8*)&pw[ln * 72 + ks * 32 + quad * 8];
                l_acc = __builtin_amdgcn_mfma_f32_16x16x32_bf16(pa, ones, l_acc, 0, 0, 0);
                for (int dt = 0; dt < 8; dt++) {
                    bf16x8 vf = *(const bf16x8*)&vb[ks * 4096 + (dt * 16 + ln) * 32 + qsw];
                    o_acc[dt] = __builtin_amdgcn_mfma_f32_16x16x32_bf16(pa, vf, o_acc[dt], 0, 0, 0);
                }
            }
            __builtin_amdgcn_s_setprio(0);
            __syncthreads();
            cur ^= 1;
        }

        // epilogue: normalize (rcp), SiLU(p) gate (exp2+rcp), store bf16
        float rinv[4];
        for (int r = 0; r < 4; r++) rinv[r] = __builtin_amdgcn_rcpf(l_acc[r]);
        for (int dt = 0; dt < 8; dt++)
            for (int r = 0; r < 4; r++) {
                int i = si + quad * 4 + r;
                int dcol = dt * 16 + ln;
                float o = o_acc[dt][r] * rinv[r];
                float pv = bf2f(qkvp[(tokb + i) * 8192 + 6144 + h * DH + dcol]);
                float gate = pv * __builtin_amdgcn_rcpf(1.0f + exp2f(-pv * LOG2E));
                ag2[(tokb + i) * 2048 + h * DH + dcol] = f2bf(gate * o);
            }
    }
}

extern "C" void kernel_launch(void* const* d_in, const int* in_sizes, int n_in,
                              void* d_out, int out_size, void* d_ws, size_t ws_size,
                              hipStream_t stream) {
    const float* x       = (const float*)d_in[0];
    const float* ln1_g   = (const float*)d_in[1];
    const float* ln1_b   = (const float*)d_in[2];
    const float* ln2_g   = (const float*)d_in[3];
    const float* ln2_b   = (const float*)d_in[4];
    const float* w_in    = (const float*)d_in[5];
    const float* w_out   = (const float*)d_in[6];
    const float* smear_f = (const float*)d_in[7];
    const float* logsc   = (const float*)d_in[8];
    float* out = (float*)d_out;
    char* ws = (char*)d_ws;

    // ws layout (bytes)
    u16* w_inT   = (u16*)(ws + 0);                       // 16 MB  [8192,1024]
    u16* w_outT  = (u16*)(ws + (size_t)16777216);        //  4 MB  [1024,2048]
    u16* lnA     = (u16*)(ws + (size_t)20971520);        //  8 MB  [4096,1024]
    u16* qkvp    = (u16*)(ws + (size_t)29360128);        // 64 MB  [4096,8192]
    u16* k_sm    = (u16*)(ws + (size_t)96468992);        // 16 MB  [bh][l][128]
    u16* ag2     = (u16*)(ws + (size_t)113246208);       // 16 MB  [4096,2048]
    float* out_pre = (float*)(ws + (size_t)96468992);    // alias k_sm (dead after attn)
    u16* v_t     = (u16*)(ws + 0);                       // alias w_inT (dead after gemm1)

    dim3 b32x8(32, 8);
    conv_transpose<<<dim3(8192 / 32, 1024 / 32), b32x8, 0, stream>>>(w_in, w_inT, 1024, 8192);
    conv_transpose<<<dim3(1024 / 32, 2048 / 32), b32x8, 0, stream>>>(w_out, w_outT, 2048, 1024);
    ln_fwd<<<NTOK, 256, 0, stream>>>(x, ln1_g, ln1_b, (void*)lnA, 1);
    gemm_8ph<<<dim3(8192 / 256, 4096 / 256), 512, 0, stream>>>(lnA, w_inT, qkvp, NTOK, 8192, 1024);
    vT_smear<<<dim3(L_SEQ / 32, 5, 32), b32x8, 0, stream>>>(qkvp, smear_f, v_t, k_sm);
    attn_kernel<<<dim3(16, 32), 256, 0, stream>>>(qkvp, k_sm, v_t, ag2, logsc);
    gemm_bt64<<<dim3(1024 / 128, 4096 / 64), 256, 0, stream>>>(ag2, w_outT, out_pre, NTOK, 1024, 2048);
    ln_fwd<<<NTOK, 256, 0, stream>>>(out_pre, ln2_g, ln2_b, (void*)out, 0);
}